// Round 2
// baseline (7697.237 us; speedup 1.0000x reference)
//
#include <hip/hip_runtime.h>
#include <hip/hip_bf16.h>
#include <math.h>

#define N_NODES 60000
#define N_EDGES 120000
#define N_BATCH 512
#define DIM 256
#define N_LAYERS 6
#define GEN_EPS 1e-7f
#define LN_EPS 1e-5f

// ---------------- embed: h[n] = node_emb[x[n]] ----------------
__global__ void embed_kernel(const int* __restrict__ x, const float* __restrict__ emb,
                             float* __restrict__ h) {
    int t = blockIdx.x * 256 + threadIdx.x;
    int n = t >> 6, lane = t & 63;
    if (n >= N_NODES) return;
    int type = x[n];
    float4 v = *(const float4*)(emb + (size_t)type * DIM + lane * 4);
    *(float4*)(h + (size_t)n * DIM + lane * 4) = v;
}

// ---------------- layernorm (in-place safe): y = LN(h)*scale + bias ----------------
__global__ void ln_kernel(float* __restrict__ hy, const float* __restrict__ scale,
                          const float* __restrict__ bias) {
    int row = blockIdx.x * 4 + (threadIdx.x >> 6);
    int lane = threadIdx.x & 63;
    if (row >= N_NODES) return;
    float4 v = *(const float4*)(hy + (size_t)row * DIM + lane * 4);
    float s = v.x + v.y + v.z + v.w;
    #pragma unroll
    for (int off = 32; off > 0; off >>= 1) s += __shfl_xor(s, off, 64);
    float mu = s * (1.0f / DIM);
    float d0 = v.x - mu, d1 = v.y - mu, d2 = v.z - mu, d3 = v.w - mu;
    float q = d0 * d0 + d1 * d1 + d2 * d2 + d3 * d3;
    #pragma unroll
    for (int off = 32; off > 0; off >>= 1) q += __shfl_xor(q, off, 64);
    float r = rsqrtf(q * (1.0f / DIM) + LN_EPS);
    int d = lane * 4;
    float4 sc = *(const float4*)(scale + d);
    float4 bi = *(const float4*)(bias + d);
    float4 o;
    o.x = d0 * r * sc.x + bi.x;
    o.y = d1 * r * sc.y + bi.y;
    o.z = d2 * r * sc.z + bi.z;
    o.w = d3 * r * sc.w + bi.w;
    *(float4*)(hy + (size_t)row * DIM + d) = o;
}

// ---------------- single edge pass (softmax is shift-invariant; msg in [1e-7,~6]
// so exp(msg) is safe): w=exp(msg), denom += w, agg += msg*w ----------
__device__ __forceinline__ float msg_val(float yv, float a, float wv, float bv) {
    return fmaxf(yv + a * wv + bv, 0.0f) + GEN_EPS;
}

__global__ void edge_acc_kernel(const int* __restrict__ ei, const float* __restrict__ ea,
                                const float* __restrict__ y, const float* __restrict__ wlw,
                                const float* __restrict__ wlb,
                                float* __restrict__ denom, float* __restrict__ agg) {
    int t = blockIdx.x * 256 + threadIdx.x;
    int e = t >> 6, lane = t & 63;
    if (e >= N_EDGES) return;
    int src = ei[e];
    int dst = ei[N_EDGES + e];
    float a = ea[e];
    int d = lane * 4;
    float4 yv = *(const float4*)(y + (size_t)src * DIM + d);
    float4 wv = *(const float4*)(wlw + d);
    float4 bv = *(const float4*)(wlb + d);
    float g0 = msg_val(yv.x, a, wv.x, bv.x);
    float g1 = msg_val(yv.y, a, wv.y, bv.y);
    float g2 = msg_val(yv.z, a, wv.z, bv.z);
    float g3 = msg_val(yv.w, a, wv.w, bv.w);
    float w0 = expf(g0);
    float w1 = expf(g1);
    float w2 = expf(g2);
    float w3 = expf(g3);
    float* dp = denom + (size_t)dst * DIM + d;
    float* ap = agg + (size_t)dst * DIM + d;
    atomicAdd(dp + 0, w0); atomicAdd(ap + 0, g0 * w0);
    atomicAdd(dp + 1, w1); atomicAdd(ap + 1, g1 * w1);
    atomicAdd(dp + 2, w2); atomicAdd(ap + 2, g2 * w2);
    atomicAdd(dp + 3, w3); atomicAdd(ap + 3, g3 * w3);
}

// ---------------- finalize (in-place into agg): A = agg/max(denom,1e-16) + y ----------------
__global__ void finalize_kernel(float* __restrict__ agg, const float* __restrict__ denom,
                                const float* __restrict__ y) {
    int t = blockIdx.x * 256 + threadIdx.x;
    size_t idx = (size_t)t * 4;
    if (idx >= (size_t)N_NODES * DIM) return;
    float4 av = *(const float4*)(agg + idx);
    float4 dv = *(const float4*)(denom + idx);
    float4 yv = *(const float4*)(y + idx);
    float4 o;
    o.x = av.x / fmaxf(dv.x, 1e-16f) + yv.x;
    o.y = av.y / fmaxf(dv.y, 1e-16f) + yv.y;
    o.z = av.z / fmaxf(dv.z, 1e-16f) + yv.z;
    o.w = av.w / fmaxf(dv.w, 1e-16f) + yv.w;
    *(float4*)(agg + idx) = o;
}

// ---------------- tiled GEMM: C = act(A@W + bias), A:MxK, W:KxN ----------------
// ACT: 0=none, 1=relu, 2=gelu(exact)
template <int ACT>
__global__ __launch_bounds__(256) void gemm_kernel(const float* __restrict__ A,
                                                   const float* __restrict__ W,
                                                   const float* __restrict__ bias,
                                                   float* __restrict__ C,
                                                   int M, int K, int Nc) {
    __shared__ float As[16][64];
    __shared__ float Bs[16][64];
    int tid = threadIdx.x;
    int tx = tid & 15;   // n dir
    int ty = tid >> 4;   // m dir
    int m0 = blockIdx.x * 64;
    int n0 = blockIdx.y * 64;
    float acc[4][4] = {};
    for (int k0 = 0; k0 < K; k0 += 16) {
        {
            int idx = tid * 4;
            int r = idx >> 4;
            int c = idx & 15;
            int gm = m0 + r;
            float4 v = make_float4(0.f, 0.f, 0.f, 0.f);
            if (gm < M) v = *(const float4*)(A + (size_t)gm * K + k0 + c);
            As[c + 0][r] = v.x; As[c + 1][r] = v.y; As[c + 2][r] = v.z; As[c + 3][r] = v.w;
        }
        {
            int idx = tid * 4;
            int r = idx >> 6;
            int c = idx & 63;
            int gn = n0 + c;
            float4 v = make_float4(0.f, 0.f, 0.f, 0.f);
            if (gn + 3 < Nc) {
                v = *(const float4*)(W + (size_t)(k0 + r) * Nc + gn);
            } else {
                float tmp[4] = {0.f, 0.f, 0.f, 0.f};
                for (int j = 0; j < 4; j++)
                    if (gn + j < Nc) tmp[j] = W[(size_t)(k0 + r) * Nc + gn + j];
                v = make_float4(tmp[0], tmp[1], tmp[2], tmp[3]);
            }
            Bs[r][c + 0] = v.x; Bs[r][c + 1] = v.y; Bs[r][c + 2] = v.z; Bs[r][c + 3] = v.w;
        }
        __syncthreads();
        #pragma unroll
        for (int k = 0; k < 16; k++) {
            float av[4], bv[4];
            #pragma unroll
            for (int i = 0; i < 4; i++) av[i] = As[k][ty * 4 + i];
            #pragma unroll
            for (int j = 0; j < 4; j++) bv[j] = Bs[k][tx * 4 + j];
            #pragma unroll
            for (int i = 0; i < 4; i++)
                #pragma unroll
                for (int j = 0; j < 4; j++) acc[i][j] += av[i] * bv[j];
        }
        __syncthreads();
    }
    #pragma unroll
    for (int i = 0; i < 4; i++) {
        int gm = m0 + ty * 4 + i;
        if (gm >= M) continue;
        #pragma unroll
        for (int j = 0; j < 4; j++) {
            int gn = n0 + tx * 4 + j;
            if (gn >= Nc) continue;
            float v = acc[i][j] + bias[gn];
            if (ACT == 1) v = fmaxf(v, 0.0f);
            else if (ACT == 2) v = 0.5f * v * (1.0f + erff(v * 0.70710678118f));
            C[(size_t)gm * Nc + gn] = v;
        }
    }
}

// ---------------- pooling: outs[batch[n], layer*D + d] += h[n,d] ----------------
__global__ void pool_kernel(const float* __restrict__ h, const int* __restrict__ batch,
                            float* __restrict__ outs, int layer) {
    int t = blockIdx.x * 256 + threadIdx.x;
    int n = t >> 6, lane = t & 63;
    if (n >= N_NODES) return;
    int b = batch[n];
    float4 v = *(const float4*)(h + (size_t)n * DIM + lane * 4);
    float* o = outs + (size_t)b * (N_LAYERS * DIM) + layer * DIM + lane * 4;
    atomicAdd(o + 0, v.x);
    atomicAdd(o + 1, v.y);
    atomicAdd(o + 2, v.z);
    atomicAdd(o + 3, v.w);
}

// ---------------- final: out[m] = z3[m,:] . w3 + b3 ----------------
__global__ void final_kernel(const float* __restrict__ z, const float* __restrict__ w,
                             const float* __restrict__ b, float* __restrict__ out) {
    int m = blockIdx.x * 64 + threadIdx.x;
    if (m >= N_BATCH) return;
    float s = 0.f;
    for (int k = 0; k < 192; k++) s += z[(size_t)m * 192 + k] * w[k];
    out[m] = s + b[0];
}

// ---------------- diagnostic sentinel: ws too small ----------------
__global__ void ws_sentinel_kernel(float* __restrict__ out) {
    int t = blockIdx.x * 256 + threadIdx.x;
    if (t < N_BATCH) out[t] = 1.0e6f;
}

extern "C" void kernel_launch(void* const* d_in, const int* in_sizes, int n_in,
                              void* d_out, int out_size, void* d_ws, size_t ws_size,
                              hipStream_t stream) {
    const int*   x        = (const int*)d_in[0];
    const int*   ei       = (const int*)d_in[1];
    const float* ea       = (const float*)d_in[2];
    const int*   batch    = (const int*)d_in[3];
    const float* node_emb = (const float*)d_in[4];
    const float* ln_scale = (const float*)d_in[5];
    const float* ln_bias  = (const float*)d_in[6];
    const float* wl_w     = (const float*)d_in[7];
    const float* wl_b     = (const float*)d_in[8];
    const float* conv_w   = (const float*)d_in[9];
    const float* conv_b   = (const float*)d_in[10];
    const float* ro_w0    = (const float*)d_in[11];
    const float* ro_b0    = (const float*)d_in[12];
    const float* ro_w1    = (const float*)d_in[13];
    const float* ro_b1    = (const float*)d_in[14];
    const float* ro_w2    = (const float*)d_in[15];
    const float* ro_b2    = (const float*)d_in[16];
    const float* ro_w3    = (const float*)d_in[17];
    const float* ro_b3    = (const float*)d_in[18];
    float* out = (float*)d_out;
    float* ws = (float*)d_ws;

    const size_t ND = (size_t)N_NODES * DIM;   // 15,360,000 floats
    // Layout: hy | den | agg | outs | z1 | z2 | z3
    float* hy_buf  = ws;
    float* den_buf = ws + ND;
    float* agg_buf = ws + 2 * ND;
    float* outs    = ws + 3 * ND;                       // B x 1536
    float* z1      = outs + (size_t)N_BATCH * 1536;     // B x 768
    float* z2      = z1 + (size_t)N_BATCH * 768;        // B x 384
    float* z3      = z2 + (size_t)N_BATCH * 384;        // B x 192
    size_t need = (3 * ND + (size_t)N_BATCH * (1536 + 768 + 384 + 192)) * sizeof(float);
    if (ws_size < need) {
        // distinct failure signature: absmax will be ~1e6
        ws_sentinel_kernel<<<2, 256, 0, stream>>>(out);
        return;
    }

    // zero pooled outputs
    hipMemsetAsync(outs, 0, (size_t)N_BATCH * 1536 * sizeof(float), stream);

    // h = node_emb[x]
    embed_kernel<<<(N_NODES * 64 + 255) / 256, 256, 0, stream>>>(x, node_emb, hy_buf);

    dim3 gemm_grid((N_NODES + 63) / 64, DIM / 64);
    int ln_blocks = (N_NODES + 3) / 4;
    int edge_blocks = (N_EDGES * 64 + 255) / 256;
    int elem_blocks = (int)((ND / 4 + 255) / 256);

    for (int i = 0; i < N_LAYERS; i++) {
        // zero den+agg (contiguous)
        hipMemsetAsync(den_buf, 0, 2 * ND * sizeof(float), stream);
        // hy: h -> y in place
        ln_kernel<<<ln_blocks, 256, 0, stream>>>(hy_buf, ln_scale + i * DIM, ln_bias + i * DIM);
        edge_acc_kernel<<<edge_blocks, 256, 0, stream>>>(ei, ea, hy_buf, wl_w + i * DIM,
                                                         wl_b + i * DIM, den_buf, agg_buf);
        // agg <- agg/den + y
        finalize_kernel<<<elem_blocks, 256, 0, stream>>>(agg_buf, den_buf, hy_buf);
        // hy <- relu(agg @ Wc + bc)
        gemm_kernel<1><<<gemm_grid, 256, 0, stream>>>(agg_buf, conv_w + (size_t)i * DIM * DIM,
                                                      conv_b + i * DIM, hy_buf,
                                                      N_NODES, DIM, DIM);
        pool_kernel<<<(N_NODES * 64 + 255) / 256, 256, 0, stream>>>(hy_buf, batch, outs, i);
    }

    // readout MLP
    gemm_kernel<2><<<dim3(8, 12), 256, 0, stream>>>(outs, ro_w0, ro_b0, z1, N_BATCH, 1536, 768);
    gemm_kernel<2><<<dim3(8, 6), 256, 0, stream>>>(z1, ro_w1, ro_b1, z2, N_BATCH, 768, 384);
    gemm_kernel<2><<<dim3(8, 3), 256, 0, stream>>>(z2, ro_w2, ro_b2, z3, N_BATCH, 384, 192);
    final_kernel<<<(N_BATCH + 63) / 64, 64, 0, stream>>>(z3, ro_w3, ro_b3, out);
}

// Round 3
// 3121.269 us; speedup vs baseline: 2.4661x; 2.4661x over previous
//
#include <hip/hip_runtime.h>
#include <hip/hip_bf16.h>
#include <math.h>

#define N_NODES 60000
#define N_EDGES 120000
#define N_BATCH 512
#define DIM 256
#define N_LAYERS 6
#define GEN_EPS 1e-7f
#define LN_EPS 1e-5f

// ---------------- embed: h[n] = node_emb[x[n]] ----------------
__global__ void embed_kernel(const int* __restrict__ x, const float* __restrict__ emb,
                             float* __restrict__ h) {
    int t = blockIdx.x * 256 + threadIdx.x;
    int n = t >> 6, lane = t & 63;
    if (n >= N_NODES) return;
    int type = x[n];
    float4 v = *(const float4*)(emb + (size_t)type * DIM + lane * 4);
    *(float4*)(h + (size_t)n * DIM + lane * 4) = v;
}

// ---------------- CSR build ----------------
__global__ void hist_kernel(const int* __restrict__ ei, int* __restrict__ deg) {
    int e = blockIdx.x * 256 + threadIdx.x;
    if (e >= N_EDGES) return;
    atomicAdd(&deg[ei[N_EDGES + e]], 1);
}

// single-block exclusive scan over deg[N] -> ofs[N+1], cursor[N]
__global__ void scan_kernel(const int* __restrict__ deg, int* __restrict__ ofs,
                            int* __restrict__ cursor) {
    __shared__ int part[256];
    int t = threadIdx.x;
    const int chunk = (N_NODES + 255) / 256;   // 235
    int lo = t * chunk;
    int hi = lo + chunk; if (hi > N_NODES) hi = N_NODES;
    int s = 0;
    for (int i = lo; i < hi; i++) s += deg[i];
    part[t] = s;
    __syncthreads();
    for (int off = 1; off < 256; off <<= 1) {
        int add = (t >= off) ? part[t - off] : 0;
        __syncthreads();
        part[t] += add;
        __syncthreads();
    }
    int base = (t == 0) ? 0 : part[t - 1];
    for (int i = lo; i < hi; i++) {
        ofs[i] = base;
        cursor[i] = base;
        base += deg[i];
    }
    if (t == 255) ofs[N_NODES] = base;
}

__global__ void scatter_kernel(const int* __restrict__ ei, const float* __restrict__ ea,
                               int* __restrict__ cursor, int* __restrict__ edge_src,
                               float* __restrict__ edge_a) {
    int e = blockIdx.x * 256 + threadIdx.x;
    if (e >= N_EDGES) return;
    int dst = ei[N_EDGES + e];
    int pos = atomicAdd(&cursor[dst], 1);
    edge_src[pos] = ei[e];
    edge_a[pos] = ea[e];
}

// ---------------- layernorm (in-place): y = LN(h)*scale + bias ----------------
__global__ void ln_kernel(float* __restrict__ hy, const float* __restrict__ scale,
                          const float* __restrict__ bias) {
    int row = blockIdx.x * 4 + (threadIdx.x >> 6);
    int lane = threadIdx.x & 63;
    if (row >= N_NODES) return;
    float4 v = *(const float4*)(hy + (size_t)row * DIM + lane * 4);
    float s = v.x + v.y + v.z + v.w;
    #pragma unroll
    for (int off = 32; off > 0; off >>= 1) s += __shfl_xor(s, off, 64);
    float mu = s * (1.0f / DIM);
    float d0 = v.x - mu, d1 = v.y - mu, d2 = v.z - mu, d3 = v.w - mu;
    float q = d0 * d0 + d1 * d1 + d2 * d2 + d3 * d3;
    #pragma unroll
    for (int off = 32; off > 0; off >>= 1) q += __shfl_xor(q, off, 64);
    float r = rsqrtf(q * (1.0f / DIM) + LN_EPS);
    int d = lane * 4;
    float4 sc = *(const float4*)(scale + d);
    float4 bi = *(const float4*)(bias + d);
    float4 o;
    o.x = d0 * r * sc.x + bi.x;
    o.y = d1 * r * sc.y + bi.y;
    o.z = d2 * r * sc.z + bi.z;
    o.w = d3 * r * sc.w + bi.w;
    *(float4*)(hy + (size_t)row * DIM + d) = o;
}

// ---------------- gather-aggregate: wave per dst node, registers only.
// softmax shift-invariant (msg in [1e-7,~20] -> exp safe in fp32)
// A[dst] = (sum msg*e^msg / max(sum e^msg,1e-16)) + y[dst]
__global__ void agg_kernel(const int* __restrict__ ofs, const int* __restrict__ edge_src,
                           const float* __restrict__ edge_a, const float* __restrict__ y,
                           const float* __restrict__ wlw, const float* __restrict__ wlb,
                           float* __restrict__ A) {
    int dst = blockIdx.x * 4 + (threadIdx.x >> 6);
    int lane = threadIdx.x & 63;
    if (dst >= N_NODES) return;
    int d = lane * 4;
    float4 wv = *(const float4*)(wlw + d);
    float4 bv = *(const float4*)(wlb + d);
    int lo = ofs[dst], hi = ofs[dst + 1];
    float den0 = 0.f, den1 = 0.f, den2 = 0.f, den3 = 0.f;
    float ag0 = 0.f, ag1 = 0.f, ag2 = 0.f, ag3 = 0.f;
    for (int e = lo; e < hi; e++) {
        int src = edge_src[e];      // wave-uniform broadcast
        float a = edge_a[e];
        float4 yv = *(const float4*)(y + (size_t)src * DIM + d);
        float g0 = fmaxf(yv.x + a * wv.x + bv.x, 0.0f) + GEN_EPS;
        float g1 = fmaxf(yv.y + a * wv.y + bv.y, 0.0f) + GEN_EPS;
        float g2 = fmaxf(yv.z + a * wv.z + bv.z, 0.0f) + GEN_EPS;
        float g3 = fmaxf(yv.w + a * wv.w + bv.w, 0.0f) + GEN_EPS;
        float w0 = expf(g0), w1 = expf(g1), w2 = expf(g2), w3 = expf(g3);
        den0 += w0; ag0 += g0 * w0;
        den1 += w1; ag1 += g1 * w1;
        den2 += w2; ag2 += g2 * w2;
        den3 += w3; ag3 += g3 * w3;
    }
    float4 yd = *(const float4*)(y + (size_t)dst * DIM + d);
    float4 o;
    o.x = ag0 / fmaxf(den0, 1e-16f) + yd.x;
    o.y = ag1 / fmaxf(den1, 1e-16f) + yd.y;
    o.z = ag2 / fmaxf(den2, 1e-16f) + yd.z;
    o.w = ag3 / fmaxf(den3, 1e-16f) + yd.w;
    *(float4*)(A + (size_t)dst * DIM + d) = o;
}

// ---------------- tiled GEMM: C = act(A@W + bias), A:MxK, W:KxN ----------------
// ACT: 0=none, 1=relu, 2=gelu(exact)
template <int ACT>
__global__ __launch_bounds__(256) void gemm_kernel(const float* __restrict__ A,
                                                   const float* __restrict__ W,
                                                   const float* __restrict__ bias,
                                                   float* __restrict__ C,
                                                   int M, int K, int Nc) {
    __shared__ float As[16][64];
    __shared__ float Bs[16][64];
    int tid = threadIdx.x;
    int tx = tid & 15;   // n dir
    int ty = tid >> 4;   // m dir
    int m0 = blockIdx.x * 64;
    int n0 = blockIdx.y * 64;
    float acc[4][4] = {};
    for (int k0 = 0; k0 < K; k0 += 16) {
        {
            int idx = tid * 4;
            int r = idx >> 4;
            int c = idx & 15;
            int gm = m0 + r;
            float4 v = make_float4(0.f, 0.f, 0.f, 0.f);
            if (gm < M) v = *(const float4*)(A + (size_t)gm * K + k0 + c);
            As[c + 0][r] = v.x; As[c + 1][r] = v.y; As[c + 2][r] = v.z; As[c + 3][r] = v.w;
        }
        {
            int idx = tid * 4;
            int r = idx >> 6;
            int c = idx & 63;
            int gn = n0 + c;
            float4 v = make_float4(0.f, 0.f, 0.f, 0.f);
            if (gn + 3 < Nc) {
                v = *(const float4*)(W + (size_t)(k0 + r) * Nc + gn);
            } else {
                float tmp[4] = {0.f, 0.f, 0.f, 0.f};
                for (int j = 0; j < 4; j++)
                    if (gn + j < Nc) tmp[j] = W[(size_t)(k0 + r) * Nc + gn + j];
                v = make_float4(tmp[0], tmp[1], tmp[2], tmp[3]);
            }
            Bs[r][c + 0] = v.x; Bs[r][c + 1] = v.y; Bs[r][c + 2] = v.z; Bs[r][c + 3] = v.w;
        }
        __syncthreads();
        #pragma unroll
        for (int k = 0; k < 16; k++) {
            float av[4], bv[4];
            #pragma unroll
            for (int i = 0; i < 4; i++) av[i] = As[k][ty * 4 + i];
            #pragma unroll
            for (int j = 0; j < 4; j++) bv[j] = Bs[k][tx * 4 + j];
            #pragma unroll
            for (int i = 0; i < 4; i++)
                #pragma unroll
                for (int j = 0; j < 4; j++) acc[i][j] += av[i] * bv[j];
        }
        __syncthreads();
    }
    #pragma unroll
    for (int i = 0; i < 4; i++) {
        int gm = m0 + ty * 4 + i;
        if (gm >= M) continue;
        #pragma unroll
        for (int j = 0; j < 4; j++) {
            int gn = n0 + tx * 4 + j;
            if (gn >= Nc) continue;
            float v = acc[i][j] + bias[gn];
            if (ACT == 1) v = fmaxf(v, 0.0f);
            else if (ACT == 2) v = 0.5f * v * (1.0f + erff(v * 0.70710678118f));
            C[(size_t)gm * Nc + gn] = v;
        }
    }
}

// ---------------- pooling: outs[batch[n], layer*D + d] += h[n,d] ----------------
__global__ void pool_kernel(const float* __restrict__ h, const int* __restrict__ batch,
                            float* __restrict__ outs, int layer) {
    int t = blockIdx.x * 256 + threadIdx.x;
    int n = t >> 6, lane = t & 63;
    if (n >= N_NODES) return;
    int b = batch[n];
    float4 v = *(const float4*)(h + (size_t)n * DIM + lane * 4);
    float* o = outs + (size_t)b * (N_LAYERS * DIM) + layer * DIM + lane * 4;
    atomicAdd(o + 0, v.x);
    atomicAdd(o + 1, v.y);
    atomicAdd(o + 2, v.z);
    atomicAdd(o + 3, v.w);
}

// ---------------- final: out[m] = z3[m,:] . w3 + b3 ----------------
__global__ void final_kernel(const float* __restrict__ z, const float* __restrict__ w,
                             const float* __restrict__ b, float* __restrict__ out) {
    int m = blockIdx.x * 64 + threadIdx.x;
    if (m >= N_BATCH) return;
    float s = 0.f;
    for (int k = 0; k < 192; k++) s += z[(size_t)m * 192 + k] * w[k];
    out[m] = s + b[0];
}

// ---------------- diagnostic sentinel: ws too small ----------------
__global__ void ws_sentinel_kernel(float* __restrict__ out) {
    int t = blockIdx.x * 256 + threadIdx.x;
    if (t < N_BATCH) out[t] = 1.0e6f;
}

extern "C" void kernel_launch(void* const* d_in, const int* in_sizes, int n_in,
                              void* d_out, int out_size, void* d_ws, size_t ws_size,
                              hipStream_t stream) {
    const int*   x        = (const int*)d_in[0];
    const int*   ei       = (const int*)d_in[1];
    const float* ea       = (const float*)d_in[2];
    const int*   batch    = (const int*)d_in[3];
    const float* node_emb = (const float*)d_in[4];
    const float* ln_scale = (const float*)d_in[5];
    const float* ln_bias  = (const float*)d_in[6];
    const float* wl_w     = (const float*)d_in[7];
    const float* wl_b     = (const float*)d_in[8];
    const float* conv_w   = (const float*)d_in[9];
    const float* conv_b   = (const float*)d_in[10];
    const float* ro_w0    = (const float*)d_in[11];
    const float* ro_b0    = (const float*)d_in[12];
    const float* ro_w1    = (const float*)d_in[13];
    const float* ro_b1    = (const float*)d_in[14];
    const float* ro_w2    = (const float*)d_in[15];
    const float* ro_b2    = (const float*)d_in[16];
    const float* ro_w3    = (const float*)d_in[17];
    const float* ro_b3    = (const float*)d_in[18];
    float* out = (float*)d_out;
    float* ws = (float*)d_ws;

    const size_t ND = (size_t)N_NODES * DIM;   // 15,360,000 floats
    // floats first (16B-aligned), ints last
    float* hy_buf = ws;                                  // N x D
    float* A_buf  = ws + ND;                             // N x D
    float* outs   = ws + 2 * ND;                         // B x 1536
    float* z1     = outs + (size_t)N_BATCH * 1536;       // B x 768
    float* z2     = z1 + (size_t)N_BATCH * 768;          // B x 384
    float* z3     = z2 + (size_t)N_BATCH * 384;          // B x 192
    float* edge_a = z3 + (size_t)N_BATCH * 192;          // E
    int* deg      = (int*)(edge_a + N_EDGES);            // N (also cursor)
    int* ofs      = deg + N_NODES;                       // N+1
    int* cursor   = ofs + N_NODES + 1;                   // N
    int* edge_src = cursor + N_NODES;                    // E
    size_t need = ((size_t)(edge_src + N_EDGES) - (size_t)ws);
    if (ws_size < need) {
        ws_sentinel_kernel<<<2, 256, 0, stream>>>(out);
        return;
    }

    int eb = (N_EDGES + 255) / 256;

    // ---- CSR build (once per call) ----
    hipMemsetAsync(deg, 0, N_NODES * sizeof(int), stream);
    hist_kernel<<<eb, 256, 0, stream>>>(ei, deg);
    scan_kernel<<<1, 256, 0, stream>>>(deg, ofs, cursor);
    scatter_kernel<<<eb, 256, 0, stream>>>(ei, ea, cursor, edge_src, edge_a);

    // zero pooled outputs
    hipMemsetAsync(outs, 0, (size_t)N_BATCH * 1536 * sizeof(float), stream);

    // h = node_emb[x]
    embed_kernel<<<(N_NODES * 64 + 255) / 256, 256, 0, stream>>>(x, node_emb, hy_buf);

    dim3 gemm_grid((N_NODES + 63) / 64, DIM / 64);
    int row_blocks = (N_NODES + 3) / 4;

    for (int i = 0; i < N_LAYERS; i++) {
        // hy: h -> y in place
        ln_kernel<<<row_blocks, 256, 0, stream>>>(hy_buf, ln_scale + i * DIM, ln_bias + i * DIM);
        // A = softmax-agg(y) + y   (registers only, no atomics)
        agg_kernel<<<row_blocks, 256, 0, stream>>>(ofs, edge_src, edge_a, hy_buf,
                                                   wl_w + i * DIM, wl_b + i * DIM, A_buf);
        // hy <- relu(A @ Wc + bc)
        gemm_kernel<1><<<gemm_grid, 256, 0, stream>>>(A_buf, conv_w + (size_t)i * DIM * DIM,
                                                      conv_b + i * DIM, hy_buf,
                                                      N_NODES, DIM, DIM);
        pool_kernel<<<(N_NODES * 64 + 255) / 256, 256, 0, stream>>>(hy_buf, batch, outs, i);
    }

    // readout MLP
    gemm_kernel<2><<<dim3(8, 12), 256, 0, stream>>>(outs, ro_w0, ro_b0, z1, N_BATCH, 1536, 768);
    gemm_kernel<2><<<dim3(8, 6), 256, 0, stream>>>(z1, ro_w1, ro_b1, z2, N_BATCH, 768, 384);
    gemm_kernel<2><<<dim3(8, 3), 256, 0, stream>>>(z2, ro_w2, ro_b2, z3, N_BATCH, 384, 192);
    final_kernel<<<(N_BATCH + 63) / 64, 64, 0, stream>>>(z3, ro_w3, ro_b3, out);
}

// Round 4
// 1053.531 us; speedup vs baseline: 7.3061x; 2.9627x over previous
//
#include <hip/hip_runtime.h>
#include <hip/hip_bf16.h>
#include <math.h>

#define N_NODES 60000
#define N_EDGES 120000
#define N_BATCH 512
#define DIM 256
#define N_LAYERS 6
#define GEN_EPS 1e-7f
#define LN_EPS 1e-5f

typedef __attribute__((ext_vector_type(8))) short bf16x8;
typedef __attribute__((ext_vector_type(4))) float f32x4;

__device__ __forceinline__ unsigned short f2bf(float f) {
    unsigned u = __float_as_uint(f);
    u = (u + 0x7fffu + ((u >> 16) & 1u)) >> 16;
    return (unsigned short)u;
}

// ---------------- embed: h[n] = node_emb[x[n]] ----------------
__global__ void embed_kernel(const int* __restrict__ x, const float* __restrict__ emb,
                             float* __restrict__ h) {
    int t = blockIdx.x * 256 + threadIdx.x;
    int n = t >> 6, lane = t & 63;
    if (n >= N_NODES) return;
    int type = x[n];
    float4 v = *(const float4*)(emb + (size_t)type * DIM + lane * 4);
    *(float4*)(h + (size_t)n * DIM + lane * 4) = v;
}

// ---------------- CSR build ----------------
__global__ void hist_kernel(const int* __restrict__ ei, int* __restrict__ deg) {
    int e = blockIdx.x * 256 + threadIdx.x;
    if (e >= N_EDGES) return;
    atomicAdd(&deg[ei[N_EDGES + e]], 1);
}

__global__ void scan_kernel(const int* __restrict__ deg, int* __restrict__ ofs,
                            int* __restrict__ cursor) {
    __shared__ int part[256];
    int t = threadIdx.x;
    const int chunk = (N_NODES + 255) / 256;
    int lo = t * chunk;
    int hi = lo + chunk; if (hi > N_NODES) hi = N_NODES;
    int s = 0;
    for (int i = lo; i < hi; i++) s += deg[i];
    part[t] = s;
    __syncthreads();
    for (int off = 1; off < 256; off <<= 1) {
        int add = (t >= off) ? part[t - off] : 0;
        __syncthreads();
        part[t] += add;
        __syncthreads();
    }
    int base = (t == 0) ? 0 : part[t - 1];
    for (int i = lo; i < hi; i++) {
        ofs[i] = base;
        cursor[i] = base;
        base += deg[i];
    }
    if (t == 255) ofs[N_NODES] = base;
}

__global__ void scatter_kernel(const int* __restrict__ ei, const float* __restrict__ ea,
                               int* __restrict__ cursor, int* __restrict__ edge_src,
                               float* __restrict__ edge_a) {
    int e = blockIdx.x * 256 + threadIdx.x;
    if (e >= N_EDGES) return;
    int dst = ei[N_EDGES + e];
    int pos = atomicAdd(&cursor[dst], 1);
    edge_src[pos] = ei[e];
    edge_a[pos] = ea[e];
}

// ---------------- batch segment offsets (batch sorted): bofs[b] = lower_bound(batch, b)
__global__ void bofs_kernel(const int* __restrict__ batch, int* __restrict__ bofs) {
    int b = blockIdx.x * 256 + threadIdx.x;
    if (b > N_BATCH) return;
    int lo = 0, hi = N_NODES;
    while (lo < hi) {
        int mid = (lo + hi) >> 1;
        if (batch[mid] < b) lo = mid + 1; else hi = mid;
    }
    bofs[b] = lo;
}

// ---------------- layernorm (in-place): y = LN(h)*scale + bias ----------------
__global__ void ln_kernel(float* __restrict__ hy, const float* __restrict__ scale,
                          const float* __restrict__ bias) {
    int row = blockIdx.x * 4 + (threadIdx.x >> 6);
    int lane = threadIdx.x & 63;
    if (row >= N_NODES) return;
    float4 v = *(const float4*)(hy + (size_t)row * DIM + lane * 4);
    float s = v.x + v.y + v.z + v.w;
    #pragma unroll
    for (int off = 32; off > 0; off >>= 1) s += __shfl_xor(s, off, 64);
    float mu = s * (1.0f / DIM);
    float d0 = v.x - mu, d1 = v.y - mu, d2 = v.z - mu, d3 = v.w - mu;
    float q = d0 * d0 + d1 * d1 + d2 * d2 + d3 * d3;
    #pragma unroll
    for (int off = 32; off > 0; off >>= 1) q += __shfl_xor(q, off, 64);
    float r = rsqrtf(q * (1.0f / DIM) + LN_EPS);
    int d = lane * 4;
    float4 sc = *(const float4*)(scale + d);
    float4 bi = *(const float4*)(bias + d);
    float4 o;
    o.x = d0 * r * sc.x + bi.x;
    o.y = d1 * r * sc.y + bi.y;
    o.z = d2 * r * sc.z + bi.z;
    o.w = d3 * r * sc.w + bi.w;
    *(float4*)(hy + (size_t)row * DIM + d) = o;
}

// ---------------- gather-aggregate -> bf16 A.  A = agg/den + y ----------------
__global__ void agg_kernel(const int* __restrict__ ofs, const int* __restrict__ edge_src,
                           const float* __restrict__ edge_a, const float* __restrict__ y,
                           const float* __restrict__ wlw, const float* __restrict__ wlb,
                           unsigned short* __restrict__ A) {
    int dst = blockIdx.x * 4 + (threadIdx.x >> 6);
    int lane = threadIdx.x & 63;
    if (dst >= N_NODES) return;
    int d = lane * 4;
    float4 wv = *(const float4*)(wlw + d);
    float4 bv = *(const float4*)(wlb + d);
    int lo = ofs[dst], hi = ofs[dst + 1];
    float den0 = 0.f, den1 = 0.f, den2 = 0.f, den3 = 0.f;
    float ag0 = 0.f, ag1 = 0.f, ag2 = 0.f, ag3 = 0.f;
    for (int e = lo; e < hi; e++) {
        int src = edge_src[e];
        float a = edge_a[e];
        float4 yv = *(const float4*)(y + (size_t)src * DIM + d);
        float g0 = fmaxf(yv.x + a * wv.x + bv.x, 0.0f) + GEN_EPS;
        float g1 = fmaxf(yv.y + a * wv.y + bv.y, 0.0f) + GEN_EPS;
        float g2 = fmaxf(yv.z + a * wv.z + bv.z, 0.0f) + GEN_EPS;
        float g3 = fmaxf(yv.w + a * wv.w + bv.w, 0.0f) + GEN_EPS;
        float w0 = expf(g0), w1 = expf(g1), w2 = expf(g2), w3 = expf(g3);
        den0 += w0; ag0 += g0 * w0;
        den1 += w1; ag1 += g1 * w1;
        den2 += w2; ag2 += g2 * w2;
        den3 += w3; ag3 += g3 * w3;
    }
    float4 yd = *(const float4*)(y + (size_t)dst * DIM + d);
    float o0 = ag0 / fmaxf(den0, 1e-16f) + yd.x;
    float o1 = ag1 / fmaxf(den1, 1e-16f) + yd.y;
    float o2 = ag2 / fmaxf(den2, 1e-16f) + yd.z;
    float o3 = ag3 / fmaxf(den3, 1e-16f) + yd.w;
    ushort4 o;
    o.x = f2bf(o0); o.y = f2bf(o1); o.z = f2bf(o2); o.w = f2bf(o3);
    *(ushort4*)(A + (size_t)dst * DIM + d) = o;
}

// ---------------- transpose + bf16 conv weights: WT[l][n][k] = bf16(W[l][k][n]) ----
__global__ void wt_kernel(const float* __restrict__ w, unsigned short* __restrict__ wt) {
    int idx = blockIdx.x * 256 + threadIdx.x;
    if (idx >= N_LAYERS * DIM * DIM) return;
    int l = idx >> 16;
    int rem = idx & 0xFFFF;
    int n = rem >> 8;
    int k = rem & 0xFF;
    wt[idx] = f2bf(w[(size_t)l * DIM * DIM + (size_t)k * DIM + n]);
}

// ---------------- MFMA conv GEMM: C = relu(A @ W + b), A: M x 256 bf16, WT: 256 x 256 bf16 (n-major)
__global__ __launch_bounds__(256) void mfma_gemm_kernel(const unsigned short* __restrict__ A,
                                                        const unsigned short* __restrict__ WT,
                                                        const float* __restrict__ bias,
                                                        float* __restrict__ C, int M) {
    int lane = threadIdx.x & 63;
    int wave = threadIdx.x >> 6;
    int wr = wave >> 1, wc = wave & 1;
    int m_base = blockIdx.x * 128 + wr * 64;
    int n_base = wc * 128;
    int frow = lane & 15;
    int kp = (lane >> 4) * 8;

    f32x4 acc[4][8];
    #pragma unroll
    for (int i = 0; i < 4; i++)
        #pragma unroll
        for (int j = 0; j < 8; j++) acc[i][j] = (f32x4){0.f, 0.f, 0.f, 0.f};

    const bf16x8 zero8 = {0, 0, 0, 0, 0, 0, 0, 0};
    for (int k0 = 0; k0 < DIM; k0 += 32) {
        bf16x8 a[4], b[8];
        #pragma unroll
        for (int i = 0; i < 4; i++) {
            int gm = m_base + i * 16 + frow;
            a[i] = (gm < M) ? *(const bf16x8*)(A + (size_t)gm * DIM + k0 + kp) : zero8;
        }
        #pragma unroll
        for (int j = 0; j < 8; j++) {
            int gn = n_base + j * 16 + frow;
            b[j] = *(const bf16x8*)(WT + (size_t)gn * DIM + k0 + kp);
        }
        #pragma unroll
        for (int i = 0; i < 4; i++)
            #pragma unroll
            for (int j = 0; j < 8; j++)
                acc[i][j] = __builtin_amdgcn_mfma_f32_16x16x32_bf16(a[i], b[j], acc[i][j], 0, 0, 0);
    }

    int ccol = lane & 15;
    int crow = (lane >> 4) * 4;
    #pragma unroll
    for (int i = 0; i < 4; i++) {
        #pragma unroll
        for (int j = 0; j < 8; j++) {
            int gn = n_base + j * 16 + ccol;
            float bb = bias[gn];
            #pragma unroll
            for (int r = 0; r < 4; r++) {
                int gm = m_base + i * 16 + crow + r;
                if (gm < M) {
                    float v = acc[i][j][r] + bb;
                    C[(size_t)gm * DIM + gn] = fmaxf(v, 0.0f);
                }
            }
        }
    }
}

// ---------------- gather pooling: outs[b, layer*D + d] = sum over batch segment ----
__global__ __launch_bounds__(256) void pool_kernel(const float* __restrict__ h,
                                                   const int* __restrict__ bofs,
                                                   float* __restrict__ outs, int layer) {
    __shared__ float red[4][DIM];
    int b = blockIdx.x;
    int wave = threadIdx.x >> 6, lane = threadIdx.x & 63;
    int lo = bofs[b], hi = bofs[b + 1];
    float4 s = make_float4(0.f, 0.f, 0.f, 0.f);
    for (int n = lo + wave; n < hi; n += 4) {
        float4 v = *(const float4*)(h + (size_t)n * DIM + lane * 4);
        s.x += v.x; s.y += v.y; s.z += v.z; s.w += v.w;
    }
    *(float4*)(&red[wave][lane * 4]) = s;
    __syncthreads();
    int t = threadIdx.x;
    float val = red[0][t] + red[1][t] + red[2][t] + red[3][t];
    outs[(size_t)b * (N_LAYERS * DIM) + layer * DIM + t] = val;
}

// ---------------- tiled fp32 GEMM (readout): C = act(A@W + bias) ----------------
template <int ACT>
__global__ __launch_bounds__(256) void gemm_kernel(const float* __restrict__ A,
                                                   const float* __restrict__ W,
                                                   const float* __restrict__ bias,
                                                   float* __restrict__ C,
                                                   int M, int K, int Nc) {
    __shared__ float As[16][64];
    __shared__ float Bs[16][64];
    int tid = threadIdx.x;
    int tx = tid & 15;
    int ty = tid >> 4;
    int m0 = blockIdx.x * 64;
    int n0 = blockIdx.y * 64;
    float acc[4][4] = {};
    for (int k0 = 0; k0 < K; k0 += 16) {
        {
            int idx = tid * 4;
            int r = idx >> 4;
            int c = idx & 15;
            int gm = m0 + r;
            float4 v = make_float4(0.f, 0.f, 0.f, 0.f);
            if (gm < M) v = *(const float4*)(A + (size_t)gm * K + k0 + c);
            As[c + 0][r] = v.x; As[c + 1][r] = v.y; As[c + 2][r] = v.z; As[c + 3][r] = v.w;
        }
        {
            int idx = tid * 4;
            int r = idx >> 6;
            int c = idx & 63;
            int gn = n0 + c;
            float4 v = make_float4(0.f, 0.f, 0.f, 0.f);
            if (gn + 3 < Nc) {
                v = *(const float4*)(W + (size_t)(k0 + r) * Nc + gn);
            } else {
                float tmp[4] = {0.f, 0.f, 0.f, 0.f};
                for (int j = 0; j < 4; j++)
                    if (gn + j < Nc) tmp[j] = W[(size_t)(k0 + r) * Nc + gn + j];
                v = make_float4(tmp[0], tmp[1], tmp[2], tmp[3]);
            }
            Bs[r][c + 0] = v.x; Bs[r][c + 1] = v.y; Bs[r][c + 2] = v.z; Bs[r][c + 3] = v.w;
        }
        __syncthreads();
        #pragma unroll
        for (int k = 0; k < 16; k++) {
            float av[4], bv[4];
            #pragma unroll
            for (int i = 0; i < 4; i++) av[i] = As[k][ty * 4 + i];
            #pragma unroll
            for (int j = 0; j < 4; j++) bv[j] = Bs[k][tx * 4 + j];
            #pragma unroll
            for (int i = 0; i < 4; i++)
                #pragma unroll
                for (int j = 0; j < 4; j++) acc[i][j] += av[i] * bv[j];
        }
        __syncthreads();
    }
    #pragma unroll
    for (int i = 0; i < 4; i++) {
        int gm = m0 + ty * 4 + i;
        if (gm >= M) continue;
        #pragma unroll
        for (int j = 0; j < 4; j++) {
            int gn = n0 + tx * 4 + j;
            if (gn >= Nc) continue;
            float v = acc[i][j] + bias[gn];
            if (ACT == 1) v = fmaxf(v, 0.0f);
            else if (ACT == 2) v = 0.5f * v * (1.0f + erff(v * 0.70710678118f));
            C[(size_t)gm * Nc + gn] = v;
        }
    }
}

// ---------------- final: out[m] = z3[m,:] . w3 + b3 ----------------
__global__ void final_kernel(const float* __restrict__ z, const float* __restrict__ w,
                             const float* __restrict__ b, float* __restrict__ out) {
    int m = blockIdx.x * 64 + threadIdx.x;
    if (m >= N_BATCH) return;
    float s = 0.f;
    for (int k = 0; k < 192; k++) s += z[(size_t)m * 192 + k] * w[k];
    out[m] = s + b[0];
}

__global__ void ws_sentinel_kernel(float* __restrict__ out) {
    int t = blockIdx.x * 256 + threadIdx.x;
    if (t < N_BATCH) out[t] = 1.0e6f;
}

extern "C" void kernel_launch(void* const* d_in, const int* in_sizes, int n_in,
                              void* d_out, int out_size, void* d_ws, size_t ws_size,
                              hipStream_t stream) {
    const int*   x        = (const int*)d_in[0];
    const int*   ei       = (const int*)d_in[1];
    const float* ea       = (const float*)d_in[2];
    const int*   batch    = (const int*)d_in[3];
    const float* node_emb = (const float*)d_in[4];
    const float* ln_scale = (const float*)d_in[5];
    const float* ln_bias  = (const float*)d_in[6];
    const float* wl_w     = (const float*)d_in[7];
    const float* wl_b     = (const float*)d_in[8];
    const float* conv_w   = (const float*)d_in[9];
    const float* conv_b   = (const float*)d_in[10];
    const float* ro_w0    = (const float*)d_in[11];
    const float* ro_b0    = (const float*)d_in[12];
    const float* ro_w1    = (const float*)d_in[13];
    const float* ro_b1    = (const float*)d_in[14];
    const float* ro_w2    = (const float*)d_in[15];
    const float* ro_b2    = (const float*)d_in[16];
    const float* ro_w3    = (const float*)d_in[17];
    const float* ro_b3    = (const float*)d_in[18];
    float* out = (float*)d_out;

    const size_t ND = (size_t)N_NODES * DIM;
    char* p = (char*)d_ws;
    float* hy_buf = (float*)p;            p += ND * sizeof(float);
    unsigned short* A_buf = (unsigned short*)p; p += ND * sizeof(unsigned short);
    float* outs = (float*)p;              p += (size_t)N_BATCH * 1536 * sizeof(float);
    float* z1 = (float*)p;                p += (size_t)N_BATCH * 768 * sizeof(float);
    float* z2 = (float*)p;                p += (size_t)N_BATCH * 384 * sizeof(float);
    float* z3 = (float*)p;                p += (size_t)N_BATCH * 192 * sizeof(float);
    unsigned short* wt_buf = (unsigned short*)p; p += (size_t)N_LAYERS * DIM * DIM * sizeof(unsigned short);
    float* edge_a = (float*)p;            p += (size_t)N_EDGES * sizeof(float);
    int* deg = (int*)p;                   p += (size_t)N_NODES * sizeof(int);
    int* ofs = (int*)p;                   p += (size_t)(N_NODES + 1) * sizeof(int);
    int* cursor = (int*)p;                p += (size_t)N_NODES * sizeof(int);
    int* edge_src = (int*)p;              p += (size_t)N_EDGES * sizeof(int);
    int* bofs = (int*)p;                  p += (size_t)(N_BATCH + 1) * sizeof(int);
    size_t need = (size_t)(p - (char*)d_ws);
    if (ws_size < need) {
        ws_sentinel_kernel<<<2, 256, 0, stream>>>(out);
        return;
    }

    int eb = (N_EDGES + 255) / 256;

    // ---- one-time prep ----
    hipMemsetAsync(deg, 0, N_NODES * sizeof(int), stream);
    hist_kernel<<<eb, 256, 0, stream>>>(ei, deg);
    scan_kernel<<<1, 256, 0, stream>>>(deg, ofs, cursor);
    scatter_kernel<<<eb, 256, 0, stream>>>(ei, ea, cursor, edge_src, edge_a);
    bofs_kernel<<<3, 256, 0, stream>>>(batch, bofs);
    wt_kernel<<<(N_LAYERS * DIM * DIM + 255) / 256, 256, 0, stream>>>(conv_w, wt_buf);

    // h = node_emb[x]
    embed_kernel<<<(N_NODES * 64 + 255) / 256, 256, 0, stream>>>(x, node_emb, hy_buf);

    int row_blocks = (N_NODES + 3) / 4;
    int gemm_blocks = (N_NODES + 127) / 128;

    for (int i = 0; i < N_LAYERS; i++) {
        ln_kernel<<<row_blocks, 256, 0, stream>>>(hy_buf, ln_scale + i * DIM, ln_bias + i * DIM);
        agg_kernel<<<row_blocks, 256, 0, stream>>>(ofs, edge_src, edge_a, hy_buf,
                                                   wl_w + i * DIM, wl_b + i * DIM, A_buf);
        mfma_gemm_kernel<<<gemm_blocks, 256, 0, stream>>>(A_buf, wt_buf + (size_t)i * DIM * DIM,
                                                          conv_b + i * DIM, hy_buf, N_NODES);
        pool_kernel<<<N_BATCH, 256, 0, stream>>>(hy_buf, bofs, outs, i);
    }

    // readout MLP (fp32)
    gemm_kernel<2><<<dim3(8, 12), 256, 0, stream>>>(outs, ro_w0, ro_b0, z1, N_BATCH, 1536, 768);
    gemm_kernel<2><<<dim3(8, 6), 256, 0, stream>>>(z1, ro_w1, ro_b1, z2, N_BATCH, 768, 384);
    gemm_kernel<2><<<dim3(8, 3), 256, 0, stream>>>(z2, ro_w2, ro_b2, z3, N_BATCH, 384, 192);
    final_kernel<<<(N_BATCH + 63) / 64, 64, 0, stream>>>(z3, ro_w3, ro_b3, out);
}

// Round 5
// 922.315 us; speedup vs baseline: 8.3456x; 1.1423x over previous
//
#include <hip/hip_runtime.h>
#include <hip/hip_bf16.h>
#include <math.h>

#define N_NODES 60000
#define N_EDGES 120000
#define N_BATCH 512
#define DIM 256
#define N_LAYERS 6
#define GEN_EPS 1e-7f
#define LN_EPS 1e-5f
#define NBLK ((N_NODES + 255) / 256)   // 235

typedef __attribute__((ext_vector_type(8))) short bf16x8;
typedef __attribute__((ext_vector_type(4))) float f32x4;

__device__ __forceinline__ unsigned short f2bf(float f) {
    unsigned u = __float_as_uint(f);
    u = (u + 0x7fffu + ((u >> 16) & 1u)) >> 16;
    return (unsigned short)u;
}

// ---------------- embed: h[n] = node_emb[x[n]] ----------------
__global__ void embed_kernel(const int* __restrict__ x, const float* __restrict__ emb,
                             float* __restrict__ h) {
    int t = blockIdx.x * 256 + threadIdx.x;
    int n = t >> 6, lane = t & 63;
    if (n >= N_NODES) return;
    int type = x[n];
    float4 v = *(const float4*)(emb + (size_t)type * DIM + lane * 4);
    *(float4*)(h + (size_t)n * DIM + lane * 4) = v;
}

// ---------------- CSR build ----------------
__global__ void hist_kernel(const int* __restrict__ ei, int* __restrict__ deg) {
    int e = blockIdx.x * 256 + threadIdx.x;
    if (e >= N_EDGES) return;
    atomicAdd(&deg[ei[N_EDGES + e]], 1);
}

// 3-stage parallel exclusive scan of deg[N] -> ofs[N+1], cursor[N]
__global__ void scan1_kernel(const int* __restrict__ deg, int* __restrict__ part) {
    __shared__ int sm[256];
    int i = blockIdx.x * 256 + threadIdx.x;
    int t = threadIdx.x;
    sm[t] = (i < N_NODES) ? deg[i] : 0;
    __syncthreads();
    for (int off = 128; off > 0; off >>= 1) {
        if (t < off) sm[t] += sm[t + off];
        __syncthreads();
    }
    if (t == 0) part[blockIdx.x] = sm[0];
}

__global__ void scan2_kernel(int* __restrict__ part) {
    __shared__ int sm[256];
    int t = threadIdx.x;
    int v = (t < NBLK) ? part[t] : 0;
    sm[t] = v;
    __syncthreads();
    for (int off = 1; off < 256; off <<= 1) {
        int add = (t >= off) ? sm[t - off] : 0;
        __syncthreads();
        sm[t] += add;
        __syncthreads();
    }
    if (t < NBLK) part[t] = sm[t] - v;   // exclusive
}

__global__ void scan3_kernel(const int* __restrict__ deg, const int* __restrict__ part,
                             int* __restrict__ ofs, int* __restrict__ cursor) {
    __shared__ int sm[256];
    int i = blockIdx.x * 256 + threadIdx.x;
    int t = threadIdx.x;
    int v = (i < N_NODES) ? deg[i] : 0;
    sm[t] = v;
    __syncthreads();
    for (int off = 1; off < 256; off <<= 1) {
        int add = (t >= off) ? sm[t - off] : 0;
        __syncthreads();
        sm[t] += add;
        __syncthreads();
    }
    int excl = part[blockIdx.x] + sm[t] - v;
    if (i < N_NODES) {
        ofs[i] = excl;
        cursor[i] = excl;
        if (i == N_NODES - 1) ofs[N_NODES] = excl + v;
    }
}

__global__ void scatter_kernel(const int* __restrict__ ei, const float* __restrict__ ea,
                               int* __restrict__ cursor, int* __restrict__ edge_src,
                               float* __restrict__ edge_a) {
    int e = blockIdx.x * 256 + threadIdx.x;
    if (e >= N_EDGES) return;
    int dst = ei[N_EDGES + e];
    int pos = atomicAdd(&cursor[dst], 1);
    edge_src[pos] = ei[e];
    edge_a[pos] = ea[e];
}

// ---------------- batch segment offsets (batch sorted) ----------------
__global__ void bofs_kernel(const int* __restrict__ batch, int* __restrict__ bofs) {
    int b = blockIdx.x * 256 + threadIdx.x;
    if (b > N_BATCH) return;
    int lo = 0, hi = N_NODES;
    while (lo < hi) {
        int mid = (lo + hi) >> 1;
        if (batch[mid] < b) lo = mid + 1; else hi = mid;
    }
    bofs[b] = lo;
}

// ---------------- inline per-row LN (wave-wide, lane owns 4 cols) ----------------
__device__ __forceinline__ float4 ln_row(const float* __restrict__ row, int d,
                                         float4 sc, float4 bi) {
    float4 v = *(const float4*)(row + d);
    float s = v.x + v.y + v.z + v.w;
    #pragma unroll
    for (int off = 32; off > 0; off >>= 1) s += __shfl_xor(s, off, 64);
    float mu = s * (1.0f / DIM);
    float d0 = v.x - mu, d1 = v.y - mu, d2 = v.z - mu, d3 = v.w - mu;
    float q = d0 * d0 + d1 * d1 + d2 * d2 + d3 * d3;
    #pragma unroll
    for (int off = 32; off > 0; off >>= 1) q += __shfl_xor(q, off, 64);
    float r = rsqrtf(q * (1.0f / DIM) + LN_EPS);
    float4 o;
    o.x = d0 * r * sc.x + bi.x;
    o.y = d1 * r * sc.y + bi.y;
    o.z = d2 * r * sc.z + bi.z;
    o.w = d3 * r * sc.w + bi.w;
    return o;
}

// ---------------- fused LN + gather-aggregate -> bf16 A ----------------
// A[dst] = softmax-agg over in-edges of relu(LN(h[src])+a*wlw+wlb)+eps, + LN(h[dst])
__global__ void agg_kernel(const int* __restrict__ ofs, const int* __restrict__ edge_src,
                           const float* __restrict__ edge_a, const float* __restrict__ h,
                           const float* __restrict__ lnsc, const float* __restrict__ lnbi,
                           const float* __restrict__ wlw, const float* __restrict__ wlb,
                           unsigned short* __restrict__ A) {
    int dst = blockIdx.x * 4 + (threadIdx.x >> 6);
    int lane = threadIdx.x & 63;
    if (dst >= N_NODES) return;
    int d = lane * 4;
    float4 sc = *(const float4*)(lnsc + d);
    float4 bi = *(const float4*)(lnbi + d);
    float4 wv = *(const float4*)(wlw + d);
    float4 bv = *(const float4*)(wlb + d);
    int lo = ofs[dst], hi = ofs[dst + 1];
    float den0 = 0.f, den1 = 0.f, den2 = 0.f, den3 = 0.f;
    float ag0 = 0.f, ag1 = 0.f, ag2 = 0.f, ag3 = 0.f;
    for (int e = lo; e < hi; e++) {
        int src = edge_src[e];      // wave-uniform
        float a = edge_a[e];
        float4 ys = ln_row(h + (size_t)src * DIM, d, sc, bi);
        float g0 = fmaxf(ys.x + a * wv.x + bv.x, 0.0f) + GEN_EPS;
        float g1 = fmaxf(ys.y + a * wv.y + bv.y, 0.0f) + GEN_EPS;
        float g2 = fmaxf(ys.z + a * wv.z + bv.z, 0.0f) + GEN_EPS;
        float g3 = fmaxf(ys.w + a * wv.w + bv.w, 0.0f) + GEN_EPS;
        float w0 = expf(g0), w1 = expf(g1), w2 = expf(g2), w3 = expf(g3);
        den0 += w0; ag0 += g0 * w0;
        den1 += w1; ag1 += g1 * w1;
        den2 += w2; ag2 += g2 * w2;
        den3 += w3; ag3 += g3 * w3;
    }
    float4 yd = ln_row(h + (size_t)dst * DIM, d, sc, bi);
    float o0 = ag0 / fmaxf(den0, 1e-16f) + yd.x;
    float o1 = ag1 / fmaxf(den1, 1e-16f) + yd.y;
    float o2 = ag2 / fmaxf(den2, 1e-16f) + yd.z;
    float o3 = ag3 / fmaxf(den3, 1e-16f) + yd.w;
    ushort4 o;
    o.x = f2bf(o0); o.y = f2bf(o1); o.z = f2bf(o2); o.w = f2bf(o3);
    *(ushort4*)(A + (size_t)dst * DIM + d) = o;
}

// ---------------- transpose + bf16 conv weights: WT[l][n][k] = bf16(W[l][k][n]) ----
__global__ void wt_kernel(const float* __restrict__ w, unsigned short* __restrict__ wt) {
    int idx = blockIdx.x * 256 + threadIdx.x;
    if (idx >= N_LAYERS * DIM * DIM) return;
    int l = idx >> 16;
    int rem = idx & 0xFFFF;
    int n = rem >> 8;
    int k = rem & 0xFF;
    wt[idx] = f2bf(w[(size_t)l * DIM * DIM + (size_t)k * DIM + n]);
}

// ---------------- MFMA conv GEMM: C = relu(A @ W + b) ----------------
__global__ __launch_bounds__(256) void mfma_gemm_kernel(const unsigned short* __restrict__ A,
                                                        const unsigned short* __restrict__ WT,
                                                        const float* __restrict__ bias,
                                                        float* __restrict__ C, int M) {
    int lane = threadIdx.x & 63;
    int wave = threadIdx.x >> 6;
    int wr = wave >> 1, wc = wave & 1;
    int m_base = blockIdx.x * 128 + wr * 64;
    int n_base = wc * 128;
    int frow = lane & 15;
    int kp = (lane >> 4) * 8;

    f32x4 acc[4][8];
    #pragma unroll
    for (int i = 0; i < 4; i++)
        #pragma unroll
        for (int j = 0; j < 8; j++) acc[i][j] = (f32x4){0.f, 0.f, 0.f, 0.f};

    const bf16x8 zero8 = {0, 0, 0, 0, 0, 0, 0, 0};
    for (int k0 = 0; k0 < DIM; k0 += 32) {
        bf16x8 a[4], b[8];
        #pragma unroll
        for (int i = 0; i < 4; i++) {
            int gm = m_base + i * 16 + frow;
            a[i] = (gm < M) ? *(const bf16x8*)(A + (size_t)gm * DIM + k0 + kp) : zero8;
        }
        #pragma unroll
        for (int j = 0; j < 8; j++) {
            int gn = n_base + j * 16 + frow;
            b[j] = *(const bf16x8*)(WT + (size_t)gn * DIM + k0 + kp);
        }
        #pragma unroll
        for (int i = 0; i < 4; i++)
            #pragma unroll
            for (int j = 0; j < 8; j++)
                acc[i][j] = __builtin_amdgcn_mfma_f32_16x16x32_bf16(a[i], b[j], acc[i][j], 0, 0, 0);
    }

    int ccol = lane & 15;
    int crow = (lane >> 4) * 4;
    #pragma unroll
    for (int i = 0; i < 4; i++) {
        #pragma unroll
        for (int j = 0; j < 8; j++) {
            int gn = n_base + j * 16 + ccol;
            float bb = bias[gn];
            #pragma unroll
            for (int r = 0; r < 4; r++) {
                int gm = m_base + i * 16 + crow + r;
                if (gm < M) {
                    float v = acc[i][j][r] + bb;
                    C[(size_t)gm * DIM + gn] = fmaxf(v, 0.0f);
                }
            }
        }
    }
}

// ---------------- gather pooling ----------------
__global__ __launch_bounds__(256) void pool_kernel(const float* __restrict__ h,
                                                   const int* __restrict__ bofs,
                                                   float* __restrict__ outs, int layer) {
    __shared__ float red[4][DIM];
    int b = blockIdx.x;
    int wave = threadIdx.x >> 6, lane = threadIdx.x & 63;
    int lo = bofs[b], hi = bofs[b + 1];
    float4 s = make_float4(0.f, 0.f, 0.f, 0.f);
    for (int n = lo + wave; n < hi; n += 4) {
        float4 v = *(const float4*)(h + (size_t)n * DIM + lane * 4);
        s.x += v.x; s.y += v.y; s.z += v.z; s.w += v.w;
    }
    *(float4*)(&red[wave][lane * 4]) = s;
    __syncthreads();
    int t = threadIdx.x;
    float val = red[0][t] + red[1][t] + red[2][t] + red[3][t];
    outs[(size_t)b * (N_LAYERS * DIM) + layer * DIM + t] = val;
}

// ---------------- tiled fp32 GEMM (readout) ----------------
template <int ACT>
__global__ __launch_bounds__(256) void gemm_kernel(const float* __restrict__ A,
                                                   const float* __restrict__ W,
                                                   const float* __restrict__ bias,
                                                   float* __restrict__ C,
                                                   int M, int K, int Nc) {
    __shared__ float As[16][64];
    __shared__ float Bs[16][64];
    int tid = threadIdx.x;
    int tx = tid & 15;
    int ty = tid >> 4;
    int m0 = blockIdx.x * 64;
    int n0 = blockIdx.y * 64;
    float acc[4][4] = {};
    for (int k0 = 0; k0 < K; k0 += 16) {
        {
            int idx = tid * 4;
            int r = idx >> 4;
            int c = idx & 15;
            int gm = m0 + r;
            float4 v = make_float4(0.f, 0.f, 0.f, 0.f);
            if (gm < M) v = *(const float4*)(A + (size_t)gm * K + k0 + c);
            As[c + 0][r] = v.x; As[c + 1][r] = v.y; As[c + 2][r] = v.z; As[c + 3][r] = v.w;
        }
        {
            int idx = tid * 4;
            int r = idx >> 6;
            int c = idx & 63;
            int gn = n0 + c;
            float4 v = make_float4(0.f, 0.f, 0.f, 0.f);
            if (gn + 3 < Nc) {
                v = *(const float4*)(W + (size_t)(k0 + r) * Nc + gn);
            } else {
                float tmp[4] = {0.f, 0.f, 0.f, 0.f};
                for (int j = 0; j < 4; j++)
                    if (gn + j < Nc) tmp[j] = W[(size_t)(k0 + r) * Nc + gn + j];
                v = make_float4(tmp[0], tmp[1], tmp[2], tmp[3]);
            }
            Bs[r][c + 0] = v.x; Bs[r][c + 1] = v.y; Bs[r][c + 2] = v.z; Bs[r][c + 3] = v.w;
        }
        __syncthreads();
        #pragma unroll
        for (int k = 0; k < 16; k++) {
            float av[4], bv[4];
            #pragma unroll
            for (int i = 0; i < 4; i++) av[i] = As[k][ty * 4 + i];
            #pragma unroll
            for (int j = 0; j < 4; j++) bv[j] = Bs[k][tx * 4 + j];
            #pragma unroll
            for (int i = 0; i < 4; i++)
                #pragma unroll
                for (int j = 0; j < 4; j++) acc[i][j] += av[i] * bv[j];
        }
        __syncthreads();
    }
    #pragma unroll
    for (int i = 0; i < 4; i++) {
        int gm = m0 + ty * 4 + i;
        if (gm >= M) continue;
        #pragma unroll
        for (int j = 0; j < 4; j++) {
            int gn = n0 + tx * 4 + j;
            if (gn >= Nc) continue;
            float v = acc[i][j] + bias[gn];
            if (ACT == 1) v = fmaxf(v, 0.0f);
            else if (ACT == 2) v = 0.5f * v * (1.0f + erff(v * 0.70710678118f));
            C[(size_t)gm * Nc + gn] = v;
        }
    }
}

// ---------------- final: out[m] = z3[m,:] . w3 + b3 ----------------
__global__ void final_kernel(const float* __restrict__ z, const float* __restrict__ w,
                             const float* __restrict__ b, float* __restrict__ out) {
    int m = blockIdx.x * 64 + threadIdx.x;
    if (m >= N_BATCH) return;
    float s = 0.f;
    for (int k = 0; k < 192; k++) s += z[(size_t)m * 192 + k] * w[k];
    out[m] = s + b[0];
}

__global__ void ws_sentinel_kernel(float* __restrict__ out) {
    int t = blockIdx.x * 256 + threadIdx.x;
    if (t < N_BATCH) out[t] = 1.0e6f;
}

extern "C" void kernel_launch(void* const* d_in, const int* in_sizes, int n_in,
                              void* d_out, int out_size, void* d_ws, size_t ws_size,
                              hipStream_t stream) {
    const int*   x        = (const int*)d_in[0];
    const int*   ei       = (const int*)d_in[1];
    const float* ea       = (const float*)d_in[2];
    const int*   batch    = (const int*)d_in[3];
    const float* node_emb = (const float*)d_in[4];
    const float* ln_scale = (const float*)d_in[5];
    const float* ln_bias  = (const float*)d_in[6];
    const float* wl_w     = (const float*)d_in[7];
    const float* wl_b     = (const float*)d_in[8];
    const float* conv_w   = (const float*)d_in[9];
    const float* conv_b   = (const float*)d_in[10];
    const float* ro_w0    = (const float*)d_in[11];
    const float* ro_b0    = (const float*)d_in[12];
    const float* ro_w1    = (const float*)d_in[13];
    const float* ro_b1    = (const float*)d_in[14];
    const float* ro_w2    = (const float*)d_in[15];
    const float* ro_b2    = (const float*)d_in[16];
    const float* ro_w3    = (const float*)d_in[17];
    const float* ro_b3    = (const float*)d_in[18];
    float* out = (float*)d_out;

    const size_t ND = (size_t)N_NODES * DIM;
    char* p = (char*)d_ws;
    float* hy_buf = (float*)p;            p += ND * sizeof(float);
    unsigned short* A_buf = (unsigned short*)p; p += ND * sizeof(unsigned short);
    float* outs = (float*)p;              p += (size_t)N_BATCH * 1536 * sizeof(float);
    float* z1 = (float*)p;                p += (size_t)N_BATCH * 768 * sizeof(float);
    float* z2 = (float*)p;                p += (size_t)N_BATCH * 384 * sizeof(float);
    float* z3 = (float*)p;                p += (size_t)N_BATCH * 192 * sizeof(float);
    unsigned short* wt_buf = (unsigned short*)p; p += (size_t)N_LAYERS * DIM * DIM * sizeof(unsigned short);
    float* edge_a = (float*)p;            p += (size_t)N_EDGES * sizeof(float);
    int* deg = (int*)p;                   p += (size_t)N_NODES * sizeof(int);
    int* part = (int*)p;                  p += (size_t)NBLK * sizeof(int);
    int* ofs = (int*)p;                   p += (size_t)(N_NODES + 1) * sizeof(int);
    int* cursor = (int*)p;                p += (size_t)N_NODES * sizeof(int);
    int* edge_src = (int*)p;              p += (size_t)N_EDGES * sizeof(int);
    int* bofs = (int*)p;                  p += (size_t)(N_BATCH + 1) * sizeof(int);
    size_t need = (size_t)(p - (char*)d_ws);
    if (ws_size < need) {
        ws_sentinel_kernel<<<2, 256, 0, stream>>>(out);
        return;
    }

    int eb = (N_EDGES + 255) / 256;

    // ---- one-time prep ----
    hipMemsetAsync(deg, 0, N_NODES * sizeof(int), stream);
    hist_kernel<<<eb, 256, 0, stream>>>(ei, deg);
    scan1_kernel<<<NBLK, 256, 0, stream>>>(deg, part);
    scan2_kernel<<<1, 256, 0, stream>>>(part);
    scan3_kernel<<<NBLK, 256, 0, stream>>>(deg, part, ofs, cursor);
    scatter_kernel<<<eb, 256, 0, stream>>>(ei, ea, cursor, edge_src, edge_a);
    bofs_kernel<<<3, 256, 0, stream>>>(batch, bofs);
    wt_kernel<<<(N_LAYERS * DIM * DIM + 255) / 256, 256, 0, stream>>>(conv_w, wt_buf);

    // h = node_emb[x]
    embed_kernel<<<(N_NODES * 64 + 255) / 256, 256, 0, stream>>>(x, node_emb, hy_buf);

    int row_blocks = (N_NODES + 3) / 4;
    int gemm_blocks = (N_NODES + 127) / 128;

    for (int i = 0; i < N_LAYERS; i++) {
        // A = softmax-agg(LN(h)) + LN(h)   (LN fused, exact)
        agg_kernel<<<row_blocks, 256, 0, stream>>>(ofs, edge_src, edge_a, hy_buf,
                                                   ln_scale + i * DIM, ln_bias + i * DIM,
                                                   wl_w + i * DIM, wl_b + i * DIM, A_buf);
        mfma_gemm_kernel<<<gemm_blocks, 256, 0, stream>>>(A_buf, wt_buf + (size_t)i * DIM * DIM,
                                                          conv_b + i * DIM, hy_buf, N_NODES);
        pool_kernel<<<N_BATCH, 256, 0, stream>>>(hy_buf, bofs, outs, i);
    }

    // readout MLP (fp32)
    gemm_kernel<2><<<dim3(8, 12), 256, 0, stream>>>(outs, ro_w0, ro_b0, z1, N_BATCH, 1536, 768);
    gemm_kernel<2><<<dim3(8, 6), 256, 0, stream>>>(z1, ro_w1, ro_b1, z2, N_BATCH, 768, 384);
    gemm_kernel<2><<<dim3(8, 3), 256, 0, stream>>>(z2, ro_w2, ro_b2, z3, N_BATCH, 384, 192);
    final_kernel<<<(N_BATCH + 63) / 64, 64, 0, stream>>>(z3, ro_w3, ro_b3, out);
}

// Round 7
// 921.977 us; speedup vs baseline: 8.3486x; 1.0004x over previous
//
#include <hip/hip_runtime.h>
#include <hip/hip_bf16.h>
#include <math.h>

#define N_NODES 60000
#define N_EDGES 120000
#define N_BATCH 512
#define DIM 256
#define N_LAYERS 6
#define GEN_EPS 1e-7f
#define LN_EPS 1e-5f
#define NBLK ((N_NODES + 255) / 256)   // 235

typedef __attribute__((ext_vector_type(8))) short bf16x8;
typedef __attribute__((ext_vector_type(4))) float f32x4;

__device__ __forceinline__ unsigned short f2bf(float f) {
    unsigned u = __float_as_uint(f);
    u = (u + 0x7fffu + ((u >> 16) & 1u)) >> 16;
    return (unsigned short)u;
}
__device__ __forceinline__ float bf2f(unsigned short u) {
    return __uint_as_float((unsigned)u << 16);
}

// ---------------- embed: h[n] = node_emb[x[n]] ----------------
__global__ void embed_kernel(const int* __restrict__ x, const float* __restrict__ emb,
                             float* __restrict__ h) {
    int t = blockIdx.x * 256 + threadIdx.x;
    int n = t >> 6, lane = t & 63;
    if (n >= N_NODES) return;
    int type = x[n];
    float4 v = *(const float4*)(emb + (size_t)type * DIM + lane * 4);
    *(float4*)(h + (size_t)n * DIM + lane * 4) = v;
}

// ---------------- CSR build ----------------
__global__ void hist_kernel(const int* __restrict__ ei, int* __restrict__ deg) {
    int e = blockIdx.x * 256 + threadIdx.x;
    if (e >= N_EDGES) return;
    atomicAdd(&deg[ei[N_EDGES + e]], 1);
}

__global__ void scan1_kernel(const int* __restrict__ deg, int* __restrict__ part) {
    __shared__ int sm[256];
    int i = blockIdx.x * 256 + threadIdx.x;
    int t = threadIdx.x;
    sm[t] = (i < N_NODES) ? deg[i] : 0;
    __syncthreads();
    for (int off = 128; off > 0; off >>= 1) {
        if (t < off) sm[t] += sm[t + off];
        __syncthreads();
    }
    if (t == 0) part[blockIdx.x] = sm[0];
}

__global__ void scan2_kernel(int* __restrict__ part) {
    __shared__ int sm[256];
    int t = threadIdx.x;
    int v = (t < NBLK) ? part[t] : 0;
    sm[t] = v;
    __syncthreads();
    for (int off = 1; off < 256; off <<= 1) {
        int add = (t >= off) ? sm[t - off] : 0;
        __syncthreads();
        sm[t] += add;
        __syncthreads();
    }
    if (t < NBLK) part[t] = sm[t] - v;   // exclusive
}

__global__ void scan3_kernel(const int* __restrict__ deg, const int* __restrict__ part,
                             int* __restrict__ ofs, int* __restrict__ cursor) {
    __shared__ int sm[256];
    int i = blockIdx.x * 256 + threadIdx.x;
    int t = threadIdx.x;
    int v = (i < N_NODES) ? deg[i] : 0;
    sm[t] = v;
    __syncthreads();
    for (int off = 1; off < 256; off <<= 1) {
        int add = (t >= off) ? sm[t - off] : 0;
        __syncthreads();
        sm[t] += add;
        __syncthreads();
    }
    int excl = part[blockIdx.x] + sm[t] - v;
    if (i < N_NODES) {
        ofs[i] = excl;
        cursor[i] = excl;
        if (i == N_NODES - 1) ofs[N_NODES] = excl + v;
    }
}

__global__ void scatter_kernel(const int* __restrict__ ei, const float* __restrict__ ea,
                               int* __restrict__ cursor, int* __restrict__ edge_src,
                               float* __restrict__ edge_a) {
    int e = blockIdx.x * 256 + threadIdx.x;
    if (e >= N_EDGES) return;
    int dst = ei[N_EDGES + e];
    int pos = atomicAdd(&cursor[dst], 1);
    edge_src[pos] = ei[e];
    edge_a[pos] = ea[e];
}

// ---------------- batch segment offsets (batch sorted) ----------------
__global__ void bofs_kernel(const int* __restrict__ batch, int* __restrict__ bofs) {
    int b = blockIdx.x * 256 + threadIdx.x;
    if (b > N_BATCH) return;
    int lo = 0, hi = N_NODES;
    while (lo < hi) {
        int mid = (lo + hi) >> 1;
        if (batch[mid] < b) lo = mid + 1; else hi = mid;
    }
    bofs[b] = lo;
}

// ---------------- inline per-row LN (wave-wide, lane owns 4 cols) ----------------
__device__ __forceinline__ float4 ln_row(const float* __restrict__ row, int d,
                                         float4 sc, float4 bi) {
    float4 v = *(const float4*)(row + d);
    float s = v.x + v.y + v.z + v.w;
    #pragma unroll
    for (int off = 32; off > 0; off >>= 1) s += __shfl_xor(s, off, 64);
    float mu = s * (1.0f / DIM);
    float d0 = v.x - mu, d1 = v.y - mu, d2 = v.z - mu, d3 = v.w - mu;
    float q = d0 * d0 + d1 * d1 + d2 * d2 + d3 * d3;
    #pragma unroll
    for (int off = 32; off > 0; off >>= 1) q += __shfl_xor(q, off, 64);
    float r = rsqrtf(q * (1.0f / DIM) + LN_EPS);
    float4 o;
    o.x = d0 * r * sc.x + bi.x;
    o.y = d1 * r * sc.y + bi.y;
    o.z = d2 * r * sc.z + bi.z;
    o.w = d3 * r * sc.w + bi.w;
    return o;
}

// ---------------- fused LN + gather-aggregate -> bf16 A ----------------
__global__ void agg_kernel(const int* __restrict__ ofs, const int* __restrict__ edge_src,
                           const float* __restrict__ edge_a, const float* __restrict__ h,
                           const float* __restrict__ lnsc, const float* __restrict__ lnbi,
                           const float* __restrict__ wlw, const float* __restrict__ wlb,
                           unsigned short* __restrict__ A) {
    int dst = blockIdx.x * 4 + (threadIdx.x >> 6);
    int lane = threadIdx.x & 63;
    if (dst >= N_NODES) return;
    int d = lane * 4;
    float4 sc = *(const float4*)(lnsc + d);
    float4 bi = *(const float4*)(lnbi + d);
    float4 wv = *(const float4*)(wlw + d);
    float4 bv = *(const float4*)(wlb + d);
    int lo = ofs[dst], hi = ofs[dst + 1];
    float den0 = 0.f, den1 = 0.f, den2 = 0.f, den3 = 0.f;
    float ag0 = 0.f, ag1 = 0.f, ag2 = 0.f, ag3 = 0.f;
    for (int e = lo; e < hi; e++) {
        int src = edge_src[e];
        float a = edge_a[e];
        float4 ys = ln_row(h + (size_t)src * DIM, d, sc, bi);
        float g0 = fmaxf(ys.x + a * wv.x + bv.x, 0.0f) + GEN_EPS;
        float g1 = fmaxf(ys.y + a * wv.y + bv.y, 0.0f) + GEN_EPS;
        float g2 = fmaxf(ys.z + a * wv.z + bv.z, 0.0f) + GEN_EPS;
        float g3 = fmaxf(ys.w + a * wv.w + bv.w, 0.0f) + GEN_EPS;
        float w0 = expf(g0), w1 = expf(g1), w2 = expf(g2), w3 = expf(g3);
        den0 += w0; ag0 += g0 * w0;
        den1 += w1; ag1 += g1 * w1;
        den2 += w2; ag2 += g2 * w2;
        den3 += w3; ag3 += g3 * w3;
    }
    float4 yd = ln_row(h + (size_t)dst * DIM, d, sc, bi);
    float o0 = ag0 / fmaxf(den0, 1e-16f) + yd.x;
    float o1 = ag1 / fmaxf(den1, 1e-16f) + yd.y;
    float o2 = ag2 / fmaxf(den2, 1e-16f) + yd.z;
    float o3 = ag3 / fmaxf(den3, 1e-16f) + yd.w;
    ushort4 o;
    o.x = f2bf(o0); o.y = f2bf(o1); o.z = f2bf(o2); o.w = f2bf(o3);
    *(ushort4*)(A + (size_t)dst * DIM + d) = o;
}

// ---------------- transpose + bf16 conv weights: WT[l][n][k] = bf16(W[l][k][n]) ----
__global__ void wt_kernel(const float* __restrict__ w, unsigned short* __restrict__ wt) {
    int idx = blockIdx.x * 256 + threadIdx.x;
    if (idx >= N_LAYERS * DIM * DIM) return;
    int l = idx >> 16;
    int rem = idx & 0xFFFF;
    int n = rem >> 8;
    int k = rem & 0xFF;
    wt[idx] = f2bf(w[(size_t)l * DIM * DIM + (size_t)k * DIM + n]);
}

// generic transpose+convert hi/lo: wt_hi/lo[n*K + k] from w[k*N + n], w: K x N
__global__ void wt_ro_kernel(const float* __restrict__ w, unsigned short* __restrict__ wth,
                             unsigned short* __restrict__ wtl, int K, int N) {
    int idx = blockIdx.x * 256 + threadIdx.x;
    if (idx >= K * N) return;
    int n = idx / K;
    int k = idx - n * K;
    float v = w[(size_t)k * N + n];
    unsigned short h = f2bf(v);
    wth[idx] = h;
    wtl[idx] = f2bf(v - bf2f(h));
}

// ---------------- MFMA conv GEMM: C = relu(A @ W + b) ----------------
__global__ __launch_bounds__(256) void mfma_gemm_kernel(const unsigned short* __restrict__ A,
                                                        const unsigned short* __restrict__ WT,
                                                        const float* __restrict__ bias,
                                                        float* __restrict__ C, int M) {
    int lane = threadIdx.x & 63;
    int wave = threadIdx.x >> 6;
    int wr = wave >> 1, wc = wave & 1;
    int m_base = blockIdx.x * 128 + wr * 64;
    int n_base = wc * 128;
    int frow = lane & 15;
    int kp = (lane >> 4) * 8;

    f32x4 acc[4][8];
    #pragma unroll
    for (int i = 0; i < 4; i++)
        #pragma unroll
        for (int j = 0; j < 8; j++) acc[i][j] = (f32x4){0.f, 0.f, 0.f, 0.f};

    const bf16x8 zero8 = {0, 0, 0, 0, 0, 0, 0, 0};
    for (int k0 = 0; k0 < DIM; k0 += 32) {
        bf16x8 a[4], b[8];
        #pragma unroll
        for (int i = 0; i < 4; i++) {
            int gm = m_base + i * 16 + frow;
            a[i] = (gm < M) ? *(const bf16x8*)(A + (size_t)gm * DIM + k0 + kp) : zero8;
        }
        #pragma unroll
        for (int j = 0; j < 8; j++) {
            int gn = n_base + j * 16 + frow;
            b[j] = *(const bf16x8*)(WT + (size_t)gn * DIM + k0 + kp);
        }
        #pragma unroll
        for (int i = 0; i < 4; i++)
            #pragma unroll
            for (int j = 0; j < 8; j++)
                acc[i][j] = __builtin_amdgcn_mfma_f32_16x16x32_bf16(a[i], b[j], acc[i][j], 0, 0, 0);
    }

    int ccol = lane & 15;
    int crow = (lane >> 4) * 4;
    #pragma unroll
    for (int i = 0; i < 4; i++) {
        #pragma unroll
        for (int j = 0; j < 8; j++) {
            int gn = n_base + j * 16 + ccol;
            float bb = bias[gn];
            #pragma unroll
            for (int r = 0; r < 4; r++) {
                int gm = m_base + i * 16 + crow + r;
                if (gm < M) {
                    float v = acc[i][j][r] + bb;
                    C[(size_t)gm * DIM + gn] = fmaxf(v, 0.0f);
                }
            }
        }
    }
}

// ---------------- MFMA readout GEMM (hi/lo split, ~fp32 accurate) ----------------
// C(fp32) = gelu(A @ W + b); A: M x K fp32 (M=512), WT hi/lo: N x K bf16 (n-major)
// acc += ah*bh + ah*bl + al*bh   (drops only al*bl ~ 2^-18 relative)
__global__ __launch_bounds__(256) void mfma_ro_kernel(const float* __restrict__ A,
                                                      const unsigned short* __restrict__ WTh,
                                                      const unsigned short* __restrict__ WTl,
                                                      const float* __restrict__ bias,
                                                      float* __restrict__ C,
                                                      int K, int Nc) {
    int lane = threadIdx.x & 63;
    int wave = threadIdx.x >> 6;
    int wr = wave >> 1, wc = wave & 1;
    int m_base = blockIdx.x * 128 + wr * 64;
    int n_base = blockIdx.y * 128 + wc * 64;
    int frow = lane & 15;
    int kp = (lane >> 4) * 8;

    f32x4 acc[4][4];
    #pragma unroll
    for (int i = 0; i < 4; i++)
        #pragma unroll
        for (int j = 0; j < 4; j++) acc[i][j] = (f32x4){0.f, 0.f, 0.f, 0.f};

    const bf16x8 zero8 = {0, 0, 0, 0, 0, 0, 0, 0};
    for (int k0 = 0; k0 < K; k0 += 32) {
        bf16x8 ah[4], al[4], bh[4], bl[4];
        #pragma unroll
        for (int i = 0; i < 4; i++) {
            int gm = m_base + i * 16 + frow;
            const float* ap = A + (size_t)gm * K + k0 + kp;
            float4 v0 = *(const float4*)(ap);
            float4 v1 = *(const float4*)(ap + 4);
            float vv[8] = {v0.x, v0.y, v0.z, v0.w, v1.x, v1.y, v1.z, v1.w};
            #pragma unroll
            for (int q = 0; q < 8; q++) {
                unsigned short hh = f2bf(vv[q]);
                ah[i][q] = (short)hh;
                al[i][q] = (short)f2bf(vv[q] - bf2f(hh));
            }
        }
        #pragma unroll
        for (int j = 0; j < 4; j++) {
            int gn = n_base + j * 16 + frow;
            bh[j] = (gn < Nc) ? *(const bf16x8*)(WTh + (size_t)gn * K + k0 + kp) : zero8;
            bl[j] = (gn < Nc) ? *(const bf16x8*)(WTl + (size_t)gn * K + k0 + kp) : zero8;
        }
        #pragma unroll
        for (int i = 0; i < 4; i++)
            #pragma unroll
            for (int j = 0; j < 4; j++) {
                acc[i][j] = __builtin_amdgcn_mfma_f32_16x16x32_bf16(ah[i], bh[j], acc[i][j], 0, 0, 0);
                acc[i][j] = __builtin_amdgcn_mfma_f32_16x16x32_bf16(ah[i], bl[j], acc[i][j], 0, 0, 0);
                acc[i][j] = __builtin_amdgcn_mfma_f32_16x16x32_bf16(al[i], bh[j], acc[i][j], 0, 0, 0);
            }
    }

    int ccol = lane & 15;
    int crow = (lane >> 4) * 4;
    #pragma unroll
    for (int i = 0; i < 4; i++) {
        #pragma unroll
        for (int j = 0; j < 4; j++) {
            int gn = n_base + j * 16 + ccol;
            if (gn >= Nc) continue;
            float bb = bias[gn];
            #pragma unroll
            for (int r = 0; r < 4; r++) {
                int gm = m_base + i * 16 + crow + r;
                float v = acc[i][j][r] + bb;
                v = 0.5f * v * (1.0f + erff(v * 0.70710678118f));
                C[(size_t)gm * Nc + gn] = v;
            }
        }
    }
}

// ---------------- gather pooling -> fp32 outs ----------------
__global__ __launch_bounds__(256) void pool_kernel(const float* __restrict__ h,
                                                   const int* __restrict__ bofs,
                                                   float* __restrict__ outs, int layer) {
    __shared__ float red[4][DIM];
    int b = blockIdx.x;
    int wave = threadIdx.x >> 6, lane = threadIdx.x & 63;
    int lo = bofs[b], hi = bofs[b + 1];
    float4 s = make_float4(0.f, 0.f, 0.f, 0.f);
    for (int n = lo + wave; n < hi; n += 4) {
        float4 v = *(const float4*)(h + (size_t)n * DIM + lane * 4);
        s.x += v.x; s.y += v.y; s.z += v.z; s.w += v.w;
    }
    *(float4*)(&red[wave][lane * 4]) = s;
    __syncthreads();
    int t = threadIdx.x;
    float val = red[0][t] + red[1][t] + red[2][t] + red[3][t];
    outs[(size_t)b * (N_LAYERS * DIM) + layer * DIM + t] = val;
}

// ---------------- final: out[m] = z3[m,:] . w3 + b3 ----------------
__global__ void final_kernel(const float* __restrict__ z, const float* __restrict__ w,
                             const float* __restrict__ b, float* __restrict__ out) {
    int m = blockIdx.x * 64 + threadIdx.x;
    if (m >= N_BATCH) return;
    float s = 0.f;
    for (int k = 0; k < 192; k++) s += z[(size_t)m * 192 + k] * w[k];
    out[m] = s + b[0];
}

__global__ void ws_sentinel_kernel(float* __restrict__ out) {
    int t = blockIdx.x * 256 + threadIdx.x;
    if (t < N_BATCH) out[t] = 1.0e6f;
}

extern "C" void kernel_launch(void* const* d_in, const int* in_sizes, int n_in,
                              void* d_out, int out_size, void* d_ws, size_t ws_size,
                              hipStream_t stream) {
    const int*   x        = (const int*)d_in[0];
    const int*   ei       = (const int*)d_in[1];
    const float* ea       = (const float*)d_in[2];
    const int*   batch    = (const int*)d_in[3];
    const float* node_emb = (const float*)d_in[4];
    const float* ln_scale = (const float*)d_in[5];
    const float* ln_bias  = (const float*)d_in[6];
    const float* wl_w     = (const float*)d_in[7];
    const float* wl_b     = (const float*)d_in[8];
    const float* conv_w   = (const float*)d_in[9];
    const float* conv_b   = (const float*)d_in[10];
    const float* ro_w0    = (const float*)d_in[11];
    const float* ro_b0    = (const float*)d_in[12];
    const float* ro_w1    = (const float*)d_in[13];
    const float* ro_b1    = (const float*)d_in[14];
    const float* ro_w2    = (const float*)d_in[15];
    const float* ro_b2    = (const float*)d_in[16];
    const float* ro_w3    = (const float*)d_in[17];
    const float* ro_b3    = (const float*)d_in[18];
    float* out = (float*)d_out;

    const size_t ND = (size_t)N_NODES * DIM;
    char* p = (char*)d_ws;
    float* hy_buf = (float*)p;                   p += ND * sizeof(float);
    float* outs = (float*)p;                     p += (size_t)N_BATCH * 1536 * sizeof(float);
    float* z1 = (float*)p;                       p += (size_t)N_BATCH * 768 * sizeof(float);
    float* z2 = (float*)p;                       p += (size_t)N_BATCH * 384 * sizeof(float);
    float* z3 = (float*)p;                       p += (size_t)N_BATCH * 192 * sizeof(float);
    unsigned short* A_buf = (unsigned short*)p;  p += ND * sizeof(unsigned short);
    unsigned short* wt_buf = (unsigned short*)p; p += (size_t)N_LAYERS * DIM * DIM * sizeof(unsigned short);
    unsigned short* wt0h = (unsigned short*)p;   p += (size_t)768 * 1536 * sizeof(unsigned short);
    unsigned short* wt0l = (unsigned short*)p;   p += (size_t)768 * 1536 * sizeof(unsigned short);
    unsigned short* wt1h = (unsigned short*)p;   p += (size_t)384 * 768 * sizeof(unsigned short);
    unsigned short* wt1l = (unsigned short*)p;   p += (size_t)384 * 768 * sizeof(unsigned short);
    unsigned short* wt2h = (unsigned short*)p;   p += (size_t)192 * 384 * sizeof(unsigned short);
    unsigned short* wt2l = (unsigned short*)p;   p += (size_t)192 * 384 * sizeof(unsigned short);
    float* edge_a = (float*)p;                   p += (size_t)N_EDGES * sizeof(float);
    int* deg = (int*)p;                          p += (size_t)N_NODES * sizeof(int);
    int* part = (int*)p;                         p += (size_t)NBLK * sizeof(int);
    int* ofs = (int*)p;                          p += (size_t)(N_NODES + 1) * sizeof(int);
    int* cursor = (int*)p;                       p += (size_t)N_NODES * sizeof(int);
    int* edge_src = (int*)p;                     p += (size_t)N_EDGES * sizeof(int);
    int* bofs = (int*)p;                         p += (size_t)(N_BATCH + 1) * sizeof(int);
    size_t need = (size_t)(p - (char*)d_ws);
    if (ws_size < need) {
        ws_sentinel_kernel<<<2, 256, 0, stream>>>(out);
        return;
    }

    int eb = (N_EDGES + 255) / 256;

    // ---- one-time prep ----
    hipMemsetAsync(deg, 0, N_NODES * sizeof(int), stream);
    hist_kernel<<<eb, 256, 0, stream>>>(ei, deg);
    scan1_kernel<<<NBLK, 256, 0, stream>>>(deg, part);
    scan2_kernel<<<1, 256, 0, stream>>>(part);
    scan3_kernel<<<NBLK, 256, 0, stream>>>(deg, part, ofs, cursor);
    scatter_kernel<<<eb, 256, 0, stream>>>(ei, ea, cursor, edge_src, edge_a);
    bofs_kernel<<<3, 256, 0, stream>>>(batch, bofs);
    wt_kernel<<<(N_LAYERS * DIM * DIM + 255) / 256, 256, 0, stream>>>(conv_w, wt_buf);
    wt_ro_kernel<<<(1536 * 768 + 255) / 256, 256, 0, stream>>>(ro_w0, wt0h, wt0l, 1536, 768);
    wt_ro_kernel<<<(768 * 384 + 255) / 256, 256, 0, stream>>>(ro_w1, wt1h, wt1l, 768, 384);
    wt_ro_kernel<<<(384 * 192 + 255) / 256, 256, 0, stream>>>(ro_w2, wt2h, wt2l, 384, 192);

    // h = node_emb[x]
    embed_kernel<<<(N_NODES * 64 + 255) / 256, 256, 0, stream>>>(x, node_emb, hy_buf);

    int row_blocks = (N_NODES + 3) / 4;
    int gemm_blocks = (N_NODES + 127) / 128;

    for (int i = 0; i < N_LAYERS; i++) {
        agg_kernel<<<row_blocks, 256, 0, stream>>>(ofs, edge_src, edge_a, hy_buf,
                                                   ln_scale + i * DIM, ln_bias + i * DIM,
                                                   wl_w + i * DIM, wl_b + i * DIM, A_buf);
        mfma_gemm_kernel<<<gemm_blocks, 256, 0, stream>>>(A_buf, wt_buf + (size_t)i * DIM * DIM,
                                                          conv_b + i * DIM, hy_buf, N_NODES);
        pool_kernel<<<N_BATCH, 256, 0, stream>>>(hy_buf, bofs, outs, i);
    }

    // readout MLP (hi/lo bf16 MFMA == fp32 accuracy, exact GELU, fp32 storage)
    mfma_ro_kernel<<<dim3(4, 6), 256, 0, stream>>>(outs, wt0h, wt0l, ro_b0, z1, 1536, 768);
    mfma_ro_kernel<<<dim3(4, 3), 256, 0, stream>>>(z1, wt1h, wt1l, ro_b1, z2, 768, 384);
    mfma_ro_kernel<<<dim3(4, 2), 256, 0, stream>>>(z2, wt2h, wt2l, ro_b2, z3, 384, 192);
    final_kernel<<<(N_BATCH + 63) / 64, 64, 0, stream>>>(z3, ro_w3, ro_b3, out);
}

// Round 8
// 800.183 us; speedup vs baseline: 9.6193x; 1.1522x over previous
//
#include <hip/hip_runtime.h>
#include <hip/hip_bf16.h>
#include <math.h>

#define N_NODES 60000
#define N_EDGES 120000
#define N_BATCH 512
#define DIM 256
#define N_LAYERS 6
#define GEN_EPS 1e-7f
#define LN_EPS 1e-5f
#define NBLK ((N_NODES + 255) / 256)   // 235

typedef __attribute__((ext_vector_type(8))) short bf16x8;
typedef __attribute__((ext_vector_type(4))) float f32x4;

__device__ __forceinline__ unsigned short f2bf(float f) {
    unsigned u = __float_as_uint(f);
    u = (u + 0x7fffu + ((u >> 16) & 1u)) >> 16;
    return (unsigned short)u;
}
__device__ __forceinline__ float bf2f(unsigned short u) {
    return __uint_as_float((unsigned)u << 16);
}

// ---------------- embed: h[n] = bf16(node_emb[x[n]]) ----------------
__global__ void embed_kernel(const int* __restrict__ x, const float* __restrict__ emb,
                             unsigned short* __restrict__ h) {
    int t = blockIdx.x * 256 + threadIdx.x;
    int n = t >> 6, lane = t & 63;
    if (n >= N_NODES) return;
    int type = x[n];
    float4 v = *(const float4*)(emb + (size_t)type * DIM + lane * 4);
    ushort4 o;
    o.x = f2bf(v.x); o.y = f2bf(v.y); o.z = f2bf(v.z); o.w = f2bf(v.w);
    *(ushort4*)(h + (size_t)n * DIM + lane * 4) = o;
}

// ---------------- CSR build ----------------
__global__ void hist_kernel(const int* __restrict__ ei, int* __restrict__ deg) {
    int e = blockIdx.x * 256 + threadIdx.x;
    if (e >= N_EDGES) return;
    atomicAdd(&deg[ei[N_EDGES + e]], 1);
}

__global__ void scan1_kernel(const int* __restrict__ deg, int* __restrict__ part) {
    __shared__ int sm[256];
    int i = blockIdx.x * 256 + threadIdx.x;
    int t = threadIdx.x;
    sm[t] = (i < N_NODES) ? deg[i] : 0;
    __syncthreads();
    for (int off = 128; off > 0; off >>= 1) {
        if (t < off) sm[t] += sm[t + off];
        __syncthreads();
    }
    if (t == 0) part[blockIdx.x] = sm[0];
}

__global__ void scan2_kernel(int* __restrict__ part) {
    __shared__ int sm[256];
    int t = threadIdx.x;
    int v = (t < NBLK) ? part[t] : 0;
    sm[t] = v;
    __syncthreads();
    for (int off = 1; off < 256; off <<= 1) {
        int add = (t >= off) ? sm[t - off] : 0;
        __syncthreads();
        sm[t] += add;
        __syncthreads();
    }
    if (t < NBLK) part[t] = sm[t] - v;   // exclusive
}

__global__ void scan3_kernel(const int* __restrict__ deg, const int* __restrict__ part,
                             int* __restrict__ ofs, int* __restrict__ cursor) {
    __shared__ int sm[256];
    int i = blockIdx.x * 256 + threadIdx.x;
    int t = threadIdx.x;
    int v = (i < N_NODES) ? deg[i] : 0;
    sm[t] = v;
    __syncthreads();
    for (int off = 1; off < 256; off <<= 1) {
        int add = (t >= off) ? sm[t - off] : 0;
        __syncthreads();
        sm[t] += add;
        __syncthreads();
    }
    int excl = part[blockIdx.x] + sm[t] - v;
    if (i < N_NODES) {
        ofs[i] = excl;
        cursor[i] = excl;
        if (i == N_NODES - 1) ofs[N_NODES] = excl + v;
    }
}

__global__ void scatter_kernel(const int* __restrict__ ei, const float* __restrict__ ea,
                               int* __restrict__ cursor, int* __restrict__ edge_src,
                               float* __restrict__ edge_a) {
    int e = blockIdx.x * 256 + threadIdx.x;
    if (e >= N_EDGES) return;
    int dst = ei[N_EDGES + e];
    int pos = atomicAdd(&cursor[dst], 1);
    edge_src[pos] = ei[e];
    edge_a[pos] = ea[e];
}

// ---------------- batch segment offsets (batch sorted) ----------------
__global__ void bofs_kernel(const int* __restrict__ batch, int* __restrict__ bofs) {
    int b = blockIdx.x * 256 + threadIdx.x;
    if (b > N_BATCH) return;
    int lo = 0, hi = N_NODES;
    while (lo < hi) {
        int mid = (lo + hi) >> 1;
        if (batch[mid] < b) lo = mid + 1; else hi = mid;
    }
    bofs[b] = lo;
}

// ---------------- inline per-row LN on bf16 row (wave-wide, lane owns 4 cols) ----
__device__ __forceinline__ float4 ln_row(const unsigned short* __restrict__ row, int d,
                                         float4 sc, float4 bi) {
    ushort4 u = *(const ushort4*)(row + d);
    float4 v;
    v.x = bf2f(u.x); v.y = bf2f(u.y); v.z = bf2f(u.z); v.w = bf2f(u.w);
    float s = v.x + v.y + v.z + v.w;
    #pragma unroll
    for (int off = 32; off > 0; off >>= 1) s += __shfl_xor(s, off, 64);
    float mu = s * (1.0f / DIM);
    float d0 = v.x - mu, d1 = v.y - mu, d2 = v.z - mu, d3 = v.w - mu;
    float q = d0 * d0 + d1 * d1 + d2 * d2 + d3 * d3;
    #pragma unroll
    for (int off = 32; off > 0; off >>= 1) q += __shfl_xor(q, off, 64);
    float r = rsqrtf(q * (1.0f / DIM) + LN_EPS);
    float4 o;
    o.x = d0 * r * sc.x + bi.x;
    o.y = d1 * r * sc.y + bi.y;
    o.z = d2 * r * sc.z + bi.z;
    o.w = d3 * r * sc.w + bi.w;
    return o;
}

// ---------------- fused LN + gather-aggregate -> bf16 A ----------------
__global__ void agg_kernel(const int* __restrict__ ofs, const int* __restrict__ edge_src,
                           const float* __restrict__ edge_a, const unsigned short* __restrict__ h,
                           const float* __restrict__ lnsc, const float* __restrict__ lnbi,
                           const float* __restrict__ wlw, const float* __restrict__ wlb,
                           unsigned short* __restrict__ A) {
    int dst = blockIdx.x * 4 + (threadIdx.x >> 6);
    int lane = threadIdx.x & 63;
    if (dst >= N_NODES) return;
    int d = lane * 4;
    float4 sc = *(const float4*)(lnsc + d);
    float4 bi = *(const float4*)(lnbi + d);
    float4 wv = *(const float4*)(wlw + d);
    float4 bv = *(const float4*)(wlb + d);
    int lo = ofs[dst], hi = ofs[dst + 1];
    float den0 = 0.f, den1 = 0.f, den2 = 0.f, den3 = 0.f;
    float ag0 = 0.f, ag1 = 0.f, ag2 = 0.f, ag3 = 0.f;
    for (int e = lo; e < hi; e++) {
        int src = edge_src[e];
        float a = edge_a[e];
        float4 ys = ln_row(h + (size_t)src * DIM, d, sc, bi);
        float g0 = fmaxf(ys.x + a * wv.x + bv.x, 0.0f) + GEN_EPS;
        float g1 = fmaxf(ys.y + a * wv.y + bv.y, 0.0f) + GEN_EPS;
        float g2 = fmaxf(ys.z + a * wv.z + bv.z, 0.0f) + GEN_EPS;
        float g3 = fmaxf(ys.w + a * wv.w + bv.w, 0.0f) + GEN_EPS;
        float w0 = expf(g0), w1 = expf(g1), w2 = expf(g2), w3 = expf(g3);
        den0 += w0; ag0 += g0 * w0;
        den1 += w1; ag1 += g1 * w1;
        den2 += w2; ag2 += g2 * w2;
        den3 += w3; ag3 += g3 * w3;
    }
    float4 yd = ln_row(h + (size_t)dst * DIM, d, sc, bi);
    float o0 = ag0 / fmaxf(den0, 1e-16f) + yd.x;
    float o1 = ag1 / fmaxf(den1, 1e-16f) + yd.y;
    float o2 = ag2 / fmaxf(den2, 1e-16f) + yd.z;
    float o3 = ag3 / fmaxf(den3, 1e-16f) + yd.w;
    ushort4 o;
    o.x = f2bf(o0); o.y = f2bf(o1); o.z = f2bf(o2); o.w = f2bf(o3);
    *(ushort4*)(A + (size_t)dst * DIM + d) = o;
}

// ---------------- transpose + bf16 conv weights: WT[l][n][k] = bf16(W[l][k][n]) ----
__global__ void wt_kernel(const float* __restrict__ w, unsigned short* __restrict__ wt) {
    int idx = blockIdx.x * 256 + threadIdx.x;
    if (idx >= N_LAYERS * DIM * DIM) return;
    int l = idx >> 16;
    int rem = idx & 0xFFFF;
    int n = rem >> 8;
    int k = rem & 0xFF;
    wt[idx] = f2bf(w[(size_t)l * DIM * DIM + (size_t)k * DIM + n]);
}

// LDS-tiled transpose + hi/lo split: wth/wtl[n*K+k] from w[k*N+n]; K,N % 32 == 0
__global__ __launch_bounds__(256) void wt_ro_t_kernel(const float* __restrict__ w,
                                                      unsigned short* __restrict__ wth,
                                                      unsigned short* __restrict__ wtl,
                                                      int K, int N) {
    __shared__ float tile[32][33];
    int k0 = blockIdx.x * 32, n0 = blockIdx.y * 32;
    int tx = threadIdx.x & 31, ty = threadIdx.x >> 5;   // 8 rows per pass
    #pragma unroll
    for (int i = 0; i < 4; i++)
        tile[ty + 8 * i][tx] = w[(size_t)(k0 + ty + 8 * i) * N + n0 + tx];
    __syncthreads();
    #pragma unroll
    for (int i = 0; i < 4; i++) {
        int n = ty + 8 * i;
        float v = tile[tx][n];               // w[k0+tx][n0+n]
        unsigned short hh = f2bf(v);
        size_t idx = (size_t)(n0 + n) * K + k0 + tx;
        wth[idx] = hh;
        wtl[idx] = f2bf(v - bf2f(hh));
    }
}

// ---------------- MFMA conv GEMM: h(bf16) = relu(A @ W + b) ----------------
__global__ __launch_bounds__(256) void mfma_gemm_kernel(const unsigned short* __restrict__ A,
                                                        const unsigned short* __restrict__ WT,
                                                        const float* __restrict__ bias,
                                                        unsigned short* __restrict__ C, int M) {
    int lane = threadIdx.x & 63;
    int wave = threadIdx.x >> 6;
    int wr = wave >> 1, wc = wave & 1;
    int m_base = blockIdx.x * 128 + wr * 64;
    int n_base = wc * 128;
    int frow = lane & 15;
    int kp = (lane >> 4) * 8;

    f32x4 acc[4][8];
    #pragma unroll
    for (int i = 0; i < 4; i++)
        #pragma unroll
        for (int j = 0; j < 8; j++) acc[i][j] = (f32x4){0.f, 0.f, 0.f, 0.f};

    const bf16x8 zero8 = {0, 0, 0, 0, 0, 0, 0, 0};
    for (int k0 = 0; k0 < DIM; k0 += 32) {
        bf16x8 a[4], b[8];
        #pragma unroll
        for (int i = 0; i < 4; i++) {
            int gm = m_base + i * 16 + frow;
            a[i] = (gm < M) ? *(const bf16x8*)(A + (size_t)gm * DIM + k0 + kp) : zero8;
        }
        #pragma unroll
        for (int j = 0; j < 8; j++) {
            int gn = n_base + j * 16 + frow;
            b[j] = *(const bf16x8*)(WT + (size_t)gn * DIM + k0 + kp);
        }
        #pragma unroll
        for (int i = 0; i < 4; i++)
            #pragma unroll
            for (int j = 0; j < 8; j++)
                acc[i][j] = __builtin_amdgcn_mfma_f32_16x16x32_bf16(a[i], b[j], acc[i][j], 0, 0, 0);
    }

    int ccol = lane & 15;
    int crow = (lane >> 4) * 4;
    #pragma unroll
    for (int i = 0; i < 4; i++) {
        #pragma unroll
        for (int j = 0; j < 8; j++) {
            int gn = n_base + j * 16 + ccol;
            float bb = bias[gn];
            #pragma unroll
            for (int r = 0; r < 4; r++) {
                int gm = m_base + i * 16 + crow + r;
                if (gm < M) {
                    float v = acc[i][j][r] + bb;
                    C[(size_t)gm * DIM + gn] = f2bf(fmaxf(v, 0.0f));
                }
            }
        }
    }
}

// ---------------- MFMA readout GEMM: wave-per-16x16-tile, hi/lo operands ----------
// C(hi/lo bf16) = gelu(A @ W + b); A hi/lo: M x K bf16, WT hi/lo: N x K bf16
// grid (M/64, N/16), 256 thr = 4 waves, wave w: rows bx*64+w*16
__global__ __launch_bounds__(256) void mfma_ro_kernel(const unsigned short* __restrict__ Ah,
                                                      const unsigned short* __restrict__ Al,
                                                      const unsigned short* __restrict__ WTh,
                                                      const unsigned short* __restrict__ WTl,
                                                      const float* __restrict__ bias,
                                                      unsigned short* __restrict__ Ch,
                                                      unsigned short* __restrict__ Cl,
                                                      int K, int Nc) {
    int lane = threadIdx.x & 63;
    int wave = threadIdx.x >> 6;
    int m0 = blockIdx.x * 64 + wave * 16;
    int n0 = blockIdx.y * 16;
    int frow = lane & 15;
    int kp = (lane >> 4) * 8;

    f32x4 acc = (f32x4){0.f, 0.f, 0.f, 0.f};
    const unsigned short* aph = Ah + (size_t)(m0 + frow) * K + kp;
    const unsigned short* apl = Al + (size_t)(m0 + frow) * K + kp;
    const unsigned short* bph = WTh + (size_t)(n0 + frow) * K + kp;
    const unsigned short* bpl = WTl + (size_t)(n0 + frow) * K + kp;
    #pragma unroll 4
    for (int k0 = 0; k0 < K; k0 += 32) {
        bf16x8 ah = *(const bf16x8*)(aph + k0);
        bf16x8 al = *(const bf16x8*)(apl + k0);
        bf16x8 bh = *(const bf16x8*)(bph + k0);
        bf16x8 bl = *(const bf16x8*)(bpl + k0);
        acc = __builtin_amdgcn_mfma_f32_16x16x32_bf16(ah, bh, acc, 0, 0, 0);
        acc = __builtin_amdgcn_mfma_f32_16x16x32_bf16(ah, bl, acc, 0, 0, 0);
        acc = __builtin_amdgcn_mfma_f32_16x16x32_bf16(al, bh, acc, 0, 0, 0);
    }

    int ccol = lane & 15;
    int crow = (lane >> 4) * 4;
    float bb = bias[n0 + ccol];
    #pragma unroll
    for (int r = 0; r < 4; r++) {
        float v = acc[r] + bb;
        v = 0.5f * v * (1.0f + erff(v * 0.70710678118f));
        unsigned short hh = f2bf(v);
        size_t idx = (size_t)(m0 + crow + r) * Nc + n0 + ccol;
        Ch[idx] = hh;
        Cl[idx] = f2bf(v - bf2f(hh));
    }
}

// ---------------- gather pooling (bf16 h) -> hi/lo bf16 outs ----------------
__global__ __launch_bounds__(256) void pool_kernel(const unsigned short* __restrict__ h,
                                                   const int* __restrict__ bofs,
                                                   unsigned short* __restrict__ outs_h,
                                                   unsigned short* __restrict__ outs_l,
                                                   int layer) {
    __shared__ float red[4][DIM];
    int b = blockIdx.x;
    int wave = threadIdx.x >> 6, lane = threadIdx.x & 63;
    int lo = bofs[b], hi = bofs[b + 1];
    float4 s = make_float4(0.f, 0.f, 0.f, 0.f);
    for (int n = lo + wave; n < hi; n += 4) {
        ushort4 u = *(const ushort4*)(h + (size_t)n * DIM + lane * 4);
        s.x += bf2f(u.x); s.y += bf2f(u.y); s.z += bf2f(u.z); s.w += bf2f(u.w);
    }
    *(float4*)(&red[wave][lane * 4]) = s;
    __syncthreads();
    int t = threadIdx.x;
    float val = red[0][t] + red[1][t] + red[2][t] + red[3][t];
    size_t idx = (size_t)b * (N_LAYERS * DIM) + layer * DIM + t;
    unsigned short hh = f2bf(val);
    outs_h[idx] = hh;
    outs_l[idx] = f2bf(val - bf2f(hh));
}

// ---------------- final: out[m] = (zh+zl)[m,:] . w3 + b3 ----------------
__global__ void final_kernel(const unsigned short* __restrict__ zh,
                             const unsigned short* __restrict__ zl,
                             const float* __restrict__ w,
                             const float* __restrict__ b, float* __restrict__ out) {
    int m = blockIdx.x * 64 + threadIdx.x;
    if (m >= N_BATCH) return;
    float s = 0.f;
    for (int k = 0; k < 192; k++)
        s += (bf2f(zh[(size_t)m * 192 + k]) + bf2f(zl[(size_t)m * 192 + k])) * w[k];
    out[m] = s + b[0];
}

__global__ void ws_sentinel_kernel(float* __restrict__ out) {
    int t = blockIdx.x * 256 + threadIdx.x;
    if (t < N_BATCH) out[t] = 1.0e6f;
}

extern "C" void kernel_launch(void* const* d_in, const int* in_sizes, int n_in,
                              void* d_out, int out_size, void* d_ws, size_t ws_size,
                              hipStream_t stream) {
    const int*   x        = (const int*)d_in[0];
    const int*   ei       = (const int*)d_in[1];
    const float* ea       = (const float*)d_in[2];
    const int*   batch    = (const int*)d_in[3];
    const float* node_emb = (const float*)d_in[4];
    const float* ln_scale = (const float*)d_in[5];
    const float* ln_bias  = (const float*)d_in[6];
    const float* wl_w     = (const float*)d_in[7];
    const float* wl_b     = (const float*)d_in[8];
    const float* conv_w   = (const float*)d_in[9];
    const float* conv_b   = (const float*)d_in[10];
    const float* ro_w0    = (const float*)d_in[11];
    const float* ro_b0    = (const float*)d_in[12];
    const float* ro_w1    = (const float*)d_in[13];
    const float* ro_b1    = (const float*)d_in[14];
    const float* ro_w2    = (const float*)d_in[15];
    const float* ro_b2    = (const float*)d_in[16];
    const float* ro_w3    = (const float*)d_in[17];
    const float* ro_b3    = (const float*)d_in[18];
    float* out = (float*)d_out;

    const size_t ND = (size_t)N_NODES * DIM;
    char* p = (char*)d_ws;
    unsigned short* hy_buf = (unsigned short*)p;  p += ND * sizeof(unsigned short);
    unsigned short* A_buf = (unsigned short*)p;   p += ND * sizeof(unsigned short);
    unsigned short* outs_h = (unsigned short*)p;  p += (size_t)N_BATCH * 1536 * sizeof(unsigned short);
    unsigned short* outs_l = (unsigned short*)p;  p += (size_t)N_BATCH * 1536 * sizeof(unsigned short);
    unsigned short* z1h = (unsigned short*)p;     p += (size_t)N_BATCH * 768 * sizeof(unsigned short);
    unsigned short* z1l = (unsigned short*)p;     p += (size_t)N_BATCH * 768 * sizeof(unsigned short);
    unsigned short* z2h = (unsigned short*)p;     p += (size_t)N_BATCH * 384 * sizeof(unsigned short);
    unsigned short* z2l = (unsigned short*)p;     p += (size_t)N_BATCH * 384 * sizeof(unsigned short);
    unsigned short* z3h = (unsigned short*)p;     p += (size_t)N_BATCH * 192 * sizeof(unsigned short);
    unsigned short* z3l = (unsigned short*)p;     p += (size_t)N_BATCH * 192 * sizeof(unsigned short);
    unsigned short* wt_buf = (unsigned short*)p;  p += (size_t)N_LAYERS * DIM * DIM * sizeof(unsigned short);
    unsigned short* wt0h = (unsigned short*)p;    p += (size_t)768 * 1536 * sizeof(unsigned short);
    unsigned short* wt0l = (unsigned short*)p;    p += (size_t)768 * 1536 * sizeof(unsigned short);
    unsigned short* wt1h = (unsigned short*)p;    p += (size_t)384 * 768 * sizeof(unsigned short);
    unsigned short* wt1l = (unsigned short*)p;    p += (size_t)384 * 768 * sizeof(unsigned short);
    unsigned short* wt2h = (unsigned short*)p;    p += (size_t)192 * 384 * sizeof(unsigned short);
    unsigned short* wt2l = (unsigned short*)p;    p += (size_t)192 * 384 * sizeof(unsigned short);
    float* edge_a = (float*)p;                    p += (size_t)N_EDGES * sizeof(float);
    int* deg = (int*)p;                           p += (size_t)N_NODES * sizeof(int);
    int* part = (int*)p;                          p += (size_t)NBLK * sizeof(int);
    int* ofs = (int*)p;                           p += (size_t)(N_NODES + 1) * sizeof(int);
    int* cursor = (int*)p;                        p += (size_t)N_NODES * sizeof(int);
    int* edge_src = (int*)p;                      p += (size_t)N_EDGES * sizeof(int);
    int* bofs = (int*)p;                          p += (size_t)(N_BATCH + 1) * sizeof(int);
    size_t need = (size_t)(p - (char*)d_ws);
    if (ws_size < need) {
        ws_sentinel_kernel<<<2, 256, 0, stream>>>(out);
        return;
    }

    int eb = (N_EDGES + 255) / 256;

    // ---- one-time prep ----
    hipMemsetAsync(deg, 0, N_NODES * sizeof(int), stream);
    hist_kernel<<<eb, 256, 0, stream>>>(ei, deg);
    scan1_kernel<<<NBLK, 256, 0, stream>>>(deg, part);
    scan2_kernel<<<1, 256, 0, stream>>>(part);
    scan3_kernel<<<NBLK, 256, 0, stream>>>(deg, part, ofs, cursor);
    scatter_kernel<<<eb, 256, 0, stream>>>(ei, ea, cursor, edge_src, edge_a);
    bofs_kernel<<<3, 256, 0, stream>>>(batch, bofs);
    wt_kernel<<<(N_LAYERS * DIM * DIM + 255) / 256, 256, 0, stream>>>(conv_w, wt_buf);
    wt_ro_t_kernel<<<dim3(1536 / 32, 768 / 32), 256, 0, stream>>>(ro_w0, wt0h, wt0l, 1536, 768);
    wt_ro_t_kernel<<<dim3(768 / 32, 384 / 32), 256, 0, stream>>>(ro_w1, wt1h, wt1l, 768, 384);
    wt_ro_t_kernel<<<dim3(384 / 32, 192 / 32), 256, 0, stream>>>(ro_w2, wt2h, wt2l, 384, 192);

    // h = bf16(node_emb[x])
    embed_kernel<<<(N_NODES * 64 + 255) / 256, 256, 0, stream>>>(x, node_emb, hy_buf);

    int row_blocks = (N_NODES + 3) / 4;
    int gemm_blocks = (N_NODES + 127) / 128;

    for (int i = 0; i < N_LAYERS; i++) {
        agg_kernel<<<row_blocks, 256, 0, stream>>>(ofs, edge_src, edge_a, hy_buf,
                                                   ln_scale + i * DIM, ln_bias + i * DIM,
                                                   wl_w + i * DIM, wl_b + i * DIM, A_buf);
        mfma_gemm_kernel<<<gemm_blocks, 256, 0, stream>>>(A_buf, wt_buf + (size_t)i * DIM * DIM,
                                                          conv_b + i * DIM, hy_buf, N_NODES);
        pool_kernel<<<N_BATCH, 256, 0, stream>>>(hy_buf, bofs, outs_h, outs_l, i);
    }

    // readout MLP (hi/lo bf16 MFMA ~ fp32, wave-per-tile grids)
    mfma_ro_kernel<<<dim3(8, 48), 256, 0, stream>>>(outs_h, outs_l, wt0h, wt0l, ro_b0,
                                                    z1h, z1l, 1536, 768);
    mfma_ro_kernel<<<dim3(8, 24), 256, 0, stream>>>(z1h, z1l, wt1h, wt1l, ro_b1,
                                                    z2h, z2l, 768, 384);
    mfma_ro_kernel<<<dim3(8, 12), 256, 0, stream>>>(z2h, z2l, wt2h, wt2l, ro_b2,
                                                    z3h, z3l, 384, 192);
    final_kernel<<<(N_BATCH + 63) / 64, 64, 0, stream>>>(z3h, z3l, ro_w3, ro_b3, out);
}

// Round 9
// 732.824 us; speedup vs baseline: 10.5035x; 1.0919x over previous
//
#include <hip/hip_runtime.h>
#include <hip/hip_bf16.h>
#include <math.h>

#define N_NODES 60000
#define N_EDGES 120000
#define N_BATCH 512
#define DIM 256
#define N_LAYERS 6
#define GEN_EPS 1e-7f
#define LN_EPS 1e-5f
#define NBLK ((N_NODES + 255) / 256)   // 235

typedef __attribute__((ext_vector_type(8))) short bf16x8;
typedef __attribute__((ext_vector_type(4))) float f32x4;

__device__ __forceinline__ unsigned short f2bf(float f) {
    unsigned u = __float_as_uint(f);
    u = (u + 0x7fffu + ((u >> 16) & 1u)) >> 16;
    return (unsigned short)u;
}
__device__ __forceinline__ float bf2f(unsigned short u) {
    return __uint_as_float((unsigned)u << 16);
}

// ---------------- embed: h[n] = bf16(node_emb[x[n]]) ----------------
__global__ void embed_kernel(const int* __restrict__ x, const float* __restrict__ emb,
                             unsigned short* __restrict__ h) {
    int t = blockIdx.x * 256 + threadIdx.x;
    int n = t >> 6, lane = t & 63;
    if (n >= N_NODES) return;
    int type = x[n];
    float4 v = *(const float4*)(emb + (size_t)type * DIM + lane * 4);
    ushort4 o;
    o.x = f2bf(v.x); o.y = f2bf(v.y); o.z = f2bf(v.z); o.w = f2bf(v.w);
    *(ushort4*)(h + (size_t)n * DIM + lane * 4) = o;
}

// ---------------- CSR build ----------------
__global__ void hist_kernel(const int* __restrict__ ei, int* __restrict__ deg) {
    int e = blockIdx.x * 256 + threadIdx.x;
    if (e >= N_EDGES) return;
    atomicAdd(&deg[ei[N_EDGES + e]], 1);
}

__global__ void scan1_kernel(const int* __restrict__ deg, int* __restrict__ part) {
    __shared__ int sm[256];
    int i = blockIdx.x * 256 + threadIdx.x;
    int t = threadIdx.x;
    sm[t] = (i < N_NODES) ? deg[i] : 0;
    __syncthreads();
    for (int off = 128; off > 0; off >>= 1) {
        if (t < off) sm[t] += sm[t + off];
        __syncthreads();
    }
    if (t == 0) part[blockIdx.x] = sm[0];
}

__global__ void scan2_kernel(int* __restrict__ part) {
    __shared__ int sm[256];
    int t = threadIdx.x;
    int v = (t < NBLK) ? part[t] : 0;
    sm[t] = v;
    __syncthreads();
    for (int off = 1; off < 256; off <<= 1) {
        int add = (t >= off) ? sm[t - off] : 0;
        __syncthreads();
        sm[t] += add;
        __syncthreads();
    }
    if (t < NBLK) part[t] = sm[t] - v;   // exclusive
}

__global__ void scan3_kernel(const int* __restrict__ deg, const int* __restrict__ part,
                             int* __restrict__ ofs, int* __restrict__ cursor) {
    __shared__ int sm[256];
    int i = blockIdx.x * 256 + threadIdx.x;
    int t = threadIdx.x;
    int v = (i < N_NODES) ? deg[i] : 0;
    sm[t] = v;
    __syncthreads();
    for (int off = 1; off < 256; off <<= 1) {
        int add = (t >= off) ? sm[t - off] : 0;
        __syncthreads();
        sm[t] += add;
        __syncthreads();
    }
    int excl = part[blockIdx.x] + sm[t] - v;
    if (i < N_NODES) {
        ofs[i] = excl;
        cursor[i] = excl;
        if (i == N_NODES - 1) ofs[N_NODES] = excl + v;
    }
}

__global__ void scatter_kernel(const int* __restrict__ ei, const float* __restrict__ ea,
                               int* __restrict__ cursor, int* __restrict__ edge_src,
                               float* __restrict__ edge_a) {
    int e = blockIdx.x * 256 + threadIdx.x;
    if (e >= N_EDGES) return;
    int dst = ei[N_EDGES + e];
    int pos = atomicAdd(&cursor[dst], 1);
    edge_src[pos] = ei[e];
    edge_a[pos] = ea[e];
}

// ---------------- batch segment offsets (batch sorted) ----------------
__global__ void bofs_kernel(const int* __restrict__ batch, int* __restrict__ bofs) {
    int b = blockIdx.x * 256 + threadIdx.x;
    if (b > N_BATCH) return;
    int lo = 0, hi = N_NODES;
    while (lo < hi) {
        int mid = (lo + hi) >> 1;
        if (batch[mid] < b) lo = mid + 1; else hi = mid;
    }
    bofs[b] = lo;
}

// ---------------- standalone LN pass: y(bf16) = LN(h)*sc + bi ----------------
// variance via E[x^2]-E[x]^2 so both wave reductions run concurrently
__global__ void ln_kernel(const unsigned short* __restrict__ h,
                          const float* __restrict__ lnsc, const float* __restrict__ lnbi,
                          unsigned short* __restrict__ y) {
    int row = blockIdx.x * 4 + (threadIdx.x >> 6);
    int lane = threadIdx.x & 63;
    if (row >= N_NODES) return;
    int d = lane * 4;
    ushort4 u = *(const ushort4*)(h + (size_t)row * DIM + d);
    float4 v;
    v.x = bf2f(u.x); v.y = bf2f(u.y); v.z = bf2f(u.z); v.w = bf2f(u.w);
    float s = v.x + v.y + v.z + v.w;
    float q = v.x * v.x + v.y * v.y + v.z * v.z + v.w * v.w;
    #pragma unroll
    for (int off = 32; off > 0; off >>= 1) {
        s += __shfl_xor(s, off, 64);
        q += __shfl_xor(q, off, 64);
    }
    float mu = s * (1.0f / DIM);
    float var = q * (1.0f / DIM) - mu * mu;
    float r = rsqrtf(fmaxf(var, 0.0f) + LN_EPS);
    float4 sc = *(const float4*)(lnsc + d);
    float4 bi = *(const float4*)(lnbi + d);
    ushort4 o;
    o.x = f2bf((v.x - mu) * r * sc.x + bi.x);
    o.y = f2bf((v.y - mu) * r * sc.y + bi.y);
    o.z = f2bf((v.z - mu) * r * sc.z + bi.z);
    o.w = f2bf((v.w - mu) * r * sc.w + bi.w);
    *(ushort4*)(y + (size_t)row * DIM + d) = o;
}

// ---------------- gather-aggregate (reads precomputed y) -> bf16 A ----------------
// A[dst] = softmax-agg over in-edges of relu(y[src]+a*wlw+wlb)+eps, + y[dst]
__global__ void agg_kernel(const int* __restrict__ ofs, const int* __restrict__ edge_src,
                           const float* __restrict__ edge_a, const unsigned short* __restrict__ y,
                           const float* __restrict__ wlw, const float* __restrict__ wlb,
                           unsigned short* __restrict__ A) {
    const float LOG2E = 1.4426950408889634f;
    int dst = blockIdx.x * 4 + (threadIdx.x >> 6);
    int lane = threadIdx.x & 63;
    if (dst >= N_NODES) return;
    int d = lane * 4;
    float4 wv = *(const float4*)(wlw + d);
    float4 bv = *(const float4*)(wlb + d);
    int lo = ofs[dst], hi = ofs[dst + 1];
    float den0 = 0.f, den1 = 0.f, den2 = 0.f, den3 = 0.f;
    float ag0 = 0.f, ag1 = 0.f, ag2 = 0.f, ag3 = 0.f;
    for (int e = lo; e < hi; e++) {
        int src = edge_src[e];
        float a = edge_a[e];
        ushort4 u = *(const ushort4*)(y + (size_t)src * DIM + d);
        float g0 = fmaxf(bf2f(u.x) + a * wv.x + bv.x, 0.0f) + GEN_EPS;
        float g1 = fmaxf(bf2f(u.y) + a * wv.y + bv.y, 0.0f) + GEN_EPS;
        float g2 = fmaxf(bf2f(u.z) + a * wv.z + bv.z, 0.0f) + GEN_EPS;
        float g3 = fmaxf(bf2f(u.w) + a * wv.w + bv.w, 0.0f) + GEN_EPS;
        float w0 = exp2f(g0 * LOG2E), w1 = exp2f(g1 * LOG2E);
        float w2 = exp2f(g2 * LOG2E), w3 = exp2f(g3 * LOG2E);
        den0 += w0; ag0 += g0 * w0;
        den1 += w1; ag1 += g1 * w1;
        den2 += w2; ag2 += g2 * w2;
        den3 += w3; ag3 += g3 * w3;
    }
    ushort4 ud = *(const ushort4*)(y + (size_t)dst * DIM + d);
    float o0 = ag0 / fmaxf(den0, 1e-16f) + bf2f(ud.x);
    float o1 = ag1 / fmaxf(den1, 1e-16f) + bf2f(ud.y);
    float o2 = ag2 / fmaxf(den2, 1e-16f) + bf2f(ud.z);
    float o3 = ag3 / fmaxf(den3, 1e-16f) + bf2f(ud.w);
    ushort4 o;
    o.x = f2bf(o0); o.y = f2bf(o1); o.z = f2bf(o2); o.w = f2bf(o3);
    *(ushort4*)(A + (size_t)dst * DIM + d) = o;
}

// ---------------- transpose + bf16 conv weights: WT[l][n][k] = bf16(W[l][k][n]) ----
__global__ void wt_kernel(const float* __restrict__ w, unsigned short* __restrict__ wt) {
    int idx = blockIdx.x * 256 + threadIdx.x;
    if (idx >= N_LAYERS * DIM * DIM) return;
    int l = idx >> 16;
    int rem = idx & 0xFFFF;
    int n = rem >> 8;
    int k = rem & 0xFF;
    wt[idx] = f2bf(w[(size_t)l * DIM * DIM + (size_t)k * DIM + n]);
}

// LDS-tiled transpose + hi/lo split: wth/wtl[n*K+k] from w[k*N+n]; K,N % 32 == 0
__global__ __launch_bounds__(256) void wt_ro_t_kernel(const float* __restrict__ w,
                                                      unsigned short* __restrict__ wth,
                                                      unsigned short* __restrict__ wtl,
                                                      int K, int N) {
    __shared__ float tile[32][33];
    int k0 = blockIdx.x * 32, n0 = blockIdx.y * 32;
    int tx = threadIdx.x & 31, ty = threadIdx.x >> 5;   // 8 rows per pass
    #pragma unroll
    for (int i = 0; i < 4; i++)
        tile[ty + 8 * i][tx] = w[(size_t)(k0 + ty + 8 * i) * N + n0 + tx];
    __syncthreads();
    #pragma unroll
    for (int i = 0; i < 4; i++) {
        int n = ty + 8 * i;
        float v = tile[tx][n];               // w[k0+tx][n0+n]
        unsigned short hh = f2bf(v);
        size_t idx = (size_t)(n0 + n) * K + k0 + tx;
        wth[idx] = hh;
        wtl[idx] = f2bf(v - bf2f(hh));
    }
}

// ---------------- MFMA conv GEMM: h(bf16) = relu(A @ W + b) ----------------
__global__ __launch_bounds__(256) void mfma_gemm_kernel(const unsigned short* __restrict__ A,
                                                        const unsigned short* __restrict__ WT,
                                                        const float* __restrict__ bias,
                                                        unsigned short* __restrict__ C, int M) {
    int lane = threadIdx.x & 63;
    int wave = threadIdx.x >> 6;
    int wr = wave >> 1, wc = wave & 1;
    int m_base = blockIdx.x * 128 + wr * 64;
    int n_base = wc * 128;
    int frow = lane & 15;
    int kp = (lane >> 4) * 8;

    f32x4 acc[4][8];
    #pragma unroll
    for (int i = 0; i < 4; i++)
        #pragma unroll
        for (int j = 0; j < 8; j++) acc[i][j] = (f32x4){0.f, 0.f, 0.f, 0.f};

    const bf16x8 zero8 = {0, 0, 0, 0, 0, 0, 0, 0};
    for (int k0 = 0; k0 < DIM; k0 += 32) {
        bf16x8 a[4], b[8];
        #pragma unroll
        for (int i = 0; i < 4; i++) {
            int gm = m_base + i * 16 + frow;
            a[i] = (gm < M) ? *(const bf16x8*)(A + (size_t)gm * DIM + k0 + kp) : zero8;
        }
        #pragma unroll
        for (int j = 0; j < 8; j++) {
            int gn = n_base + j * 16 + frow;
            b[j] = *(const bf16x8*)(WT + (size_t)gn * DIM + k0 + kp);
        }
        #pragma unroll
        for (int i = 0; i < 4; i++)
            #pragma unroll
            for (int j = 0; j < 8; j++)
                acc[i][j] = __builtin_amdgcn_mfma_f32_16x16x32_bf16(a[i], b[j], acc[i][j], 0, 0, 0);
    }

    int ccol = lane & 15;
    int crow = (lane >> 4) * 4;
    #pragma unroll
    for (int i = 0; i < 4; i++) {
        #pragma unroll
        for (int j = 0; j < 8; j++) {
            int gn = n_base + j * 16 + ccol;
            float bb = bias[gn];
            #pragma unroll
            for (int r = 0; r < 4; r++) {
                int gm = m_base + i * 16 + crow + r;
                if (gm < M) {
                    float v = acc[i][j][r] + bb;
                    C[(size_t)gm * DIM + gn] = f2bf(fmaxf(v, 0.0f));
                }
            }
        }
    }
}

// ---------------- MFMA readout GEMM: wave-per-16x16-tile, hi/lo operands ----------
__global__ __launch_bounds__(256) void mfma_ro_kernel(const unsigned short* __restrict__ Ah,
                                                      const unsigned short* __restrict__ Al,
                                                      const unsigned short* __restrict__ WTh,
                                                      const unsigned short* __restrict__ WTl,
                                                      const float* __restrict__ bias,
                                                      unsigned short* __restrict__ Ch,
                                                      unsigned short* __restrict__ Cl,
                                                      int K, int Nc) {
    int lane = threadIdx.x & 63;
    int wave = threadIdx.x >> 6;
    int m0 = blockIdx.x * 64 + wave * 16;
    int n0 = blockIdx.y * 16;
    int frow = lane & 15;
    int kp = (lane >> 4) * 8;

    f32x4 acc = (f32x4){0.f, 0.f, 0.f, 0.f};
    const unsigned short* aph = Ah + (size_t)(m0 + frow) * K + kp;
    const unsigned short* apl = Al + (size_t)(m0 + frow) * K + kp;
    const unsigned short* bph = WTh + (size_t)(n0 + frow) * K + kp;
    const unsigned short* bpl = WTl + (size_t)(n0 + frow) * K + kp;
    #pragma unroll 4
    for (int k0 = 0; k0 < K; k0 += 32) {
        bf16x8 ah = *(const bf16x8*)(aph + k0);
        bf16x8 al = *(const bf16x8*)(apl + k0);
        bf16x8 bh = *(const bf16x8*)(bph + k0);
        bf16x8 bl = *(const bf16x8*)(bpl + k0);
        acc = __builtin_amdgcn_mfma_f32_16x16x32_bf16(ah, bh, acc, 0, 0, 0);
        acc = __builtin_amdgcn_mfma_f32_16x16x32_bf16(ah, bl, acc, 0, 0, 0);
        acc = __builtin_amdgcn_mfma_f32_16x16x32_bf16(al, bh, acc, 0, 0, 0);
    }

    int ccol = lane & 15;
    int crow = (lane >> 4) * 4;
    float bb = bias[n0 + ccol];
    #pragma unroll
    for (int r = 0; r < 4; r++) {
        float v = acc[r] + bb;
        v = 0.5f * v * (1.0f + erff(v * 0.70710678118f));
        unsigned short hh = f2bf(v);
        size_t idx = (size_t)(m0 + crow + r) * Nc + n0 + ccol;
        Ch[idx] = hh;
        Cl[idx] = f2bf(v - bf2f(hh));
    }
}

// ---------------- gather pooling (bf16 h) -> hi/lo bf16 outs ----------------
__global__ __launch_bounds__(256) void pool_kernel(const unsigned short* __restrict__ h,
                                                   const int* __restrict__ bofs,
                                                   unsigned short* __restrict__ outs_h,
                                                   unsigned short* __restrict__ outs_l,
                                                   int layer) {
    __shared__ float red[4][DIM];
    int b = blockIdx.x;
    int wave = threadIdx.x >> 6, lane = threadIdx.x & 63;
    int lo = bofs[b], hi = bofs[b + 1];
    float4 s = make_float4(0.f, 0.f, 0.f, 0.f);
    for (int n = lo + wave; n < hi; n += 4) {
        ushort4 u = *(const ushort4*)(h + (size_t)n * DIM + lane * 4);
        s.x += bf2f(u.x); s.y += bf2f(u.y); s.z += bf2f(u.z); s.w += bf2f(u.w);
    }
    *(float4*)(&red[wave][lane * 4]) = s;
    __syncthreads();
    int t = threadIdx.x;
    float val = red[0][t] + red[1][t] + red[2][t] + red[3][t];
    size_t idx = (size_t)b * (N_LAYERS * DIM) + layer * DIM + t;
    unsigned short hh = f2bf(val);
    outs_h[idx] = hh;
    outs_l[idx] = f2bf(val - bf2f(hh));
}

// ---------------- final: out[m] = (zh+zl)[m,:] . w3 + b3 ----------------
__global__ void final_kernel(const unsigned short* __restrict__ zh,
                             const unsigned short* __restrict__ zl,
                             const float* __restrict__ w,
                             const float* __restrict__ b, float* __restrict__ out) {
    int m = blockIdx.x * 64 + threadIdx.x;
    if (m >= N_BATCH) return;
    float s = 0.f;
    for (int k = 0; k < 192; k++)
        s += (bf2f(zh[(size_t)m * 192 + k]) + bf2f(zl[(size_t)m * 192 + k])) * w[k];
    out[m] = s + b[0];
}

__global__ void ws_sentinel_kernel(float* __restrict__ out) {
    int t = blockIdx.x * 256 + threadIdx.x;
    if (t < N_BATCH) out[t] = 1.0e6f;
}

extern "C" void kernel_launch(void* const* d_in, const int* in_sizes, int n_in,
                              void* d_out, int out_size, void* d_ws, size_t ws_size,
                              hipStream_t stream) {
    const int*   x        = (const int*)d_in[0];
    const int*   ei       = (const int*)d_in[1];
    const float* ea       = (const float*)d_in[2];
    const int*   batch    = (const int*)d_in[3];
    const float* node_emb = (const float*)d_in[4];
    const float* ln_scale = (const float*)d_in[5];
    const float* ln_bias  = (const float*)d_in[6];
    const float* wl_w     = (const float*)d_in[7];
    const float* wl_b     = (const float*)d_in[8];
    const float* conv_w   = (const float*)d_in[9];
    const float* conv_b   = (const float*)d_in[10];
    const float* ro_w0    = (const float*)d_in[11];
    const float* ro_b0    = (const float*)d_in[12];
    const float* ro_w1    = (const float*)d_in[13];
    const float* ro_b1    = (const float*)d_in[14];
    const float* ro_w2    = (const float*)d_in[15];
    const float* ro_b2    = (const float*)d_in[16];
    const float* ro_w3    = (const float*)d_in[17];
    const float* ro_b3    = (const float*)d_in[18];
    float* out = (float*)d_out;

    const size_t ND = (size_t)N_NODES * DIM;
    char* p = (char*)d_ws;
    unsigned short* hy_buf = (unsigned short*)p;  p += ND * sizeof(unsigned short);
    unsigned short* y_buf = (unsigned short*)p;   p += ND * sizeof(unsigned short);
    unsigned short* A_buf = (unsigned short*)p;   p += ND * sizeof(unsigned short);
    unsigned short* outs_h = (unsigned short*)p;  p += (size_t)N_BATCH * 1536 * sizeof(unsigned short);
    unsigned short* outs_l = (unsigned short*)p;  p += (size_t)N_BATCH * 1536 * sizeof(unsigned short);
    unsigned short* z1h = (unsigned short*)p;     p += (size_t)N_BATCH * 768 * sizeof(unsigned short);
    unsigned short* z1l = (unsigned short*)p;     p += (size_t)N_BATCH * 768 * sizeof(unsigned short);
    unsigned short* z2h = (unsigned short*)p;     p += (size_t)N_BATCH * 384 * sizeof(unsigned short);
    unsigned short* z2l = (unsigned short*)p;     p += (size_t)N_BATCH * 384 * sizeof(unsigned short);
    unsigned short* z3h = (unsigned short*)p;     p += (size_t)N_BATCH * 192 * sizeof(unsigned short);
    unsigned short* z3l = (unsigned short*)p;     p += (size_t)N_BATCH * 192 * sizeof(unsigned short);
    unsigned short* wt_buf = (unsigned short*)p;  p += (size_t)N_LAYERS * DIM * DIM * sizeof(unsigned short);
    unsigned short* wt0h = (unsigned short*)p;    p += (size_t)768 * 1536 * sizeof(unsigned short);
    unsigned short* wt0l = (unsigned short*)p;    p += (size_t)768 * 1536 * sizeof(unsigned short);
    unsigned short* wt1h = (unsigned short*)p;    p += (size_t)384 * 768 * sizeof(unsigned short);
    unsigned short* wt1l = (unsigned short*)p;    p += (size_t)384 * 768 * sizeof(unsigned short);
    unsigned short* wt2h = (unsigned short*)p;    p += (size_t)192 * 384 * sizeof(unsigned short);
    unsigned short* wt2l = (unsigned short*)p;    p += (size_t)192 * 384 * sizeof(unsigned short);
    float* edge_a = (float*)p;                    p += (size_t)N_EDGES * sizeof(float);
    int* deg = (int*)p;                           p += (size_t)N_NODES * sizeof(int);
    int* part = (int*)p;                          p += (size_t)NBLK * sizeof(int);
    int* ofs = (int*)p;                           p += (size_t)(N_NODES + 1) * sizeof(int);
    int* cursor = (int*)p;                        p += (size_t)N_NODES * sizeof(int);
    int* edge_src = (int*)p;                      p += (size_t)N_EDGES * sizeof(int);
    int* bofs = (int*)p;                          p += (size_t)(N_BATCH + 1) * sizeof(int);
    size_t need = (size_t)(p - (char*)d_ws);
    if (ws_size < need) {
        ws_sentinel_kernel<<<2, 256, 0, stream>>>(out);
        return;
    }

    int eb = (N_EDGES + 255) / 256;

    // ---- one-time prep ----
    hipMemsetAsync(deg, 0, N_NODES * sizeof(int), stream);
    hist_kernel<<<eb, 256, 0, stream>>>(ei, deg);
    scan1_kernel<<<NBLK, 256, 0, stream>>>(deg, part);
    scan2_kernel<<<1, 256, 0, stream>>>(part);
    scan3_kernel<<<NBLK, 256, 0, stream>>>(deg, part, ofs, cursor);
    scatter_kernel<<<eb, 256, 0, stream>>>(ei, ea, cursor, edge_src, edge_a);
    bofs_kernel<<<3, 256, 0, stream>>>(batch, bofs);
    wt_kernel<<<(N_LAYERS * DIM * DIM + 255) / 256, 256, 0, stream>>>(conv_w, wt_buf);
    wt_ro_t_kernel<<<dim3(1536 / 32, 768 / 32), 256, 0, stream>>>(ro_w0, wt0h, wt0l, 1536, 768);
    wt_ro_t_kernel<<<dim3(768 / 32, 384 / 32), 256, 0, stream>>>(ro_w1, wt1h, wt1l, 768, 384);
    wt_ro_t_kernel<<<dim3(384 / 32, 192 / 32), 256, 0, stream>>>(ro_w2, wt2h, wt2l, 384, 192);

    // h = bf16(node_emb[x])
    embed_kernel<<<(N_NODES * 64 + 255) / 256, 256, 0, stream>>>(x, node_emb, hy_buf);

    int row_blocks = (N_NODES + 3) / 4;
    int gemm_blocks = (N_NODES + 127) / 128;

    for (int i = 0; i < N_LAYERS; i++) {
        // y = LN(h) once per node
        ln_kernel<<<row_blocks, 256, 0, stream>>>(hy_buf, ln_scale + i * DIM, ln_bias + i * DIM, y_buf);
        // A = softmax-agg(y) + y
        agg_kernel<<<row_blocks, 256, 0, stream>>>(ofs, edge_src, edge_a, y_buf,
                                                   wl_w + i * DIM, wl_b + i * DIM, A_buf);
        mfma_gemm_kernel<<<gemm_blocks, 256, 0, stream>>>(A_buf, wt_buf + (size_t)i * DIM * DIM,
                                                          conv_b + i * DIM, hy_buf, N_NODES);
        pool_kernel<<<N_BATCH, 256, 0, stream>>>(hy_buf, bofs, outs_h, outs_l, i);
    }

    // readout MLP (hi/lo bf16 MFMA ~ fp32, wave-per-tile grids)
    mfma_ro_kernel<<<dim3(8, 48), 256, 0, stream>>>(outs_h, outs_l, wt0h, wt0l, ro_b0,
                                                    z1h, z1l, 1536, 768);
    mfma_ro_kernel<<<dim3(8, 24), 256, 0, stream>>>(z1h, z1l, wt1h, wt1l, ro_b1,
                                                    z2h, z2l, 768, 384);
    mfma_ro_kernel<<<dim3(8, 12), 256, 0, stream>>>(z2h, z2l, wt2h, wt2l, ro_b2,
                                                    z3h, z3l, 384, 192);
    final_kernel<<<(N_BATCH + 63) / 64, 64, 0, stream>>>(z3h, z3l, ro_w3, ro_b3, out);
}

// Round 10
// 723.596 us; speedup vs baseline: 10.6375x; 1.0128x over previous
//
#include <hip/hip_runtime.h>
#include <hip/hip_bf16.h>
#include <math.h>

#define N_NODES 60000
#define N_EDGES 120000
#define N_BATCH 512
#define DIM 256
#define N_LAYERS 6
#define GEN_EPS 1e-7f
#define LN_EPS 1e-5f
#define NBLK ((N_NODES + 255) / 256)   // 235

typedef __attribute__((ext_vector_type(8))) short bf16x8;
typedef __attribute__((ext_vector_type(4))) float f32x4;

__device__ __forceinline__ unsigned short f2bf(float f) {
    unsigned u = __float_as_uint(f);
    u = (u + 0x7fffu + ((u >> 16) & 1u)) >> 16;
    return (unsigned short)u;
}
__device__ __forceinline__ float bf2f(unsigned short u) {
    return __uint_as_float((unsigned)u << 16);
}

// ---------------- embed: h[n] = bf16(node_emb[x[n]]) ----------------
__global__ void embed_kernel(const int* __restrict__ x, const float* __restrict__ emb,
                             unsigned short* __restrict__ h) {
    int t = blockIdx.x * 256 + threadIdx.x;
    int n = t >> 6, lane = t & 63;
    if (n >= N_NODES) return;
    int type = x[n];
    float4 v = *(const float4*)(emb + (size_t)type * DIM + lane * 4);
    ushort4 o;
    o.x = f2bf(v.x); o.y = f2bf(v.y); o.z = f2bf(v.z); o.w = f2bf(v.w);
    *(ushort4*)(h + (size_t)n * DIM + lane * 4) = o;
}

// ---------------- CSR build ----------------
__global__ void hist_kernel(const int* __restrict__ ei, int* __restrict__ deg) {
    int e = blockIdx.x * 256 + threadIdx.x;
    if (e >= N_EDGES) return;
    atomicAdd(&deg[ei[N_EDGES + e]], 1);
}

__global__ void scan1_kernel(const int* __restrict__ deg, int* __restrict__ part) {
    __shared__ int sm[256];
    int i = blockIdx.x * 256 + threadIdx.x;
    int t = threadIdx.x;
    sm[t] = (i < N_NODES) ? deg[i] : 0;
    __syncthreads();
    for (int off = 128; off > 0; off >>= 1) {
        if (t < off) sm[t] += sm[t + off];
        __syncthreads();
    }
    if (t == 0) part[blockIdx.x] = sm[0];
}

__global__ void scan2_kernel(int* __restrict__ part) {
    __shared__ int sm[256];
    int t = threadIdx.x;
    int v = (t < NBLK) ? part[t] : 0;
    sm[t] = v;
    __syncthreads();
    for (int off = 1; off < 256; off <<= 1) {
        int add = (t >= off) ? sm[t - off] : 0;
        __syncthreads();
        sm[t] += add;
        __syncthreads();
    }
    if (t < NBLK) part[t] = sm[t] - v;   // exclusive
}

__global__ void scan3_kernel(const int* __restrict__ deg, const int* __restrict__ part,
                             int* __restrict__ ofs, int* __restrict__ cursor) {
    __shared__ int sm[256];
    int i = blockIdx.x * 256 + threadIdx.x;
    int t = threadIdx.x;
    int v = (i < N_NODES) ? deg[i] : 0;
    sm[t] = v;
    __syncthreads();
    for (int off = 1; off < 256; off <<= 1) {
        int add = (t >= off) ? sm[t - off] : 0;
        __syncthreads();
        sm[t] += add;
        __syncthreads();
    }
    int excl = part[blockIdx.x] + sm[t] - v;
    if (i < N_NODES) {
        ofs[i] = excl;
        cursor[i] = excl;
        if (i == N_NODES - 1) ofs[N_NODES] = excl + v;
    }
}

__global__ void scatter_kernel(const int* __restrict__ ei, const float* __restrict__ ea,
                               int* __restrict__ cursor, int* __restrict__ edge_src,
                               float* __restrict__ edge_a) {
    int e = blockIdx.x * 256 + threadIdx.x;
    if (e >= N_EDGES) return;
    int dst = ei[N_EDGES + e];
    int pos = atomicAdd(&cursor[dst], 1);
    edge_src[pos] = ei[e];
    edge_a[pos] = ea[e];
}

// ---------------- batch segment offsets (batch sorted) ----------------
__global__ void bofs_kernel(const int* __restrict__ batch, int* __restrict__ bofs) {
    int b = blockIdx.x * 256 + threadIdx.x;
    if (b > N_BATCH) return;
    int lo = 0, hi = N_NODES;
    while (lo < hi) {
        int mid = (lo + hi) >> 1;
        if (batch[mid] < b) lo = mid + 1; else hi = mid;
    }
    bofs[b] = lo;
}

// ---------------- standalone LN pass: y(bf16) = LN(h)*sc + bi ----------------
__global__ void ln_kernel(const unsigned short* __restrict__ h,
                          const float* __restrict__ lnsc, const float* __restrict__ lnbi,
                          unsigned short* __restrict__ y) {
    int row = blockIdx.x * 4 + (threadIdx.x >> 6);
    int lane = threadIdx.x & 63;
    if (row >= N_NODES) return;
    int d = lane * 4;
    ushort4 u = *(const ushort4*)(h + (size_t)row * DIM + d);
    float4 v;
    v.x = bf2f(u.x); v.y = bf2f(u.y); v.z = bf2f(u.z); v.w = bf2f(u.w);
    float s = v.x + v.y + v.z + v.w;
    float q = v.x * v.x + v.y * v.y + v.z * v.z + v.w * v.w;
    #pragma unroll
    for (int off = 32; off > 0; off >>= 1) {
        s += __shfl_xor(s, off, 64);
        q += __shfl_xor(q, off, 64);
    }
    float mu = s * (1.0f / DIM);
    float var = q * (1.0f / DIM) - mu * mu;
    float r = rsqrtf(fmaxf(var, 0.0f) + LN_EPS);
    float4 sc = *(const float4*)(lnsc + d);
    float4 bi = *(const float4*)(lnbi + d);
    ushort4 o;
    o.x = f2bf((v.x - mu) * r * sc.x + bi.x);
    o.y = f2bf((v.y - mu) * r * sc.y + bi.y);
    o.z = f2bf((v.z - mu) * r * sc.z + bi.z);
    o.w = f2bf((v.w - mu) * r * sc.w + bi.w);
    *(ushort4*)(y + (size_t)row * DIM + d) = o;
}

// ---------------- gather-aggregate (reads precomputed y) -> bf16 A ----------------
__global__ void agg_kernel(const int* __restrict__ ofs, const int* __restrict__ edge_src,
                           const float* __restrict__ edge_a, const unsigned short* __restrict__ y,
                           const float* __restrict__ wlw, const float* __restrict__ wlb,
                           unsigned short* __restrict__ A) {
    const float LOG2E = 1.4426950408889634f;
    int dst = blockIdx.x * 4 + (threadIdx.x >> 6);
    int lane = threadIdx.x & 63;
    if (dst >= N_NODES) return;
    int d = lane * 4;
    float4 wv = *(const float4*)(wlw + d);
    float4 bv = *(const float4*)(wlb + d);
    int lo = ofs[dst], hi = ofs[dst + 1];
    float den0 = 0.f, den1 = 0.f, den2 = 0.f, den3 = 0.f;
    float ag0 = 0.f, ag1 = 0.f, ag2 = 0.f, ag3 = 0.f;
    for (int e = lo; e < hi; e++) {
        int src = edge_src[e];
        float a = edge_a[e];
        ushort4 u = *(const ushort4*)(y + (size_t)src * DIM + d);
        float g0 = fmaxf(bf2f(u.x) + a * wv.x + bv.x, 0.0f) + GEN_EPS;
        float g1 = fmaxf(bf2f(u.y) + a * wv.y + bv.y, 0.0f) + GEN_EPS;
        float g2 = fmaxf(bf2f(u.z) + a * wv.z + bv.z, 0.0f) + GEN_EPS;
        float g3 = fmaxf(bf2f(u.w) + a * wv.w + bv.w, 0.0f) + GEN_EPS;
        float w0 = exp2f(g0 * LOG2E), w1 = exp2f(g1 * LOG2E);
        float w2 = exp2f(g2 * LOG2E), w3 = exp2f(g3 * LOG2E);
        den0 += w0; ag0 += g0 * w0;
        den1 += w1; ag1 += g1 * w1;
        den2 += w2; ag2 += g2 * w2;
        den3 += w3; ag3 += g3 * w3;
    }
    ushort4 ud = *(const ushort4*)(y + (size_t)dst * DIM + d);
    float o0 = ag0 / fmaxf(den0, 1e-16f) + bf2f(ud.x);
    float o1 = ag1 / fmaxf(den1, 1e-16f) + bf2f(ud.y);
    float o2 = ag2 / fmaxf(den2, 1e-16f) + bf2f(ud.z);
    float o3 = ag3 / fmaxf(den3, 1e-16f) + bf2f(ud.w);
    ushort4 o;
    o.x = f2bf(o0); o.y = f2bf(o1); o.z = f2bf(o2); o.w = f2bf(o3);
    *(ushort4*)(A + (size_t)dst * DIM + d) = o;
}

// ---------------- transpose + bf16 conv weights: WT[l][n][k] = bf16(W[l][k][n]) ----
__global__ void wt_kernel(const float* __restrict__ w, unsigned short* __restrict__ wt) {
    int idx = blockIdx.x * 256 + threadIdx.x;
    if (idx >= N_LAYERS * DIM * DIM) return;
    int l = idx >> 16;
    int rem = idx & 0xFFFF;
    int n = rem >> 8;
    int k = rem & 0xFF;
    wt[idx] = f2bf(w[(size_t)l * DIM * DIM + (size_t)k * DIM + n]);
}

// LDS-tiled transpose + hi/lo split: wth/wtl[n*K+k] from w[k*N+n]; K,N % 32 == 0
__global__ __launch_bounds__(256) void wt_ro_t_kernel(const float* __restrict__ w,
                                                      unsigned short* __restrict__ wth,
                                                      unsigned short* __restrict__ wtl,
                                                      int K, int N) {
    __shared__ float tile[32][33];
    int k0 = blockIdx.x * 32, n0 = blockIdx.y * 32;
    int tx = threadIdx.x & 31, ty = threadIdx.x >> 5;   // 8 rows per pass
    #pragma unroll
    for (int i = 0; i < 4; i++)
        tile[ty + 8 * i][tx] = w[(size_t)(k0 + ty + 8 * i) * N + n0 + tx];
    __syncthreads();
    #pragma unroll
    for (int i = 0; i < 4; i++) {
        int n = ty + 8 * i;
        float v = tile[tx][n];               // w[k0+tx][n0+n]
        unsigned short hh = f2bf(v);
        size_t idx = (size_t)(n0 + n) * K + k0 + tx;
        wth[idx] = hh;
        wtl[idx] = f2bf(v - bf2f(hh));
    }
}

// ---------------- MFMA conv GEMM: h(bf16) = relu(A @ W + b) ----------------
// 512 thr = 8 waves (2 wr x 4 wc), block tile 128x256, wave tile 64x64
__global__ __launch_bounds__(512) void mfma_gemm_kernel(const unsigned short* __restrict__ A,
                                                        const unsigned short* __restrict__ WT,
                                                        const float* __restrict__ bias,
                                                        unsigned short* __restrict__ C, int M) {
    int lane = threadIdx.x & 63;
    int wave = threadIdx.x >> 6;
    int wr = wave >> 2, wc = wave & 3;
    int m_base = blockIdx.x * 128 + wr * 64;
    int n_base = wc * 64;
    int frow = lane & 15;
    int kp = (lane >> 4) * 8;

    f32x4 acc[4][4];
    #pragma unroll
    for (int i = 0; i < 4; i++)
        #pragma unroll
        for (int j = 0; j < 4; j++) acc[i][j] = (f32x4){0.f, 0.f, 0.f, 0.f};

    const bf16x8 zero8 = {0, 0, 0, 0, 0, 0, 0, 0};
    for (int k0 = 0; k0 < DIM; k0 += 32) {
        bf16x8 a[4], b[4];
        #pragma unroll
        for (int i = 0; i < 4; i++) {
            int gm = m_base + i * 16 + frow;
            a[i] = (gm < M) ? *(const bf16x8*)(A + (size_t)gm * DIM + k0 + kp) : zero8;
        }
        #pragma unroll
        for (int j = 0; j < 4; j++) {
            int gn = n_base + j * 16 + frow;
            b[j] = *(const bf16x8*)(WT + (size_t)gn * DIM + k0 + kp);
        }
        #pragma unroll
        for (int i = 0; i < 4; i++)
            #pragma unroll
            for (int j = 0; j < 4; j++)
                acc[i][j] = __builtin_amdgcn_mfma_f32_16x16x32_bf16(a[i], b[j], acc[i][j], 0, 0, 0);
    }

    int ccol = lane & 15;
    int crow = (lane >> 4) * 4;
    #pragma unroll
    for (int i = 0; i < 4; i++) {
        #pragma unroll
        for (int j = 0; j < 4; j++) {
            int gn = n_base + j * 16 + ccol;
            float bb = bias[gn];
            #pragma unroll
            for (int r = 0; r < 4; r++) {
                int gm = m_base + i * 16 + crow + r;
                if (gm < M) {
                    float v = acc[i][j][r] + bb;
                    C[(size_t)gm * DIM + gn] = f2bf(fmaxf(v, 0.0f));
                }
            }
        }
    }
}

// ---------------- MFMA readout GEMM: wave-per-16x16-tile, hi/lo operands ----------
__global__ __launch_bounds__(256) void mfma_ro_kernel(const unsigned short* __restrict__ Ah,
                                                      const unsigned short* __restrict__ Al,
                                                      const unsigned short* __restrict__ WTh,
                                                      const unsigned short* __restrict__ WTl,
                                                      const float* __restrict__ bias,
                                                      unsigned short* __restrict__ Ch,
                                                      unsigned short* __restrict__ Cl,
                                                      int K, int Nc) {
    int lane = threadIdx.x & 63;
    int wave = threadIdx.x >> 6;
    int m0 = blockIdx.x * 64 + wave * 16;
    int n0 = blockIdx.y * 16;
    int frow = lane & 15;
    int kp = (lane >> 4) * 8;

    f32x4 acc = (f32x4){0.f, 0.f, 0.f, 0.f};
    const unsigned short* aph = Ah + (size_t)(m0 + frow) * K + kp;
    const unsigned short* apl = Al + (size_t)(m0 + frow) * K + kp;
    const unsigned short* bph = WTh + (size_t)(n0 + frow) * K + kp;
    const unsigned short* bpl = WTl + (size_t)(n0 + frow) * K + kp;
    #pragma unroll 4
    for (int k0 = 0; k0 < K; k0 += 32) {
        bf16x8 ah = *(const bf16x8*)(aph + k0);
        bf16x8 al = *(const bf16x8*)(apl + k0);
        bf16x8 bh = *(const bf16x8*)(bph + k0);
        bf16x8 bl = *(const bf16x8*)(bpl + k0);
        acc = __builtin_amdgcn_mfma_f32_16x16x32_bf16(ah, bh, acc, 0, 0, 0);
        acc = __builtin_amdgcn_mfma_f32_16x16x32_bf16(ah, bl, acc, 0, 0, 0);
        acc = __builtin_amdgcn_mfma_f32_16x16x32_bf16(al, bh, acc, 0, 0, 0);
    }

    int ccol = lane & 15;
    int crow = (lane >> 4) * 4;
    float bb = bias[n0 + ccol];
    #pragma unroll
    for (int r = 0; r < 4; r++) {
        float v = acc[r] + bb;
        v = 0.5f * v * (1.0f + erff(v * 0.70710678118f));
        unsigned short hh = f2bf(v);
        size_t idx = (size_t)(m0 + crow + r) * Nc + n0 + ccol;
        Ch[idx] = hh;
        Cl[idx] = f2bf(v - bf2f(hh));
    }
}

// ---------------- gather pooling (bf16 h) -> hi/lo bf16 outs ----------------
__global__ __launch_bounds__(256) void pool_kernel(const unsigned short* __restrict__ h,
                                                   const int* __restrict__ bofs,
                                                   unsigned short* __restrict__ outs_h,
                                                   unsigned short* __restrict__ outs_l,
                                                   int layer) {
    __shared__ float red[4][DIM];
    int b = blockIdx.x;
    int wave = threadIdx.x >> 6, lane = threadIdx.x & 63;
    int lo = bofs[b], hi = bofs[b + 1];
    float4 s = make_float4(0.f, 0.f, 0.f, 0.f);
    for (int n = lo + wave; n < hi; n += 4) {
        ushort4 u = *(const ushort4*)(h + (size_t)n * DIM + lane * 4);
        s.x += bf2f(u.x); s.y += bf2f(u.y); s.z += bf2f(u.z); s.w += bf2f(u.w);
    }
    *(float4*)(&red[wave][lane * 4]) = s;
    __syncthreads();
    int t = threadIdx.x;
    float val = red[0][t] + red[1][t] + red[2][t] + red[3][t];
    size_t idx = (size_t)b * (N_LAYERS * DIM) + layer * DIM + t;
    unsigned short hh = f2bf(val);
    outs_h[idx] = hh;
    outs_l[idx] = f2bf(val - bf2f(hh));
}

// ---------------- final: out[m] = (zh+zl)[m,:] . w3 + b3 ----------------
__global__ void final_kernel(const unsigned short* __restrict__ zh,
                             const unsigned short* __restrict__ zl,
                             const float* __restrict__ w,
                             const float* __restrict__ b, float* __restrict__ out) {
    int m = blockIdx.x * 64 + threadIdx.x;
    if (m >= N_BATCH) return;
    float s = 0.f;
    for (int k = 0; k < 192; k++)
        s += (bf2f(zh[(size_t)m * 192 + k]) + bf2f(zl[(size_t)m * 192 + k])) * w[k];
    out[m] = s + b[0];
}

__global__ void ws_sentinel_kernel(float* __restrict__ out) {
    int t = blockIdx.x * 256 + threadIdx.x;
    if (t < N_BATCH) out[t] = 1.0e6f;
}

extern "C" void kernel_launch(void* const* d_in, const int* in_sizes, int n_in,
                              void* d_out, int out_size, void* d_ws, size_t ws_size,
                              hipStream_t stream) {
    const int*   x        = (const int*)d_in[0];
    const int*   ei       = (const int*)d_in[1];
    const float* ea       = (const float*)d_in[2];
    const int*   batch    = (const int*)d_in[3];
    const float* node_emb = (const float*)d_in[4];
    const float* ln_scale = (const float*)d_in[5];
    const float* ln_bias  = (const float*)d_in[6];
    const float* wl_w     = (const float*)d_in[7];
    const float* wl_b     = (const float*)d_in[8];
    const float* conv_w   = (const float*)d_in[9];
    const float* conv_b   = (const float*)d_in[10];
    const float* ro_w0    = (const float*)d_in[11];
    const float* ro_b0    = (const float*)d_in[12];
    const float* ro_w1    = (const float*)d_in[13];
    const float* ro_b1    = (const float*)d_in[14];
    const float* ro_w2    = (const float*)d_in[15];
    const float* ro_b2    = (const float*)d_in[16];
    const float* ro_w3    = (const float*)d_in[17];
    const float* ro_b3    = (const float*)d_in[18];
    float* out = (float*)d_out;

    const size_t ND = (size_t)N_NODES * DIM;
    char* p = (char*)d_ws;
    unsigned short* hy_buf = (unsigned short*)p;  p += ND * sizeof(unsigned short);
    unsigned short* y_buf = (unsigned short*)p;   p += ND * sizeof(unsigned short);
    unsigned short* A_buf = (unsigned short*)p;   p += ND * sizeof(unsigned short);
    unsigned short* outs_h = (unsigned short*)p;  p += (size_t)N_BATCH * 1536 * sizeof(unsigned short);
    unsigned short* outs_l = (unsigned short*)p;  p += (size_t)N_BATCH * 1536 * sizeof(unsigned short);
    unsigned short* z1h = (unsigned short*)p;     p += (size_t)N_BATCH * 768 * sizeof(unsigned short);
    unsigned short* z1l = (unsigned short*)p;     p += (size_t)N_BATCH * 768 * sizeof(unsigned short);
    unsigned short* z2h = (unsigned short*)p;     p += (size_t)N_BATCH * 384 * sizeof(unsigned short);
    unsigned short* z2l = (unsigned short*)p;     p += (size_t)N_BATCH * 384 * sizeof(unsigned short);
    unsigned short* z3h = (unsigned short*)p;     p += (size_t)N_BATCH * 192 * sizeof(unsigned short);
    unsigned short* z3l = (unsigned short*)p;     p += (size_t)N_BATCH * 192 * sizeof(unsigned short);
    unsigned short* wt_buf = (unsigned short*)p;  p += (size_t)N_LAYERS * DIM * DIM * sizeof(unsigned short);
    unsigned short* wt0h = (unsigned short*)p;    p += (size_t)768 * 1536 * sizeof(unsigned short);
    unsigned short* wt0l = (unsigned short*)p;    p += (size_t)768 * 1536 * sizeof(unsigned short);
    unsigned short* wt1h = (unsigned short*)p;    p += (size_t)384 * 768 * sizeof(unsigned short);
    unsigned short* wt1l = (unsigned short*)p;    p += (size_t)384 * 768 * sizeof(unsigned short);
    unsigned short* wt2h = (unsigned short*)p;    p += (size_t)192 * 384 * sizeof(unsigned short);
    unsigned short* wt2l = (unsigned short*)p;    p += (size_t)192 * 384 * sizeof(unsigned short);
    float* edge_a = (float*)p;                    p += (size_t)N_EDGES * sizeof(float);
    int* deg = (int*)p;                           p += (size_t)N_NODES * sizeof(int);
    int* part = (int*)p;                          p += (size_t)NBLK * sizeof(int);
    int* ofs = (int*)p;                           p += (size_t)(N_NODES + 1) * sizeof(int);
    int* cursor = (int*)p;                        p += (size_t)N_NODES * sizeof(int);
    int* edge_src = (int*)p;                      p += (size_t)N_EDGES * sizeof(int);
    int* bofs = (int*)p;                          p += (size_t)(N_BATCH + 1) * sizeof(int);
    size_t need = (size_t)(p - (char*)d_ws);
    if (ws_size < need) {
        ws_sentinel_kernel<<<2, 256, 0, stream>>>(out);
        return;
    }

    int eb = (N_EDGES + 255) / 256;

    // ---- one-time prep ----
    hipMemsetAsync(deg, 0, N_NODES * sizeof(int), stream);
    hist_kernel<<<eb, 256, 0, stream>>>(ei, deg);
    scan1_kernel<<<NBLK, 256, 0, stream>>>(deg, part);
    scan2_kernel<<<1, 256, 0, stream>>>(part);
    scan3_kernel<<<NBLK, 256, 0, stream>>>(deg, part, ofs, cursor);
    scatter_kernel<<<eb, 256, 0, stream>>>(ei, ea, cursor, edge_src, edge_a);
    bofs_kernel<<<3, 256, 0, stream>>>(batch, bofs);
    wt_kernel<<<(N_LAYERS * DIM * DIM + 255) / 256, 256, 0, stream>>>(conv_w, wt_buf);
    wt_ro_t_kernel<<<dim3(1536 / 32, 768 / 32), 256, 0, stream>>>(ro_w0, wt0h, wt0l, 1536, 768);
    wt_ro_t_kernel<<<dim3(768 / 32, 384 / 32), 256, 0, stream>>>(ro_w1, wt1h, wt1l, 768, 384);
    wt_ro_t_kernel<<<dim3(384 / 32, 192 / 32), 256, 0, stream>>>(ro_w2, wt2h, wt2l, 384, 192);

    // h = bf16(node_emb[x])
    embed_kernel<<<(N_NODES * 64 + 255) / 256, 256, 0, stream>>>(x, node_emb, hy_buf);

    int row_blocks = (N_NODES + 3) / 4;
    int gemm_blocks = (N_NODES + 127) / 128;

    for (int i = 0; i < N_LAYERS; i++) {
        // y = LN(h) once per node
        ln_kernel<<<row_blocks, 256, 0, stream>>>(hy_buf, ln_scale + i * DIM, ln_bias + i * DIM, y_buf);
        // A = softmax-agg(y) + y
        agg_kernel<<<row_blocks, 256, 0, stream>>>(ofs, edge_src, edge_a, y_buf,
                                                   wl_w + i * DIM, wl_b + i * DIM, A_buf);
        mfma_gemm_kernel<<<gemm_blocks, 512, 0, stream>>>(A_buf, wt_buf + (size_t)i * DIM * DIM,
                                                          conv_b + i * DIM, hy_buf, N_NODES);
        pool_kernel<<<N_BATCH, 256, 0, stream>>>(hy_buf, bofs, outs_h, outs_l, i);
    }

    // readout MLP (hi/lo bf16 MFMA ~ fp32, wave-per-tile grids)
    mfma_ro_kernel<<<dim3(8, 48), 256, 0, stream>>>(outs_h, outs_l, wt0h, wt0l, ro_b0,
                                                    z1h, z1l, 1536, 768);
    mfma_ro_kernel<<<dim3(8, 24), 256, 0, stream>>>(z1h, z1l, wt1h, wt1l, ro_b1,
                                                    z2h, z2l, 768, 384);
    mfma_ro_kernel<<<dim3(8, 12), 256, 0, stream>>>(z2h, z2l, wt2h, wt2l, ro_b2,
                                                    z3h, z3l, 384, 192);
    final_kernel<<<(N_BATCH + 63) / 64, 64, 0, stream>>>(z3h, z3l, ro_w3, ro_b3, out);
}

// Round 11
// 691.795 us; speedup vs baseline: 11.1265x; 1.0460x over previous
//
#include <hip/hip_runtime.h>
#include <hip/hip_bf16.h>
#include <math.h>

#define N_NODES 60000
#define N_EDGES 120000
#define N_BATCH 512
#define DIM 256
#define N_LAYERS 6
#define GEN_EPS 1e-7f
#define LN_EPS 1e-5f
#define NBLK ((N_NODES + 255) / 256)   // 235

typedef __attribute__((ext_vector_type(8))) short bf16x8;
typedef __attribute__((ext_vector_type(4))) float f32x4;

__device__ __forceinline__ unsigned short f2bf(float f) {
    unsigned u = __float_as_uint(f);
    u = (u + 0x7fffu + ((u >> 16) & 1u)) >> 16;
    return (unsigned short)u;
}
__device__ __forceinline__ float bf2f(unsigned short u) {
    return __uint_as_float((unsigned)u << 16);
}

// ---------------- embed + LN0: h = bf16(emb[x]), y = bf16(LN(emb[x])*sc+bi) ----
__global__ void embed_ln_kernel(const int* __restrict__ x, const float* __restrict__ emb,
                                const float* __restrict__ lnsc, const float* __restrict__ lnbi,
                                unsigned short* __restrict__ h, unsigned short* __restrict__ y) {
    int row = blockIdx.x * 4 + (threadIdx.x >> 6);
    int lane = threadIdx.x & 63;
    if (row >= N_NODES) return;
    int d = lane * 4;
    int type = x[row];
    float4 v = *(const float4*)(emb + (size_t)type * DIM + d);
    ushort4 ho;
    ho.x = f2bf(v.x); ho.y = f2bf(v.y); ho.z = f2bf(v.z); ho.w = f2bf(v.w);
    *(ushort4*)(h + (size_t)row * DIM + d) = ho;
    float s = v.x + v.y + v.z + v.w;
    float q = v.x * v.x + v.y * v.y + v.z * v.z + v.w * v.w;
    #pragma unroll
    for (int off = 32; off > 0; off >>= 1) {
        s += __shfl_xor(s, off, 64);
        q += __shfl_xor(q, off, 64);
    }
    float mu = s * (1.0f / DIM);
    float var = q * (1.0f / DIM) - mu * mu;
    float r = rsqrtf(fmaxf(var, 0.0f) + LN_EPS);
    float4 sc = *(const float4*)(lnsc + d);
    float4 bi = *(const float4*)(lnbi + d);
    ushort4 o;
    o.x = f2bf((v.x - mu) * r * sc.x + bi.x);
    o.y = f2bf((v.y - mu) * r * sc.y + bi.y);
    o.z = f2bf((v.z - mu) * r * sc.z + bi.z);
    o.w = f2bf((v.w - mu) * r * sc.w + bi.w);
    *(ushort4*)(y + (size_t)row * DIM + d) = o;
}

// ---------------- CSR build ----------------
__global__ void hist_kernel(const int* __restrict__ ei, int* __restrict__ deg) {
    int e = blockIdx.x * 256 + threadIdx.x;
    if (e >= N_EDGES) return;
    atomicAdd(&deg[ei[N_EDGES + e]], 1);
}

__global__ void scan1_kernel(const int* __restrict__ deg, int* __restrict__ part) {
    __shared__ int sm[256];
    int i = blockIdx.x * 256 + threadIdx.x;
    int t = threadIdx.x;
    sm[t] = (i < N_NODES) ? deg[i] : 0;
    __syncthreads();
    for (int off = 128; off > 0; off >>= 1) {
        if (t < off) sm[t] += sm[t + off];
        __syncthreads();
    }
    if (t == 0) part[blockIdx.x] = sm[0];
}

__global__ void scan2_kernel(int* __restrict__ part) {
    __shared__ int sm[256];
    int t = threadIdx.x;
    int v = (t < NBLK) ? part[t] : 0;
    sm[t] = v;
    __syncthreads();
    for (int off = 1; off < 256; off <<= 1) {
        int add = (t >= off) ? sm[t - off] : 0;
        __syncthreads();
        sm[t] += add;
        __syncthreads();
    }
    if (t < NBLK) part[t] = sm[t] - v;   // exclusive
}

__global__ void scan3_kernel(const int* __restrict__ deg, const int* __restrict__ part,
                             int* __restrict__ ofs, int* __restrict__ cursor) {
    __shared__ int sm[256];
    int i = blockIdx.x * 256 + threadIdx.x;
    int t = threadIdx.x;
    int v = (i < N_NODES) ? deg[i] : 0;
    sm[t] = v;
    __syncthreads();
    for (int off = 1; off < 256; off <<= 1) {
        int add = (t >= off) ? sm[t - off] : 0;
        __syncthreads();
        sm[t] += add;
        __syncthreads();
    }
    int excl = part[blockIdx.x] + sm[t] - v;
    if (i < N_NODES) {
        ofs[i] = excl;
        cursor[i] = excl;
        if (i == N_NODES - 1) ofs[N_NODES] = excl + v;
    }
}

__global__ void scatter_kernel(const int* __restrict__ ei, const float* __restrict__ ea,
                               int* __restrict__ cursor, int* __restrict__ edge_src,
                               float* __restrict__ edge_a) {
    int e = blockIdx.x * 256 + threadIdx.x;
    if (e >= N_EDGES) return;
    int dst = ei[N_EDGES + e];
    int pos = atomicAdd(&cursor[dst], 1);
    edge_src[pos] = ei[e];
    edge_a[pos] = ea[e];
}

// ---------------- batch segment offsets (batch sorted) ----------------
__global__ void bofs_kernel(const int* __restrict__ batch, int* __restrict__ bofs) {
    int b = blockIdx.x * 256 + threadIdx.x;
    if (b > N_BATCH) return;
    int lo = 0, hi = N_NODES;
    while (lo < hi) {
        int mid = (lo + hi) >> 1;
        if (batch[mid] < b) lo = mid + 1; else hi = mid;
    }
    bofs[b] = lo;
}

// ---------------- gather-aggregate (reads precomputed y) -> bf16 A ----------------
__global__ void agg_kernel(const int* __restrict__ ofs, const int* __restrict__ edge_src,
                           const float* __restrict__ edge_a, const unsigned short* __restrict__ y,
                           const float* __restrict__ wlw, const float* __restrict__ wlb,
                           unsigned short* __restrict__ A) {
    const float LOG2E = 1.4426950408889634f;
    int dst = blockIdx.x * 4 + (threadIdx.x >> 6);
    int lane = threadIdx.x & 63;
    if (dst >= N_NODES) return;
    int d = lane * 4;
    float4 wv = *(const float4*)(wlw + d);
    float4 bv = *(const float4*)(wlb + d);
    int lo = ofs[dst], hi = ofs[dst + 1];
    float den0 = 0.f, den1 = 0.f, den2 = 0.f, den3 = 0.f;
    float ag0 = 0.f, ag1 = 0.f, ag2 = 0.f, ag3 = 0.f;
    for (int e = lo; e < hi; e++) {
        int src = edge_src[e];
        float a = edge_a[e];
        ushort4 u = *(const ushort4*)(y + (size_t)src * DIM + d);
        float g0 = fmaxf(bf2f(u.x) + a * wv.x + bv.x, 0.0f) + GEN_EPS;
        float g1 = fmaxf(bf2f(u.y) + a * wv.y + bv.y, 0.0f) + GEN_EPS;
        float g2 = fmaxf(bf2f(u.z) + a * wv.z + bv.z, 0.0f) + GEN_EPS;
        float g3 = fmaxf(bf2f(u.w) + a * wv.w + bv.w, 0.0f) + GEN_EPS;
        float w0 = exp2f(g0 * LOG2E), w1 = exp2f(g1 * LOG2E);
        float w2 = exp2f(g2 * LOG2E), w3 = exp2f(g3 * LOG2E);
        den0 += w0; ag0 += g0 * w0;
        den1 += w1; ag1 += g1 * w1;
        den2 += w2; ag2 += g2 * w2;
        den3 += w3; ag3 += g3 * w3;
    }
    ushort4 ud = *(const ushort4*)(y + (size_t)dst * DIM + d);
    float o0 = ag0 / fmaxf(den0, 1e-16f) + bf2f(ud.x);
    float o1 = ag1 / fmaxf(den1, 1e-16f) + bf2f(ud.y);
    float o2 = ag2 / fmaxf(den2, 1e-16f) + bf2f(ud.z);
    float o3 = ag3 / fmaxf(den3, 1e-16f) + bf2f(ud.w);
    ushort4 o;
    o.x = f2bf(o0); o.y = f2bf(o1); o.z = f2bf(o2); o.w = f2bf(o3);
    *(ushort4*)(A + (size_t)dst * DIM + d) = o;
}

// ---------------- transpose + bf16 conv weights: WT[l][n][k] = bf16(W[l][k][n]) ----
__global__ void wt_kernel(const float* __restrict__ w, unsigned short* __restrict__ wt) {
    int idx = blockIdx.x * 256 + threadIdx.x;
    if (idx >= N_LAYERS * DIM * DIM) return;
    int l = idx >> 16;
    int rem = idx & 0xFFFF;
    int n = rem >> 8;
    int k = rem & 0xFF;
    wt[idx] = f2bf(w[(size_t)l * DIM * DIM + (size_t)k * DIM + n]);
}

// LDS-tiled transpose + hi/lo split: wth/wtl[n*K+k] from w[k*N+n]; K,N % 32 == 0
__global__ __launch_bounds__(256) void wt_ro_t_kernel(const float* __restrict__ w,
                                                      unsigned short* __restrict__ wth,
                                                      unsigned short* __restrict__ wtl,
                                                      int K, int N) {
    __shared__ float tile[32][33];
    int k0 = blockIdx.x * 32, n0 = blockIdx.y * 32;
    int tx = threadIdx.x & 31, ty = threadIdx.x >> 5;   // 8 rows per pass
    #pragma unroll
    for (int i = 0; i < 4; i++)
        tile[ty + 8 * i][tx] = w[(size_t)(k0 + ty + 8 * i) * N + n0 + tx];
    __syncthreads();
    #pragma unroll
    for (int i = 0; i < 4; i++) {
        int n = ty + 8 * i;
        float v = tile[tx][n];               // w[k0+tx][n0+n]
        unsigned short hh = f2bf(v);
        size_t idx = (size_t)(n0 + n) * K + k0 + tx;
        wth[idx] = hh;
        wtl[idx] = f2bf(v - bf2f(hh));
    }
}

// ---------------- MFMA conv GEMM + fused next-layer LN ----------------
// 512 thr = 8 waves (2 wr x 4 wc), block 128x256 (full rows), wave tile 64x64.
// Register double-buffered k-loop. Epilogue: h = relu(acc+b) (bf16 out),
// and if do_ln: y = LN(h)*sc+bi (bf16 out) via 16-lane butterfly + LDS combine.
__global__ __launch_bounds__(512) void mfma_gemm_kernel(const unsigned short* __restrict__ A,
                                                        const unsigned short* __restrict__ WT,
                                                        const float* __restrict__ bias,
                                                        const float* __restrict__ lnsc,
                                                        const float* __restrict__ lnbi,
                                                        unsigned short* __restrict__ Ch,
                                                        unsigned short* __restrict__ Cy,
                                                        int do_ln, int M) {
    __shared__ float lsum[128][4];
    __shared__ float lsq[128][4];
    int lane = threadIdx.x & 63;
    int wave = threadIdx.x >> 6;
    int wr = wave >> 2, wc = wave & 3;
    int m_base = blockIdx.x * 128 + wr * 64;
    int n_base = wc * 64;
    int frow = lane & 15;
    int kp = (lane >> 4) * 8;

    f32x4 acc[4][4];
    #pragma unroll
    for (int i = 0; i < 4; i++)
        #pragma unroll
        for (int j = 0; j < 4; j++) acc[i][j] = (f32x4){0.f, 0.f, 0.f, 0.f};

    const bf16x8 zero8 = {0, 0, 0, 0, 0, 0, 0, 0};
    bf16x8 a0[4], b0[4], a1[4], b1[4];

    auto loadA = [&](bf16x8* dst, int k0) {
        #pragma unroll
        for (int i = 0; i < 4; i++) {
            int gm = m_base + i * 16 + frow;
            dst[i] = (gm < M) ? *(const bf16x8*)(A + (size_t)gm * DIM + k0 + kp) : zero8;
        }
    };
    auto loadB = [&](bf16x8* dst, int k0) {
        #pragma unroll
        for (int j = 0; j < 4; j++)
            dst[j] = *(const bf16x8*)(WT + (size_t)(n_base + j * 16 + frow) * DIM + k0 + kp);
    };
    auto domfma = [&](bf16x8* a, bf16x8* b) {
        #pragma unroll
        for (int i = 0; i < 4; i++)
            #pragma unroll
            for (int j = 0; j < 4; j++)
                acc[i][j] = __builtin_amdgcn_mfma_f32_16x16x32_bf16(a[i], b[j], acc[i][j], 0, 0, 0);
    };

    loadA(a0, 0); loadB(b0, 0);
    #pragma unroll
    for (int kk = 0; kk < 8; kk += 2) {
        if (kk + 1 < 8) { loadA(a1, (kk + 1) * 32); loadB(b1, (kk + 1) * 32); }
        domfma(a0, b0);
        if (kk + 2 < 8) { loadA(a0, (kk + 2) * 32); loadB(b0, (kk + 2) * 32); }
        if (kk + 1 < 8) domfma(a1, b1);
    }

    int ccol = lane & 15;
    int crow = (lane >> 4) * 4;

    // epilogue: v = relu(acc + bias) -> h; per-lane row partial sums for LN
    float psum[4][4], psq[4][4];
    #pragma unroll
    for (int i = 0; i < 4; i++)
        #pragma unroll
        for (int r = 0; r < 4; r++) { psum[i][r] = 0.f; psq[i][r] = 0.f; }

    #pragma unroll
    for (int i = 0; i < 4; i++) {
        #pragma unroll
        for (int j = 0; j < 4; j++) {
            int gn = n_base + j * 16 + ccol;
            float bb = bias[gn];
            #pragma unroll
            for (int r = 0; r < 4; r++) {
                float v = fmaxf(acc[i][j][r] + bb, 0.0f);
                acc[i][j][r] = v;   // keep for LN
                psum[i][r] += v;
                psq[i][r] += v * v;
                int gm = m_base + i * 16 + crow + r;
                if (gm < M) Ch[(size_t)gm * DIM + gn] = f2bf(v);
            }
        }
    }

    if (do_ln) {
        // butterfly across the 16 ccol lanes (masks < 16 stay in group)
        #pragma unroll
        for (int i = 0; i < 4; i++)
            #pragma unroll
            for (int r = 0; r < 4; r++) {
                float s = psum[i][r], q = psq[i][r];
                #pragma unroll
                for (int off = 1; off < 16; off <<= 1) {
                    s += __shfl_xor(s, off, 64);
                    q += __shfl_xor(q, off, 64);
                }
                psum[i][r] = s; psq[i][r] = q;
            }
        if (ccol == 0) {
            #pragma unroll
            for (int i = 0; i < 4; i++)
                #pragma unroll
                for (int r = 0; r < 4; r++) {
                    int lr = wr * 64 + i * 16 + crow + r;
                    lsum[lr][wc] = psum[i][r];
                    lsq[lr][wc] = psq[i][r];
                }
        }
        __syncthreads();
        #pragma unroll
        for (int i = 0; i < 4; i++) {
            #pragma unroll
            for (int r = 0; r < 4; r++) {
                int lr = wr * 64 + i * 16 + crow + r;
                float s = lsum[lr][0] + lsum[lr][1] + lsum[lr][2] + lsum[lr][3];
                float q = lsq[lr][0] + lsq[lr][1] + lsq[lr][2] + lsq[lr][3];
                float mu = s * (1.0f / DIM);
                float var = q * (1.0f / DIM) - mu * mu;
                float rs = rsqrtf(fmaxf(var, 0.0f) + LN_EPS);
                int gm = m_base + i * 16 + crow + r;
                if (gm < M) {
                    #pragma unroll
                    for (int j = 0; j < 4; j++) {
                        int gn = n_base + j * 16 + ccol;
                        float yv = (acc[i][j][r] - mu) * rs * lnsc[gn] + lnbi[gn];
                        Cy[(size_t)gm * DIM + gn] = f2bf(yv);
                    }
                }
            }
        }
    }
}

// ---------------- MFMA readout GEMM: wave-per-16x16-tile, hi/lo operands ----------
__global__ __launch_bounds__(256) void mfma_ro_kernel(const unsigned short* __restrict__ Ah,
                                                      const unsigned short* __restrict__ Al,
                                                      const unsigned short* __restrict__ WTh,
                                                      const unsigned short* __restrict__ WTl,
                                                      const float* __restrict__ bias,
                                                      unsigned short* __restrict__ Ch,
                                                      unsigned short* __restrict__ Cl,
                                                      int K, int Nc) {
    int lane = threadIdx.x & 63;
    int wave = threadIdx.x >> 6;
    int m0 = blockIdx.x * 64 + wave * 16;
    int n0 = blockIdx.y * 16;
    int frow = lane & 15;
    int kp = (lane >> 4) * 8;

    f32x4 acc = (f32x4){0.f, 0.f, 0.f, 0.f};
    const unsigned short* aph = Ah + (size_t)(m0 + frow) * K + kp;
    const unsigned short* apl = Al + (size_t)(m0 + frow) * K + kp;
    const unsigned short* bph = WTh + (size_t)(n0 + frow) * K + kp;
    const unsigned short* bpl = WTl + (size_t)(n0 + frow) * K + kp;
    #pragma unroll 4
    for (int k0 = 0; k0 < K; k0 += 32) {
        bf16x8 ah = *(const bf16x8*)(aph + k0);
        bf16x8 al = *(const bf16x8*)(apl + k0);
        bf16x8 bh = *(const bf16x8*)(bph + k0);
        bf16x8 bl = *(const bf16x8*)(bpl + k0);
        acc = __builtin_amdgcn_mfma_f32_16x16x32_bf16(ah, bh, acc, 0, 0, 0);
        acc = __builtin_amdgcn_mfma_f32_16x16x32_bf16(ah, bl, acc, 0, 0, 0);
        acc = __builtin_amdgcn_mfma_f32_16x16x32_bf16(al, bh, acc, 0, 0, 0);
    }

    int ccol = lane & 15;
    int crow = (lane >> 4) * 4;
    float bb = bias[n0 + ccol];
    #pragma unroll
    for (int r = 0; r < 4; r++) {
        float v = acc[r] + bb;
        v = 0.5f * v * (1.0f + erff(v * 0.70710678118f));
        unsigned short hh = f2bf(v);
        size_t idx = (size_t)(m0 + crow + r) * Nc + n0 + ccol;
        Ch[idx] = hh;
        Cl[idx] = f2bf(v - bf2f(hh));
    }
}

// ---------------- gather pooling (bf16 h) -> hi/lo bf16 outs ----------------
__global__ __launch_bounds__(256) void pool_kernel(const unsigned short* __restrict__ h,
                                                   const int* __restrict__ bofs,
                                                   unsigned short* __restrict__ outs_h,
                                                   unsigned short* __restrict__ outs_l,
                                                   int layer) {
    __shared__ float red[4][DIM];
    int b = blockIdx.x;
    int wave = threadIdx.x >> 6, lane = threadIdx.x & 63;
    int lo = bofs[b], hi = bofs[b + 1];
    float4 s = make_float4(0.f, 0.f, 0.f, 0.f);
    for (int n = lo + wave; n < hi; n += 4) {
        ushort4 u = *(const ushort4*)(h + (size_t)n * DIM + lane * 4);
        s.x += bf2f(u.x); s.y += bf2f(u.y); s.z += bf2f(u.z); s.w += bf2f(u.w);
    }
    *(float4*)(&red[wave][lane * 4]) = s;
    __syncthreads();
    int t = threadIdx.x;
    float val = red[0][t] + red[1][t] + red[2][t] + red[3][t];
    size_t idx = (size_t)b * (N_LAYERS * DIM) + layer * DIM + t;
    unsigned short hh = f2bf(val);
    outs_h[idx] = hh;
    outs_l[idx] = f2bf(val - bf2f(hh));
}

// ---------------- final: out[m] = (zh+zl)[m,:] . w3 + b3 ----------------
__global__ void final_kernel(const unsigned short* __restrict__ zh,
                             const unsigned short* __restrict__ zl,
                             const float* __restrict__ w,
                             const float* __restrict__ b, float* __restrict__ out) {
    int m = blockIdx.x * 64 + threadIdx.x;
    if (m >= N_BATCH) return;
    float s = 0.f;
    for (int k = 0; k < 192; k++)
        s += (bf2f(zh[(size_t)m * 192 + k]) + bf2f(zl[(size_t)m * 192 + k])) * w[k];
    out[m] = s + b[0];
}

__global__ void ws_sentinel_kernel(float* __restrict__ out) {
    int t = blockIdx.x * 256 + threadIdx.x;
    if (t < N_BATCH) out[t] = 1.0e6f;
}

extern "C" void kernel_launch(void* const* d_in, const int* in_sizes, int n_in,
                              void* d_out, int out_size, void* d_ws, size_t ws_size,
                              hipStream_t stream) {
    const int*   x        = (const int*)d_in[0];
    const int*   ei       = (const int*)d_in[1];
    const float* ea       = (const float*)d_in[2];
    const int*   batch    = (const int*)d_in[3];
    const float* node_emb = (const float*)d_in[4];
    const float* ln_scale = (const float*)d_in[5];
    const float* ln_bias  = (const float*)d_in[6];
    const float* wl_w     = (const float*)d_in[7];
    const float* wl_b     = (const float*)d_in[8];
    const float* conv_w   = (const float*)d_in[9];
    const float* conv_b   = (const float*)d_in[10];
    const float* ro_w0    = (const float*)d_in[11];
    const float* ro_b0    = (const float*)d_in[12];
    const float* ro_w1    = (const float*)d_in[13];
    const float* ro_b1    = (const float*)d_in[14];
    const float* ro_w2    = (const float*)d_in[15];
    const float* ro_b2    = (const float*)d_in[16];
    const float* ro_w3    = (const float*)d_in[17];
    const float* ro_b3    = (const float*)d_in[18];
    float* out = (float*)d_out;

    const size_t ND = (size_t)N_NODES * DIM;
    char* p = (char*)d_ws;
    unsigned short* hy_buf = (unsigned short*)p;  p += ND * sizeof(unsigned short);
    unsigned short* y_buf = (unsigned short*)p;   p += ND * sizeof(unsigned short);
    unsigned short* A_buf = (unsigned short*)p;   p += ND * sizeof(unsigned short);
    unsigned short* outs_h = (unsigned short*)p;  p += (size_t)N_BATCH * 1536 * sizeof(unsigned short);
    unsigned short* outs_l = (unsigned short*)p;  p += (size_t)N_BATCH * 1536 * sizeof(unsigned short);
    unsigned short* z1h = (unsigned short*)p;     p += (size_t)N_BATCH * 768 * sizeof(unsigned short);
    unsigned short* z1l = (unsigned short*)p;     p += (size_t)N_BATCH * 768 * sizeof(unsigned short);
    unsigned short* z2h = (unsigned short*)p;     p += (size_t)N_BATCH * 384 * sizeof(unsigned short);
    unsigned short* z2l = (unsigned short*)p;     p += (size_t)N_BATCH * 384 * sizeof(unsigned short);
    unsigned short* z3h = (unsigned short*)p;     p += (size_t)N_BATCH * 192 * sizeof(unsigned short);
    unsigned short* z3l = (unsigned short*)p;     p += (size_t)N_BATCH * 192 * sizeof(unsigned short);
    unsigned short* wt_buf = (unsigned short*)p;  p += (size_t)N_LAYERS * DIM * DIM * sizeof(unsigned short);
    unsigned short* wt0h = (unsigned short*)p;    p += (size_t)768 * 1536 * sizeof(unsigned short);
    unsigned short* wt0l = (unsigned short*)p;    p += (size_t)768 * 1536 * sizeof(unsigned short);
    unsigned short* wt1h = (unsigned short*)p;    p += (size_t)384 * 768 * sizeof(unsigned short);
    unsigned short* wt1l = (unsigned short*)p;    p += (size_t)384 * 768 * sizeof(unsigned short);
    unsigned short* wt2h = (unsigned short*)p;    p += (size_t)192 * 384 * sizeof(unsigned short);
    unsigned short* wt2l = (unsigned short*)p;    p += (size_t)192 * 384 * sizeof(unsigned short);
    float* edge_a = (float*)p;                    p += (size_t)N_EDGES * sizeof(float);
    int* deg = (int*)p;                           p += (size_t)N_NODES * sizeof(int);
    int* part = (int*)p;                          p += (size_t)NBLK * sizeof(int);
    int* ofs = (int*)p;                           p += (size_t)(N_NODES + 1) * sizeof(int);
    int* cursor = (int*)p;                        p += (size_t)N_NODES * sizeof(int);
    int* edge_src = (int*)p;                      p += (size_t)N_EDGES * sizeof(int);
    int* bofs = (int*)p;                          p += (size_t)(N_BATCH + 1) * sizeof(int);
    size_t need = (size_t)(p - (char*)d_ws);
    if (ws_size < need) {
        ws_sentinel_kernel<<<2, 256, 0, stream>>>(out);
        return;
    }

    int eb = (N_EDGES + 255) / 256;

    // ---- one-time prep ----
    hipMemsetAsync(deg, 0, N_NODES * sizeof(int), stream);
    hist_kernel<<<eb, 256, 0, stream>>>(ei, deg);
    scan1_kernel<<<NBLK, 256, 0, stream>>>(deg, part);
    scan2_kernel<<<1, 256, 0, stream>>>(part);
    scan3_kernel<<<NBLK, 256, 0, stream>>>(deg, part, ofs, cursor);
    scatter_kernel<<<eb, 256, 0, stream>>>(ei, ea, cursor, edge_src, edge_a);
    bofs_kernel<<<3, 256, 0, stream>>>(batch, bofs);
    wt_kernel<<<(N_LAYERS * DIM * DIM + 255) / 256, 256, 0, stream>>>(conv_w, wt_buf);
    wt_ro_t_kernel<<<dim3(1536 / 32, 768 / 32), 256, 0, stream>>>(ro_w0, wt0h, wt0l, 1536, 768);
    wt_ro_t_kernel<<<dim3(768 / 32, 384 / 32), 256, 0, stream>>>(ro_w1, wt1h, wt1l, 768, 384);
    wt_ro_t_kernel<<<dim3(384 / 32, 192 / 32), 256, 0, stream>>>(ro_w2, wt2h, wt2l, 384, 192);

    int row_blocks = (N_NODES + 3) / 4;
    int gemm_blocks = (N_NODES + 127) / 128;

    // h0 = bf16(emb[x]); y0 = LN0(h0)
    embed_ln_kernel<<<row_blocks, 256, 0, stream>>>(x, node_emb, ln_scale, ln_bias, hy_buf, y_buf);

    for (int i = 0; i < N_LAYERS; i++) {
        // A = softmax-agg(y) + y
        agg_kernel<<<row_blocks, 256, 0, stream>>>(ofs, edge_src, edge_a, y_buf,
                                                   wl_w + i * DIM, wl_b + i * DIM, A_buf);
        // h = relu(A @ Wc + bc); y = LN_{i+1}(h) fused (skip for last layer)
        int nl = (i + 1 < N_LAYERS) ? (i + 1) : i;
        mfma_gemm_kernel<<<gemm_blocks, 512, 0, stream>>>(A_buf, wt_buf + (size_t)i * DIM * DIM,
                                                          conv_b + i * DIM,
                                                          ln_scale + nl * DIM, ln_bias + nl * DIM,
                                                          hy_buf, y_buf,
                                                          (i + 1 < N_LAYERS) ? 1 : 0, N_NODES);
        pool_kernel<<<N_BATCH, 256, 0, stream>>>(hy_buf, bofs, outs_h, outs_l, i);
    }

    // readout MLP (hi/lo bf16 MFMA ~ fp32, wave-per-tile grids)
    mfma_ro_kernel<<<dim3(8, 48), 256, 0, stream>>>(outs_h, outs_l, wt0h, wt0l, ro_b0,
                                                    z1h, z1l, 1536, 768);
    mfma_ro_kernel<<<dim3(8, 24), 256, 0, stream>>>(z1h, z1l, wt1h, wt1l, ro_b1,
                                                    z2h, z2l, 768, 384);
    mfma_ro_kernel<<<dim3(8, 12), 256, 0, stream>>>(z2h, z2l, wt2h, wt2l, ro_b2,
                                                    z3h, z3l, 384, 192);
    final_kernel<<<(N_BATCH + 63) / 64, 64, 0, stream>>>(z3h, z3l, ro_w3, ro_b3, out);
}

// Round 12
// 687.936 us; speedup vs baseline: 11.1889x; 1.0056x over previous
//
#include <hip/hip_runtime.h>
#include <hip/hip_bf16.h>
#include <math.h>

#define N_NODES 60000
#define N_EDGES 120000
#define N_BATCH 512
#define DIM 256
#define N_LAYERS 6
#define GEN_EPS 1e-7f
#define LN_EPS 1e-5f
#define NBLK ((N_NODES + 255) / 256)   // 235

typedef __attribute__((ext_vector_type(8))) short bf16x8;
typedef __attribute__((ext_vector_type(4))) float f32x4;

__device__ __forceinline__ unsigned short f2bf(float f) {
    unsigned u = __float_as_uint(f);
    u = (u + 0x7fffu + ((u >> 16) & 1u)) >> 16;
    return (unsigned short)u;
}
__device__ __forceinline__ float bf2f(unsigned short u) {
    return __uint_as_float((unsigned)u << 16);
}

// ---------------- embed + LN0: h = bf16(emb[x]), y = bf16(LN(emb[x])*sc+bi) ----
__global__ void embed_ln_kernel(const int* __restrict__ x, const float* __restrict__ emb,
                                const float* __restrict__ lnsc, const float* __restrict__ lnbi,
                                unsigned short* __restrict__ h, unsigned short* __restrict__ y) {
    int row = blockIdx.x * 4 + (threadIdx.x >> 6);
    int lane = threadIdx.x & 63;
    if (row >= N_NODES) return;
    int d = lane * 4;
    int type = x[row];
    float4 v = *(const float4*)(emb + (size_t)type * DIM + d);
    ushort4 ho;
    ho.x = f2bf(v.x); ho.y = f2bf(v.y); ho.z = f2bf(v.z); ho.w = f2bf(v.w);
    *(ushort4*)(h + (size_t)row * DIM + d) = ho;
    float s = v.x + v.y + v.z + v.w;
    float q = v.x * v.x + v.y * v.y + v.z * v.z + v.w * v.w;
    #pragma unroll
    for (int off = 32; off > 0; off >>= 1) {
        s += __shfl_xor(s, off, 64);
        q += __shfl_xor(q, off, 64);
    }
    float mu = s * (1.0f / DIM);
    float var = q * (1.0f / DIM) - mu * mu;
    float r = rsqrtf(fmaxf(var, 0.0f) + LN_EPS);
    float4 sc = *(const float4*)(lnsc + d);
    float4 bi = *(const float4*)(lnbi + d);
    ushort4 o;
    o.x = f2bf((v.x - mu) * r * sc.x + bi.x);
    o.y = f2bf((v.y - mu) * r * sc.y + bi.y);
    o.z = f2bf((v.z - mu) * r * sc.z + bi.z);
    o.w = f2bf((v.w - mu) * r * sc.w + bi.w);
    *(ushort4*)(y + (size_t)row * DIM + d) = o;
}

// ---------------- CSR build ----------------
__global__ void hist_kernel(const int* __restrict__ ei, int* __restrict__ deg) {
    int e = blockIdx.x * 256 + threadIdx.x;
    if (e >= N_EDGES) return;
    atomicAdd(&deg[ei[N_EDGES + e]], 1);
}

__global__ void scan1_kernel(const int* __restrict__ deg, int* __restrict__ part) {
    __shared__ int sm[256];
    int i = blockIdx.x * 256 + threadIdx.x;
    int t = threadIdx.x;
    sm[t] = (i < N_NODES) ? deg[i] : 0;
    __syncthreads();
    for (int off = 128; off > 0; off >>= 1) {
        if (t < off) sm[t] += sm[t + off];
        __syncthreads();
    }
    if (t == 0) part[blockIdx.x] = sm[0];
}

__global__ void scan2_kernel(int* __restrict__ part) {
    __shared__ int sm[256];
    int t = threadIdx.x;
    int v = (t < NBLK) ? part[t] : 0;
    sm[t] = v;
    __syncthreads();
    for (int off = 1; off < 256; off <<= 1) {
        int add = (t >= off) ? sm[t - off] : 0;
        __syncthreads();
        sm[t] += add;
        __syncthreads();
    }
    if (t < NBLK) part[t] = sm[t] - v;   // exclusive
}

__global__ void scan3_kernel(const int* __restrict__ deg, const int* __restrict__ part,
                             int* __restrict__ ofs, int* __restrict__ cursor) {
    __shared__ int sm[256];
    int i = blockIdx.x * 256 + threadIdx.x;
    int t = threadIdx.x;
    int v = (i < N_NODES) ? deg[i] : 0;
    sm[t] = v;
    __syncthreads();
    for (int off = 1; off < 256; off <<= 1) {
        int add = (t >= off) ? sm[t - off] : 0;
        __syncthreads();
        sm[t] += add;
        __syncthreads();
    }
    int excl = part[blockIdx.x] + sm[t] - v;
    if (i < N_NODES) {
        ofs[i] = excl;
        cursor[i] = excl;
        if (i == N_NODES - 1) ofs[N_NODES] = excl + v;
    }
}

__global__ void scatter_kernel(const int* __restrict__ ei, const float* __restrict__ ea,
                               int* __restrict__ cursor, int* __restrict__ edge_src,
                               float* __restrict__ edge_a) {
    int e = blockIdx.x * 256 + threadIdx.x;
    if (e >= N_EDGES) return;
    int dst = ei[N_EDGES + e];
    int pos = atomicAdd(&cursor[dst], 1);
    edge_src[pos] = ei[e];
    edge_a[pos] = ea[e];
}

// ---------------- batch segment offsets (batch sorted) ----------------
__global__ void bofs_kernel(const int* __restrict__ batch, int* __restrict__ bofs) {
    int b = blockIdx.x * 256 + threadIdx.x;
    if (b > N_BATCH) return;
    int lo = 0, hi = N_NODES;
    while (lo < hi) {
        int mid = (lo + hi) >> 1;
        if (batch[mid] < b) lo = mid + 1; else hi = mid;
    }
    bofs[b] = lo;
}

// ---------------- gather-aggregate (reads precomputed y) -> bf16 A ----------------
__global__ void agg_kernel(const int* __restrict__ ofs, const int* __restrict__ edge_src,
                           const float* __restrict__ edge_a, const unsigned short* __restrict__ y,
                           const float* __restrict__ wlw, const float* __restrict__ wlb,
                           unsigned short* __restrict__ A) {
    const float LOG2E = 1.4426950408889634f;
    int dst = blockIdx.x * 4 + (threadIdx.x >> 6);
    int lane = threadIdx.x & 63;
    if (dst >= N_NODES) return;
    int d = lane * 4;
    float4 wv = *(const float4*)(wlw + d);
    float4 bv = *(const float4*)(wlb + d);
    int lo = ofs[dst], hi = ofs[dst + 1];
    float den0 = 0.f, den1 = 0.f, den2 = 0.f, den3 = 0.f;
    float ag0 = 0.f, ag1 = 0.f, ag2 = 0.f, ag3 = 0.f;
    for (int e = lo; e < hi; e++) {
        int src = edge_src[e];
        float a = edge_a[e];
        ushort4 u = *(const ushort4*)(y + (size_t)src * DIM + d);
        float g0 = fmaxf(bf2f(u.x) + a * wv.x + bv.x, 0.0f) + GEN_EPS;
        float g1 = fmaxf(bf2f(u.y) + a * wv.y + bv.y, 0.0f) + GEN_EPS;
        float g2 = fmaxf(bf2f(u.z) + a * wv.z + bv.z, 0.0f) + GEN_EPS;
        float g3 = fmaxf(bf2f(u.w) + a * wv.w + bv.w, 0.0f) + GEN_EPS;
        float w0 = exp2f(g0 * LOG2E), w1 = exp2f(g1 * LOG2E);
        float w2 = exp2f(g2 * LOG2E), w3 = exp2f(g3 * LOG2E);
        den0 += w0; ag0 += g0 * w0;
        den1 += w1; ag1 += g1 * w1;
        den2 += w2; ag2 += g2 * w2;
        den3 += w3; ag3 += g3 * w3;
    }
    ushort4 ud = *(const ushort4*)(y + (size_t)dst * DIM + d);
    float o0 = ag0 / fmaxf(den0, 1e-16f) + bf2f(ud.x);
    float o1 = ag1 / fmaxf(den1, 1e-16f) + bf2f(ud.y);
    float o2 = ag2 / fmaxf(den2, 1e-16f) + bf2f(ud.z);
    float o3 = ag3 / fmaxf(den3, 1e-16f) + bf2f(ud.w);
    ushort4 o;
    o.x = f2bf(o0); o.y = f2bf(o1); o.z = f2bf(o2); o.w = f2bf(o3);
    *(ushort4*)(A + (size_t)dst * DIM + d) = o;
}

// ---------------- transpose + bf16 conv weights: WT[l][n][k] = bf16(W[l][k][n]) ----
__global__ void wt_kernel(const float* __restrict__ w, unsigned short* __restrict__ wt) {
    int idx = blockIdx.x * 256 + threadIdx.x;
    if (idx >= N_LAYERS * DIM * DIM) return;
    int l = idx >> 16;
    int rem = idx & 0xFFFF;
    int n = rem >> 8;
    int k = rem & 0xFF;
    wt[idx] = f2bf(w[(size_t)l * DIM * DIM + (size_t)k * DIM + n]);
}

// LDS-tiled transpose + hi/lo split: wth/wtl[n*K+k] from w[k*N+n]; K,N % 32 == 0
__global__ __launch_bounds__(256) void wt_ro_t_kernel(const float* __restrict__ w,
                                                      unsigned short* __restrict__ wth,
                                                      unsigned short* __restrict__ wtl,
                                                      int K, int N) {
    __shared__ float tile[32][33];
    int k0 = blockIdx.x * 32, n0 = blockIdx.y * 32;
    int tx = threadIdx.x & 31, ty = threadIdx.x >> 5;   // 8 rows per pass
    #pragma unroll
    for (int i = 0; i < 4; i++)
        tile[ty + 8 * i][tx] = w[(size_t)(k0 + ty + 8 * i) * N + n0 + tx];
    __syncthreads();
    #pragma unroll
    for (int i = 0; i < 4; i++) {
        int n = ty + 8 * i;
        float v = tile[tx][n];               // w[k0+tx][n0+n]
        unsigned short hh = f2bf(v);
        size_t idx = (size_t)(n0 + n) * K + k0 + tx;
        wth[idx] = hh;
        wtl[idx] = f2bf(v - bf2f(hh));
    }
}

// ---------------- MFMA conv GEMM + fused next-layer LN ----------------
// 256 thr = 4 waves (1 wr x 4 wc), block 64x256 (full rows), wave tile 64x64.
// 938 blocks -> ~3.7 blocks/CU (tail-balanced). Epilogue: h = relu(acc+b),
// if do_ln: y = LN(h)*sc+bi via 16-lane butterfly + LDS cross-wave combine.
__global__ __launch_bounds__(256) void mfma_gemm_kernel(const unsigned short* __restrict__ A,
                                                        const unsigned short* __restrict__ WT,
                                                        const float* __restrict__ bias,
                                                        const float* __restrict__ lnsc,
                                                        const float* __restrict__ lnbi,
                                                        unsigned short* __restrict__ Ch,
                                                        unsigned short* __restrict__ Cy,
                                                        int do_ln, int M) {
    __shared__ float lsum[64][4];
    __shared__ float lsq[64][4];
    int lane = threadIdx.x & 63;
    int wc = threadIdx.x >> 6;
    int m_base = blockIdx.x * 64;
    int n_base = wc * 64;
    int frow = lane & 15;
    int kp = (lane >> 4) * 8;

    f32x4 acc[4][4];
    #pragma unroll
    for (int i = 0; i < 4; i++)
        #pragma unroll
        for (int j = 0; j < 4; j++) acc[i][j] = (f32x4){0.f, 0.f, 0.f, 0.f};

    const bf16x8 zero8 = {0, 0, 0, 0, 0, 0, 0, 0};
    for (int k0 = 0; k0 < DIM; k0 += 32) {
        bf16x8 a[4], b[4];
        #pragma unroll
        for (int i = 0; i < 4; i++) {
            int gm = m_base + i * 16 + frow;
            a[i] = (gm < M) ? *(const bf16x8*)(A + (size_t)gm * DIM + k0 + kp) : zero8;
        }
        #pragma unroll
        for (int j = 0; j < 4; j++)
            b[j] = *(const bf16x8*)(WT + (size_t)(n_base + j * 16 + frow) * DIM + k0 + kp);
        #pragma unroll
        for (int i = 0; i < 4; i++)
            #pragma unroll
            for (int j = 0; j < 4; j++)
                acc[i][j] = __builtin_amdgcn_mfma_f32_16x16x32_bf16(a[i], b[j], acc[i][j], 0, 0, 0);
    }

    int ccol = lane & 15;
    int crow = (lane >> 4) * 4;

    float psum[4][4], psq[4][4];
    #pragma unroll
    for (int i = 0; i < 4; i++)
        #pragma unroll
        for (int r = 0; r < 4; r++) { psum[i][r] = 0.f; psq[i][r] = 0.f; }

    #pragma unroll
    for (int i = 0; i < 4; i++) {
        #pragma unroll
        for (int j = 0; j < 4; j++) {
            int gn = n_base + j * 16 + ccol;
            float bb = bias[gn];
            #pragma unroll
            for (int r = 0; r < 4; r++) {
                float v = fmaxf(acc[i][j][r] + bb, 0.0f);
                acc[i][j][r] = v;   // keep for LN
                psum[i][r] += v;
                psq[i][r] += v * v;
                int gm = m_base + i * 16 + crow + r;
                if (gm < M) Ch[(size_t)gm * DIM + gn] = f2bf(v);
            }
        }
    }

    if (do_ln) {
        #pragma unroll
        for (int i = 0; i < 4; i++)
            #pragma unroll
            for (int r = 0; r < 4; r++) {
                float s = psum[i][r], q = psq[i][r];
                #pragma unroll
                for (int off = 1; off < 16; off <<= 1) {
                    s += __shfl_xor(s, off, 64);
                    q += __shfl_xor(q, off, 64);
                }
                psum[i][r] = s; psq[i][r] = q;
            }
        if (ccol == 0) {
            #pragma unroll
            for (int i = 0; i < 4; i++)
                #pragma unroll
                for (int r = 0; r < 4; r++) {
                    int lr = i * 16 + crow + r;
                    lsum[lr][wc] = psum[i][r];
                    lsq[lr][wc] = psq[i][r];
                }
        }
        __syncthreads();
        #pragma unroll
        for (int i = 0; i < 4; i++) {
            #pragma unroll
            for (int r = 0; r < 4; r++) {
                int lr = i * 16 + crow + r;
                float s = lsum[lr][0] + lsum[lr][1] + lsum[lr][2] + lsum[lr][3];
                float q = lsq[lr][0] + lsq[lr][1] + lsq[lr][2] + lsq[lr][3];
                float mu = s * (1.0f / DIM);
                float var = q * (1.0f / DIM) - mu * mu;
                float rs = rsqrtf(fmaxf(var, 0.0f) + LN_EPS);
                int gm = m_base + i * 16 + crow + r;
                if (gm < M) {
                    #pragma unroll
                    for (int j = 0; j < 4; j++) {
                        int gn = n_base + j * 16 + ccol;
                        float yv = (acc[i][j][r] - mu) * rs * lnsc[gn] + lnbi[gn];
                        Cy[(size_t)gm * DIM + gn] = f2bf(yv);
                    }
                }
            }
        }
    }
}

// ---------------- MFMA readout GEMM: wave-per-16x16-tile, hi/lo operands ----------
__global__ __launch_bounds__(256) void mfma_ro_kernel(const unsigned short* __restrict__ Ah,
                                                      const unsigned short* __restrict__ Al,
                                                      const unsigned short* __restrict__ WTh,
                                                      const unsigned short* __restrict__ WTl,
                                                      const float* __restrict__ bias,
                                                      unsigned short* __restrict__ Ch,
                                                      unsigned short* __restrict__ Cl,
                                                      int K, int Nc) {
    int lane = threadIdx.x & 63;
    int wave = threadIdx.x >> 6;
    int m0 = blockIdx.x * 64 + wave * 16;
    int n0 = blockIdx.y * 16;
    int frow = lane & 15;
    int kp = (lane >> 4) * 8;

    f32x4 acc = (f32x4){0.f, 0.f, 0.f, 0.f};
    const unsigned short* aph = Ah + (size_t)(m0 + frow) * K + kp;
    const unsigned short* apl = Al + (size_t)(m0 + frow) * K + kp;
    const unsigned short* bph = WTh + (size_t)(n0 + frow) * K + kp;
    const unsigned short* bpl = WTl + (size_t)(n0 + frow) * K + kp;
    #pragma unroll 4
    for (int k0 = 0; k0 < K; k0 += 32) {
        bf16x8 ah = *(const bf16x8*)(aph + k0);
        bf16x8 al = *(const bf16x8*)(apl + k0);
        bf16x8 bh = *(const bf16x8*)(bph + k0);
        bf16x8 bl = *(const bf16x8*)(bpl + k0);
        acc = __builtin_amdgcn_mfma_f32_16x16x32_bf16(ah, bh, acc, 0, 0, 0);
        acc = __builtin_amdgcn_mfma_f32_16x16x32_bf16(ah, bl, acc, 0, 0, 0);
        acc = __builtin_amdgcn_mfma_f32_16x16x32_bf16(al, bh, acc, 0, 0, 0);
    }

    int ccol = lane & 15;
    int crow = (lane >> 4) * 4;
    float bb = bias[n0 + ccol];
    #pragma unroll
    for (int r = 0; r < 4; r++) {
        float v = acc[r] + bb;
        v = 0.5f * v * (1.0f + erff(v * 0.70710678118f));
        unsigned short hh = f2bf(v);
        size_t idx = (size_t)(m0 + crow + r) * Nc + n0 + ccol;
        Ch[idx] = hh;
        Cl[idx] = f2bf(v - bf2f(hh));
    }
}

// ---------------- gather pooling (bf16 h) -> hi/lo bf16 outs ----------------
__global__ __launch_bounds__(256) void pool_kernel(const unsigned short* __restrict__ h,
                                                   const int* __restrict__ bofs,
                                                   unsigned short* __restrict__ outs_h,
                                                   unsigned short* __restrict__ outs_l,
                                                   int layer) {
    __shared__ float red[4][DIM];
    int b = blockIdx.x;
    int wave = threadIdx.x >> 6, lane = threadIdx.x & 63;
    int lo = bofs[b], hi = bofs[b + 1];
    float4 s = make_float4(0.f, 0.f, 0.f, 0.f);
    for (int n = lo + wave; n < hi; n += 4) {
        ushort4 u = *(const ushort4*)(h + (size_t)n * DIM + lane * 4);
        s.x += bf2f(u.x); s.y += bf2f(u.y); s.z += bf2f(u.z); s.w += bf2f(u.w);
    }
    *(float4*)(&red[wave][lane * 4]) = s;
    __syncthreads();
    int t = threadIdx.x;
    float val = red[0][t] + red[1][t] + red[2][t] + red[3][t];
    size_t idx = (size_t)b * (N_LAYERS * DIM) + layer * DIM + t;
    unsigned short hh = f2bf(val);
    outs_h[idx] = hh;
    outs_l[idx] = f2bf(val - bf2f(hh));
}

// ---------------- final: out[m] = (zh+zl)[m,:] . w3 + b3 ----------------
__global__ void final_kernel(const unsigned short* __restrict__ zh,
                             const unsigned short* __restrict__ zl,
                             const float* __restrict__ w,
                             const float* __restrict__ b, float* __restrict__ out) {
    int m = blockIdx.x * 64 + threadIdx.x;
    if (m >= N_BATCH) return;
    float s = 0.f;
    for (int k = 0; k < 192; k++)
        s += (bf2f(zh[(size_t)m * 192 + k]) + bf2f(zl[(size_t)m * 192 + k])) * w[k];
    out[m] = s + b[0];
}

__global__ void ws_sentinel_kernel(float* __restrict__ out) {
    int t = blockIdx.x * 256 + threadIdx.x;
    if (t < N_BATCH) out[t] = 1.0e6f;
}

extern "C" void kernel_launch(void* const* d_in, const int* in_sizes, int n_in,
                              void* d_out, int out_size, void* d_ws, size_t ws_size,
                              hipStream_t stream) {
    const int*   x        = (const int*)d_in[0];
    const int*   ei       = (const int*)d_in[1];
    const float* ea       = (const float*)d_in[2];
    const int*   batch    = (const int*)d_in[3];
    const float* node_emb = (const float*)d_in[4];
    const float* ln_scale = (const float*)d_in[5];
    const float* ln_bias  = (const float*)d_in[6];
    const float* wl_w     = (const float*)d_in[7];
    const float* wl_b     = (const float*)d_in[8];
    const float* conv_w   = (const float*)d_in[9];
    const float* conv_b   = (const float*)d_in[10];
    const float* ro_w0    = (const float*)d_in[11];
    const float* ro_b0    = (const float*)d_in[12];
    const float* ro_w1    = (const float*)d_in[13];
    const float* ro_b1    = (const float*)d_in[14];
    const float* ro_w2    = (const float*)d_in[15];
    const float* ro_b2    = (const float*)d_in[16];
    const float* ro_w3    = (const float*)d_in[17];
    const float* ro_b3    = (const float*)d_in[18];
    float* out = (float*)d_out;

    const size_t ND = (size_t)N_NODES * DIM;
    char* p = (char*)d_ws;
    unsigned short* hy_buf = (unsigned short*)p;  p += ND * sizeof(unsigned short);
    unsigned short* y_buf = (unsigned short*)p;   p += ND * sizeof(unsigned short);
    unsigned short* A_buf = (unsigned short*)p;   p += ND * sizeof(unsigned short);
    unsigned short* outs_h = (unsigned short*)p;  p += (size_t)N_BATCH * 1536 * sizeof(unsigned short);
    unsigned short* outs_l = (unsigned short*)p;  p += (size_t)N_BATCH * 1536 * sizeof(unsigned short);
    unsigned short* z1h = (unsigned short*)p;     p += (size_t)N_BATCH * 768 * sizeof(unsigned short);
    unsigned short* z1l = (unsigned short*)p;     p += (size_t)N_BATCH * 768 * sizeof(unsigned short);
    unsigned short* z2h = (unsigned short*)p;     p += (size_t)N_BATCH * 384 * sizeof(unsigned short);
    unsigned short* z2l = (unsigned short*)p;     p += (size_t)N_BATCH * 384 * sizeof(unsigned short);
    unsigned short* z3h = (unsigned short*)p;     p += (size_t)N_BATCH * 192 * sizeof(unsigned short);
    unsigned short* z3l = (unsigned short*)p;     p += (size_t)N_BATCH * 192 * sizeof(unsigned short);
    unsigned short* wt_buf = (unsigned short*)p;  p += (size_t)N_LAYERS * DIM * DIM * sizeof(unsigned short);
    unsigned short* wt0h = (unsigned short*)p;    p += (size_t)768 * 1536 * sizeof(unsigned short);
    unsigned short* wt0l = (unsigned short*)p;    p += (size_t)768 * 1536 * sizeof(unsigned short);
    unsigned short* wt1h = (unsigned short*)p;    p += (size_t)384 * 768 * sizeof(unsigned short);
    unsigned short* wt1l = (unsigned short*)p;    p += (size_t)384 * 768 * sizeof(unsigned short);
    unsigned short* wt2h = (unsigned short*)p;    p += (size_t)192 * 384 * sizeof(unsigned short);
    unsigned short* wt2l = (unsigned short*)p;    p += (size_t)192 * 384 * sizeof(unsigned short);
    float* edge_a = (float*)p;                    p += (size_t)N_EDGES * sizeof(float);
    int* deg = (int*)p;                           p += (size_t)N_NODES * sizeof(int);
    int* part = (int*)p;                          p += (size_t)NBLK * sizeof(int);
    int* ofs = (int*)p;                           p += (size_t)(N_NODES + 1) * sizeof(int);
    int* cursor = (int*)p;                        p += (size_t)N_NODES * sizeof(int);
    int* edge_src = (int*)p;                      p += (size_t)N_EDGES * sizeof(int);
    int* bofs = (int*)p;                          p += (size_t)(N_BATCH + 1) * sizeof(int);
    size_t need = (size_t)(p - (char*)d_ws);
    if (ws_size < need) {
        ws_sentinel_kernel<<<2, 256, 0, stream>>>(out);
        return;
    }

    int eb = (N_EDGES + 255) / 256;

    // ---- one-time prep ----
    hipMemsetAsync(deg, 0, N_NODES * sizeof(int), stream);
    hist_kernel<<<eb, 256, 0, stream>>>(ei, deg);
    scan1_kernel<<<NBLK, 256, 0, stream>>>(deg, part);
    scan2_kernel<<<1, 256, 0, stream>>>(part);
    scan3_kernel<<<NBLK, 256, 0, stream>>>(deg, part, ofs, cursor);
    scatter_kernel<<<eb, 256, 0, stream>>>(ei, ea, cursor, edge_src, edge_a);
    bofs_kernel<<<3, 256, 0, stream>>>(batch, bofs);
    wt_kernel<<<(N_LAYERS * DIM * DIM + 255) / 256, 256, 0, stream>>>(conv_w, wt_buf);
    wt_ro_t_kernel<<<dim3(1536 / 32, 768 / 32), 256, 0, stream>>>(ro_w0, wt0h, wt0l, 1536, 768);
    wt_ro_t_kernel<<<dim3(768 / 32, 384 / 32), 256, 0, stream>>>(ro_w1, wt1h, wt1l, 768, 384);
    wt_ro_t_kernel<<<dim3(384 / 32, 192 / 32), 256, 0, stream>>>(ro_w2, wt2h, wt2l, 384, 192);

    int row_blocks = (N_NODES + 3) / 4;
    int gemm_blocks = (N_NODES + 63) / 64;

    // h0 = bf16(emb[x]); y0 = LN0(h0)
    embed_ln_kernel<<<row_blocks, 256, 0, stream>>>(x, node_emb, ln_scale, ln_bias, hy_buf, y_buf);

    for (int i = 0; i < N_LAYERS; i++) {
        // A = softmax-agg(y) + y
        agg_kernel<<<row_blocks, 256, 0, stream>>>(ofs, edge_src, edge_a, y_buf,
                                                   wl_w + i * DIM, wl_b + i * DIM, A_buf);
        // h = relu(A @ Wc + bc); y = LN_{i+1}(h) fused (skip for last layer)
        int nl = (i + 1 < N_LAYERS) ? (i + 1) : i;
        mfma_gemm_kernel<<<gemm_blocks, 256, 0, stream>>>(A_buf, wt_buf + (size_t)i * DIM * DIM,
                                                          conv_b + i * DIM,
                                                          ln_scale + nl * DIM, ln_bias + nl * DIM,
                                                          hy_buf, y_buf,
                                                          (i + 1 < N_LAYERS) ? 1 : 0, N_NODES);
        pool_kernel<<<N_BATCH, 256, 0, stream>>>(hy_buf, bofs, outs_h, outs_l, i);
    }

    // readout MLP (hi/lo bf16 MFMA ~ fp32, wave-per-tile grids)
    mfma_ro_kernel<<<dim3(8, 48), 256, 0, stream>>>(outs_h, outs_l, wt0h, wt0l, ro_b0,
                                                    z1h, z1l, 1536, 768);
    mfma_ro_kernel<<<dim3(8, 24), 256, 0, stream>>>(z1h, z1l, wt1h, wt1l, ro_b1,
                                                    z2h, z2l, 768, 384);
    mfma_ro_kernel<<<dim3(8, 12), 256, 0, stream>>>(z2h, z2l, wt2h, wt2l, ro_b2,
                                                    z3h, z3l, 384, 192);
    final_kernel<<<(N_BATCH + 63) / 64, 64, 0, stream>>>(z3h, z3l, ro_w3, ro_b3, out);
}